// Round 10
// baseline (587.625 us; speedup 1.0000x reference)
//
#include <hip/hip_runtime.h>
#include <hip/hip_bf16.h>
#include <math.h>
#include <string.h>

#define B_ 128
#define L_ 128
#define N_ 6
#define FA_ 39
#define FB_ 10
#define D_ 200
#define MB_ 256
#define R_ 3
#define T_ 2
#define NEGV -9e8f
#define BL_ (B_*L_)        // 16384
#define BLD_ (BL_*D_)      // 3276800
#define BD_ (B_*D_)        // 25600
#define G3D_ (3*D_)        // 600
#define FP32TAG 0x3F800000u
#define KP 416             // padded K for gate GEMM (400 -> 416 = 13*32)
#define NP 896             // padded N for gate GEMM (800 -> 896 = 7*128)
#define KC 224             // padded K for ctx GEMM (200 -> 224 = 7*32)
#define NC 256             // padded N for ctx GEMM (200 -> 256)

typedef __hip_bfloat16 bf16;
typedef __attribute__((ext_vector_type(8))) short short8;
typedef __attribute__((ext_vector_type(4))) float f32x4;

__device__ __forceinline__ float b2f(const bf16 x){ return __bfloat162float(x); }
__device__ __forceinline__ unsigned short f2b(float v){ bf16 t = __float2bfloat16(v); return *reinterpret_cast<unsigned short*>(&t); }
__device__ __forceinline__ float bu2f(unsigned short u){ unsigned x = ((unsigned)u)<<16; float f; memcpy(&f,&x,4); return f; }
__device__ __forceinline__ float lreluf(float x){ return x>=0.f ? x : 0.01f*x; }
__device__ __forceinline__ float eluf(float x){ return x>0.f ? x : expm1f(x); }
__device__ __forceinline__ float sigmf(float x){ return 1.f/(1.f+expf(-x)); }

#define NSEG 25
struct CvtArgs { const void* src[NSEG]; int ofs[NSEG+1]; };

#define PREPB_N (R_*NP*KP)     // 1118208
#define PREPW_N (R_*NC*KC)     // 172032
#define PREPB2_N (NP*KP)       // 372736
#define PREPW2_N (NC*KC)       // 57344

// merged prep: convert -> B2t (atom gate W) -> WatT (atom ctx W) -> B2m (mol gate W) -> WmtT (mol ctx W)
__global__ void k_prep(CvtArgs c, float* __restrict__ dst,
                       const void* __restrict__ Wih, const void* __restrict__ Whh,
                       unsigned short* __restrict__ B2t,
                       const void* __restrict__ Watt_r, unsigned short* __restrict__ WatT,
                       const void* __restrict__ mWih_r, const void* __restrict__ mWhh_r,
                       unsigned short* __restrict__ B2m,
                       const void* __restrict__ Wmt_r, unsigned short* __restrict__ WmtT,
                       const unsigned* __restrict__ amtag, int total){
    int i = blockIdx.x*blockDim.x + threadIdx.x;
    bool f32 = (*amtag == FP32TAG);
    if (i < total){
        int s = 0;
        while (i >= c.ofs[s+1]) s++;
        int j = i - c.ofs[s];
        dst[i] = f32 ? ((const float*)c.src[s])[j] : b2f(((const bf16*)c.src[s])[j]);
        return;
    }
    int i2 = i - total;
    if (i2 < PREPB_N){
        int kk = i2 % KP;
        int rest = i2 / KP;
        int n = rest % NP;
        int r = rest / NP;
        float v = 0.f;
        if (kk < 200){
            if (n < 600){
                size_t si = ((size_t)(r*G3D_ + n))*D_ + kk;
                v = f32 ? ((const float*)Wih)[si] : b2f(((const bf16*)Wih)[si]);
            }
        } else if (kk < 400){
            int j = -1;
            if (n < 400) j = n;
            else if (n >= 600 && n < 800) j = n - 200;
            if (j >= 0){
                size_t si = ((size_t)(r*G3D_ + j))*D_ + (kk-200);
                v = f32 ? ((const float*)Whh)[si] : b2f(((const bf16*)Whh)[si]);
            }
        }
        B2t[i2] = f2b(v);
        return;
    }
    int i3 = i2 - PREPB_N;
    if (i3 < PREPW_N){
        int kk = i3 % KC;
        int rest = i3 / KC;
        int n = rest % NC;
        int r = rest / NC;
        float v = 0.f;
        if (kk < 200 && n < 200){
            size_t si = ((size_t)r*D_ + kk)*D_ + n;
            v = f32 ? ((const float*)Watt_r)[si] : b2f(((const bf16*)Watt_r)[si]);
        }
        WatT[i3] = f2b(v);
        return;
    }
    int i4 = i3 - PREPW_N;
    if (i4 < PREPB2_N){
        int kk = i4 % KP;
        int n = i4 / KP;
        float v = 0.f;
        if (kk < 200){
            if (n < 600){
                size_t si = (size_t)n*D_ + kk;
                v = f32 ? ((const float*)mWih_r)[si] : b2f(((const bf16*)mWih_r)[si]);
            }
        } else if (kk < 400){
            int j = -1;
            if (n < 400) j = n;
            else if (n >= 600 && n < 800) j = n - 200;
            if (j >= 0){
                size_t si = (size_t)j*D_ + (kk-200);
                v = f32 ? ((const float*)mWhh_r)[si] : b2f(((const bf16*)mWhh_r)[si]);
            }
        }
        B2m[i4] = f2b(v);
        return;
    }
    int i5 = i4 - PREPB2_N;
    if (i5 < PREPW2_N){
        int kk = i5 % KC;
        int n = i5 / KC;
        float v = 0.f;
        if (kk < 200 && n < 200){
            size_t si = (size_t)kk*D_ + n;
            v = f32 ? ((const float*)Wmt_r)[si] : b2f(((const bf16*)Wmt_r)[si]);
        }
        WmtT[i5] = f2b(v);
    }
}

// fused init, wave-per-atom: atom_feature + P + XH h-half + XH pad + round-0 s1/tb dots
__global__ void __launch_bounds__(256) k_init(const float* __restrict__ atom_list,
                       const float* __restrict__ W_atom, const float* __restrict__ b_atom,
                       const float* __restrict__ W_nei, const float* __restrict__ b_nei,
                       const float* __restrict__ W_align,
                       float* __restrict__ h, float* __restrict__ cur,
                       unsigned short* __restrict__ XH, float* __restrict__ P,
                       float* __restrict__ s1, float* __restrict__ tb){
    int wv = threadIdx.x >> 6, lane = threadIdx.x & 63;
    int al = blockIdx.x*4 + wv;
    const float* arow = atom_list + (size_t)al*FA_;
    float a1 = 0.f, a2 = 0.f;
    for (int d = lane; d < D_; d += 64){
        float acc1 = b_atom[d], acc2 = b_nei[d];
        for (int k=0;k<FA_;k++){
            float a = arow[k];
            acc1 += a * W_atom[k*D_ + d];
            acc2 += a * W_nei[k*D_ + d];
        }
        float v = lreluf(acc1);
        size_t gi = (size_t)al*D_ + d;
        h[gi] = v; cur[gi] = v;
        XH[(size_t)al*KP + 200 + d] = f2b(v);
        P[gi] = acc2;
        a1 += v * W_align[d];
        a2 += v * W_align[D_ + d];
    }
    if (lane < 16) XH[(size_t)al*KP + 400 + lane] = 0;
    for (int o=32;o>0;o>>=1){ a1 += __shfl_xor(a1,o); a2 += __shfl_xor(a2,o); }
    if (lane==0){ s1[al] = a1; tb[al] = a2; }
}

// attention: softmax + weighted neighbor sum -> bf16 wnei (stride KC, zero-padded tail)
__global__ void __launch_bounds__(256) k_attn(
        const float* __restrict__ cur, const float* __restrict__ s1, const float* __restrict__ tb,
        const int* __restrict__ adl, const int* __restrict__ bdl,
        const float* __restrict__ P, const float* __restrict__ bond_list,
        const float* __restrict__ W_nei,
        const float* __restrict__ W_align, const float* __restrict__ b_align, int r,
        unsigned short* __restrict__ wnei, float* __restrict__ wsum){
    int wv = threadIdx.x >> 6;
    int lane = threadIdx.x & 63;
    int al = blockIdx.x*4 + wv;
    int bi = al >> 7;            // / L_
    __shared__ float s_nei[4][N_][D_];

    int idxn[N_]; bool pad[N_];
    for (int n=0;n<N_;n++){ idxn[n] = adl[al*N_ + n]; pad[n] = (idxn[n] == L_-1); }

    float s2[N_];
    if (r == 0){
        const float* Wb = W_nei + FA_*D_;
        for (int j = lane; j < N_*D_; j += 64){
            int n = j / D_, d = j - n*D_;
            int bd = bdl[al*N_ + n];
            const float* brow = bond_list + ((size_t)bi*MB_ + bd)*FB_;
            float acc = P[((size_t)bi*L_ + idxn[n])*D_ + d];
            #pragma unroll
            for (int k=0;k<FB_;k++) acc += brow[k] * Wb[k*D_ + d];
            s_nei[wv][n][d] = lreluf(acc);
        }
        const float* Wab = W_align + D_;
        for (int n=0;n<N_;n++){
            float acc = 0.f;
            for (int d=lane; d<D_; d+=64) acc += s_nei[wv][n][d] * Wab[d];
            for (int o=32;o>0;o>>=1) acc += __shfl_xor(acc,o);
            s2[n] = acc;
        }
    } else {
        float tmp = 0.f;
        if (lane < N_) tmp = tb[bi*L_ + idxn[lane]];
        for (int n=0;n<N_;n++) s2[n] = __shfl(tmp, n);
    }

    float s1v = s1[al];
    float bav = b_align[r];
    float a[N_]; float mx = -1e30f;
    for (int n=0;n<N_;n++){
        float v = lreluf(s1v + s2[n] + bav);
        if (pad[n]) v += NEGV;
        a[n] = v; mx = fmaxf(mx, v);
    }
    float w[N_]; float se = 0.f;
    for (int n=0;n<N_;n++){ float e = expf(a[n]-mx); w[n]=e; se += e; }
    float inv = 1.f/se; float wsv = 0.f;
    for (int n=0;n<N_;n++){ w[n] = pad[n] ? 0.f : w[n]*inv; wsv += w[n]; }

    if (r == 0){
        for (int d=lane; d<D_; d+=64){
            float acc = 0.f;
            #pragma unroll
            for (int n=0;n<N_;n++) acc += w[n] * s_nei[wv][n][d];
            wnei[(size_t)al*KC + d] = f2b(acc);
        }
    } else {
        for (int d=lane; d<D_; d+=64){
            float acc = 0.f;
            #pragma unroll
            for (int n=0;n<N_;n++) acc += w[n] * cur[((size_t)bi*L_ + idxn[n])*D_ + d];
            wnei[(size_t)al*KC + d] = f2b(acc);
        }
    }
    if (lane < 24) wnei[(size_t)al*KC + 200 + lane] = 0;
    if (lane==0) wsum[al] = wsv;
}

// MFMA ctx GEMM: elu(Wn[M,KC] @ Bt^T + wsum*bias) -> XH x-half. 128x64 tile.
// grid mapping: m0=(bid&mmask)*128, n0=(bid>>mshift)*64
__global__ void __launch_bounds__(256) k_ctxmfma(const unsigned short* __restrict__ Wn,
        const float* __restrict__ wsum, const unsigned short* __restrict__ WatT,
        const float* __restrict__ bias, int r, unsigned short* __restrict__ XH,
        int mmask, int mshift){
    __shared__ unsigned short As[128][40];
    __shared__ unsigned short Bs[64][40];
    int tid = threadIdx.x;
    int m0 = ((int)blockIdx.x & mmask) * 128;
    int n0 = ((int)blockIdx.x >> mshift) * 64;
    const unsigned short* Bt = WatT + (size_t)r*NC*KC;
    int lane = tid & 63, wv = tid >> 6;
    int quad = lane >> 4, lm = lane & 15;
    f32x4 acc[2][4];
    #pragma unroll
    for (int a=0;a<2;a++)
        #pragma unroll
        for (int b=0;b<4;b++) acc[a][b] = (f32x4){0.f,0.f,0.f,0.f};
    for (int ks = 0; ks < 7; ks++){
        int s0 = tid, s1_ = tid + 256;
        int r0_ = s0 >> 2, c0 = (s0 & 3) * 8;
        int r1_ = s1_ >> 2, c1 = (s1_ & 3) * 8;
        uint4 a0 = *(const uint4*)&Wn[(size_t)(m0 + r0_)*KC + ks*32 + c0];
        uint4 a1 = *(const uint4*)&Wn[(size_t)(m0 + r1_)*KC + ks*32 + c1];
        uint4 b0 = *(const uint4*)&Bt[(size_t)(n0 + (tid >> 2))*KC + ks*32 + (tid & 3)*8];
        __syncthreads();
        *(uint4*)&As[r0_][c0] = a0;
        *(uint4*)&As[r1_][c1] = a1;
        *(uint4*)&Bs[tid >> 2][(tid & 3)*8] = b0;
        __syncthreads();
        short8 av0 = *(const short8*)&As[wv*32 + lm][quad*8];
        short8 av1 = *(const short8*)&As[wv*32 + 16 + lm][quad*8];
        #pragma unroll
        for (int ns=0; ns<4; ns++){
            short8 bv = *(const short8*)&Bs[ns*16 + lm][quad*8];
            acc[0][ns] = __builtin_amdgcn_mfma_f32_16x16x32_bf16(av0, bv, acc[0][ns], 0,0,0);
            acc[1][ns] = __builtin_amdgcn_mfma_f32_16x16x32_bf16(av1, bv, acc[1][ns], 0,0,0);
        }
    }
    #pragma unroll
    for (int ms=0; ms<2; ms++)
      #pragma unroll
      for (int ns=0; ns<4; ns++){
        int n = n0 + ns*16 + lm;
        if (n < 200){
            float bv = bias[r*D_ + n];
            #pragma unroll
            for (int i=0;i<4;i++){
                int row = m0 + wv*32 + ms*16 + quad*4 + i;
                float v = acc[ms][ns][i] + wsum[row]*bv;
                XH[(size_t)row*KP + n] = f2b(eluf(v));
            }
        }
      }
}

// MFMA gate GEMM: C[M,NP] = XH[M,KP] @ Bt^T. 128x128 tile.
// grid mapping: m0=(bid&mmask)*128, n0=(bid>>mshift)*128
__global__ void __launch_bounds__(256) k_gemm(const unsigned short* __restrict__ XH,
        const unsigned short* __restrict__ B2t, unsigned short* __restrict__ C, int r,
        int mmask, int mshift){
    __shared__ unsigned short As[128][40];
    __shared__ unsigned short Bs[128][40];
    int tid = threadIdx.x;
    int m0 = ((int)blockIdx.x & mmask) * 128;
    int n0 = ((int)blockIdx.x >> mshift) * 128;
    const unsigned short* Bt = B2t + (size_t)r*NP*KP;
    int lane = tid & 63, wv = tid >> 6;
    int quad = lane >> 4, lm = lane & 15;
    f32x4 acc[2][8];
    #pragma unroll
    for (int a=0;a<2;a++)
        #pragma unroll
        for (int b=0;b<8;b++) acc[a][b] = (f32x4){0.f,0.f,0.f,0.f};
    for (int ks = 0; ks < 13; ks++){
        int s0 = tid, s1_ = tid + 256;
        int r0_ = s0 >> 2, c0 = (s0 & 3) * 8;
        int r1_ = s1_ >> 2, c1 = (s1_ & 3) * 8;
        uint4 a0 = *(const uint4*)&XH[(size_t)(m0 + r0_)*KP + ks*32 + c0];
        uint4 a1 = *(const uint4*)&XH[(size_t)(m0 + r1_)*KP + ks*32 + c1];
        uint4 b0 = *(const uint4*)&Bt[(size_t)(n0 + r0_)*KP + ks*32 + c0];
        uint4 b1 = *(const uint4*)&Bt[(size_t)(n0 + r1_)*KP + ks*32 + c1];
        __syncthreads();
        *(uint4*)&As[r0_][c0] = a0;
        *(uint4*)&As[r1_][c1] = a1;
        *(uint4*)&Bs[r0_][c0] = b0;
        *(uint4*)&Bs[r1_][c1] = b1;
        __syncthreads();
        short8 av0 = *(const short8*)&As[wv*32 + lm][quad*8];
        short8 av1 = *(const short8*)&As[wv*32 + 16 + lm][quad*8];
        #pragma unroll
        for (int ns=0; ns<8; ns++){
            short8 bv = *(const short8*)&Bs[ns*16 + lm][quad*8];
            acc[0][ns] = __builtin_amdgcn_mfma_f32_16x16x32_bf16(av0, bv, acc[0][ns], 0,0,0);
            acc[1][ns] = __builtin_amdgcn_mfma_f32_16x16x32_bf16(av1, bv, acc[1][ns], 0,0,0);
        }
    }
    #pragma unroll
    for (int ms=0; ms<2; ms++)
      #pragma unroll
      for (int ns=0; ns<8; ns++)
        #pragma unroll
        for (int i=0;i<4;i++){
            int row = m0 + wv*32 + ms*16 + quad*4 + i;
            C[(size_t)row*NP + n0 + ns*16 + lm] = f2b(acc[ms][ns][i]);
        }
}

// GRU combine, wave-per-atom; fuses next-round s1/tb dots (r<2) or curdot (r==2)
__global__ void __launch_bounds__(256) k_gru2(const unsigned short* __restrict__ C,
        float* __restrict__ h, float* __restrict__ cur, unsigned short* __restrict__ XH,
        const float* __restrict__ bih, const float* __restrict__ bhh,
        const float* __restrict__ W_align, const float* __restrict__ Wma, int r,
        float* __restrict__ s1, float* __restrict__ tb, float* __restrict__ curdot){
    int wv = threadIdx.x >> 6, lane = threadIdx.x & 63;
    int al = blockIdx.x*4 + wv;
    size_t base = (size_t)al*NP;
    const float* bi = bih + r*G3D_;
    const float* bh = bhh + r*G3D_;
    const float* Wa = W_align + (r+1)*2*D_;   // dereferenced only when r<2
    bool last = (r == R_-1);
    float a1 = 0.f, a2 = 0.f;
    for (int j = lane; j < D_; j += 64){
        float rsum = bu2f(C[base + j]);
        float zsum = bu2f(C[base + 200 + j]);
        float gin  = bu2f(C[base + 400 + j]);
        float ghn  = bu2f(C[base + 600 + j]);
        float rr = sigmf(rsum + bi[j] + bh[j]);
        float zz = sigmf(zsum + bi[D_+j] + bh[D_+j]);
        float nn = tanhf(gin + bi[2*D_+j] + rr*(ghn + bh[2*D_+j]));
        size_t gi = (size_t)al*D_ + j;
        float hv = h[gi];
        float hn = (1.f-zz)*nn + zz*hv;
        h[gi] = hn;
        float cv = fmaxf(hn, 0.f);
        cur[gi] = cv;
        XH[(size_t)al*KP + 200 + j] = f2b(hn);
        if (last){
            a1 += cv * Wma[D_+j];
        } else {
            a1 += cv * Wa[j];
            a2 += cv * Wa[D_+j];
        }
    }
    for (int o=32;o>0;o>>=1){ a1 += __shfl_xor(a1,o); a2 += __shfl_xor(a2,o); }
    if (lane==0){
        if (last) curdot[al] = a1;
        else { s1[al] = a1; tb[al] = a2; }
    }
}

__device__ __forceinline__ float brSum(float v, float* s_red){
    for (int o=32;o>0;o>>=1) v += __shfl_xor(v,o);
    int lane = threadIdx.x & 63, wid = threadIdx.x >> 6;
    __syncthreads();
    if (lane==0) s_red[wid] = v;
    __syncthreads();
    float r = 0.f;
    int nw = blockDim.x >> 6;
    for (int i=0;i<nw;i++) r += s_red[i];
    return r;
}

__device__ __forceinline__ float brMax(float v, float* s_red){
    for (int o=32;o>0;o>>=1) v = fmaxf(v, __shfl_xor(v,o));
    int lane = threadIdx.x & 63, wid = threadIdx.x >> 6;
    __syncthreads();
    if (lane==0) s_red[wid] = v;
    __syncthreads();
    float r = s_red[0];
    int nw = blockDim.x >> 6;
    for (int i=1;i<nw;i++) r = fmaxf(r, s_red[i]);
    return r;
}

// mol pooling, (b,d)-parallel: mf = sum_l am*cur; also seeds XHm h-half + pad
__global__ void k_molpool(const float* __restrict__ cur, const float* __restrict__ amask,
                          float* __restrict__ mf, unsigned short* __restrict__ XHm){
    int idx = blockIdx.x*blockDim.x + threadIdx.x;
    if (idx >= BD_) return;
    int b = idx / D_, d = idx - b*D_;
    const float* cb = cur + (size_t)b*L_*D_ + d;
    const float* ab = amask + b*L_;
    float acc = 0.f;
    for (int l=0;l<L_;l++) acc += cb[(size_t)l*D_] * ab[l];
    mf[idx] = acc;
    XHm[(size_t)b*KP + 200 + d] = f2b(acc);
    if (d < 16) XHm[(size_t)b*KP + 400 + d] = 0;
}

// mol attention scores+softmax, one block per molecule (all-parallel reductions)
__global__ void __launch_bounds__(256) k_molattn(const float* __restrict__ mf,
        const float* __restrict__ curdot, const float* __restrict__ amask,
        const float* __restrict__ Wma, const float* __restrict__ bma,
        float* __restrict__ wM, float* __restrict__ wsmM){
    int b = blockIdx.x, tid = threadIdx.x;
    __shared__ float s_red[8];
    float p = (tid < D_) ? fmaxf(mf[b*D_+tid], 0.f) * Wma[tid] : 0.f;
    float s1v = brSum(p, s_red);
    float am = 0.f, sc = -1e30f;
    if (tid < L_){
        am = amask[b*L_+tid];
        sc = lreluf(s1v + curdot[b*L_+tid] + bma[0]);
        if (am == 0.f) sc += NEGV;
    }
    float mx = brMax(sc, s_red);
    float e = (tid < L_) ? expf(sc - mx) : 0.f;
    float se = brSum(e, s_red);
    float wv = (tid < L_) ? e/se*am : 0.f;
    if (tid < L_) wM[b*L_+tid] = wv;
    float wsm = brSum(wv, s_red);
    if (tid == 0) wsmM[b] = wsm;
}

// mol weighted context, (b,d)-parallel -> bf16 wc (stride KC, zero pad)
__global__ void k_molwc(const float* __restrict__ cur, const float* __restrict__ wM,
                        unsigned short* __restrict__ wc16){
    int idx = blockIdx.x*blockDim.x + threadIdx.x;
    if (idx >= BD_) return;
    int b = idx / D_, d = idx - b*D_;
    const float* cb = cur + (size_t)b*L_*D_ + d;
    const float* wb = wM + b*L_;
    float acc = 0.f;
    for (int l=0;l<L_;l++) acc += wb[l] * cb[(size_t)l*D_];
    wc16[(size_t)b*KC + d] = f2b(acc);
    if (d < 24) wc16[(size_t)b*KC + 200 + d] = 0;
}

// mol GRU combine from gate GEMM output, (b,d)-parallel; updates mf and XHm h-half
__global__ void k_molcomb(const unsigned short* __restrict__ Cm, float* __restrict__ mf,
                          unsigned short* __restrict__ XHm,
                          const float* __restrict__ mbih, const float* __restrict__ mbhh){
    int idx = blockIdx.x*blockDim.x + threadIdx.x;
    if (idx >= BD_) return;
    int b = idx / D_, j = idx - b*D_;
    size_t base = (size_t)b*NP;
    float rsum = bu2f(Cm[base + j]);
    float zsum = bu2f(Cm[base + 200 + j]);
    float gin  = bu2f(Cm[base + 400 + j]);
    float ghn  = bu2f(Cm[base + 600 + j]);
    float rr = sigmf(rsum + mbih[j] + mbhh[j]);
    float zz = sigmf(zsum + mbih[D_+j] + mbhh[D_+j]);
    float nn = tanhf(gin + mbih[2*D_+j] + rr*(ghn + mbhh[2*D_+j]));
    float hv = mf[idx];
    float hn = (1.f-zz)*nn + zz*hv;
    mf[idx] = hn;
    XHm[(size_t)b*KP + 200 + j] = f2b(hn);
}

// output head, one block per molecule
__global__ void __launch_bounds__(256) k_molhead(const float* __restrict__ mf,
        const float* __restrict__ Wme, const float* __restrict__ bme,
        const float* __restrict__ Wout, const float* __restrict__ bout,
        void* __restrict__ out, const unsigned* __restrict__ amtag){
    int b = blockIdx.x, tid = threadIdx.x;
    __shared__ float s_mf[D_];
    __shared__ float s_red[8];
    if (tid < D_) s_mf[tid] = mf[b*D_+tid];
    __syncthreads();
    const float dd = (float)(R_ - 2);
    float p = 0.f;
    if (tid < D_){
        float acc = bme[tid];
        for (int k=0;k<D_;k++){
            float m = s_mf[k];
            acc += m * Wme[(size_t)k*D_ + tid];
            acc += (m + dd) * Wme[(size_t)(D_+k)*D_ + tid];
        }
        p = acc * Wout[tid];
    }
    float o = brSum(p, s_red);
    if (tid==0){
        o += bout[0];
        if (*amtag == FP32TAG) ((float*)out)[b] = o;
        else ((bf16*)out)[b] = __float2bfloat16(o);
    }
}

extern "C" void kernel_launch(void* const* d_in, const int* in_sizes, int n_in,
                              void* d_out, int out_size, void* d_ws, size_t ws_size,
                              hipStream_t stream) {
    const int* adl = (const int*)d_in[2];
    const int* bdl = (const int*)d_in[3];
    const unsigned* amtag = (const unsigned*)d_in[4];

    static const int srcidx[NSEG] = {0,1,4,5,6,7,8,9,10,11,12,15,16,17,18,19,20,21,22,23,24,25,26,27,28};
    static const int segsz[NSEG]  = {638976,327680,16384,7800,200,9800,200,1200,3,120000,600,
                                     1800,1800,400,1,40000,200,120000,120000,600,600,80000,200,200,1};
    CvtArgs ca;
    int ofs[NSEG+1]; ofs[0] = 0;
    for (int i=0;i<NSEG;i++){ ca.src[i] = d_in[srcidx[i]]; ca.ofs[i] = ofs[i]; ofs[i+1] = ofs[i] + segsz[i]; }
    ca.ofs[NSEG] = ofs[NSEG];
    const int total = ofs[NSEG];           // 1488645

    // ws layout (floats; offsets 16B aligned). ~79.4 MB total.
    float* ws   = (float*)d_ws;
    float* conv = ws;                                    // 1488648
    float* h    = conv + 1488648;                        // BLD_
    float* cur  = h + BLD_;                              // BLD_
    unsigned short* XH   = (unsigned short*)(cur + BLD_);        // BL_*KP
    unsigned short* B2t  = XH + (size_t)BL_*KP;                  // PREPB_N
    unsigned short* WatT = B2t + PREPB_N;                        // PREPW_N
    unsigned short* B2m  = WatT + PREPW_N;                       // PREPB2_N
    unsigned short* WmtT = B2m + PREPB2_N;                       // PREPW2_N
    float* creg = (float*)(WmtT + PREPW2_N);             // C region: BL_*NP shorts = 7340032 fl
    unsigned short* C = (unsigned short*)creg;
    unsigned short* wnei = (unsigned short*)creg;        // BL_*KC shorts, overlays C head
    float* P    = creg + 1900032;                        // BLD_, overlays C mid (round-0 only)
    float* s1   = creg + 7340032;                        // after C region
    float* tb   = s1 + BL_;
    float* wsum = tb + BL_;
    float* curdot = wsum + BL_;                          // BL_
    float* mf   = curdot + BL_;                          // BD_
    float* wM   = mf + BD_;                              // B_*L_
    float* wsmM = wM + BL_;                              // B_ (pad to 128)
    unsigned short* XHm  = (unsigned short*)(wsmM + 128);    // 128*KP
    unsigned short* Cm   = XHm + (size_t)B_*KP;              // 128*NP
    unsigned short* wc16 = Cm + (size_t)B_*NP;               // 128*KC

    const float* c_atom  = conv + ofs[0];
    const float* c_bond  = conv + ofs[1];
    const float* c_amask = conv + ofs[2];
    const float* c_Watom = conv + ofs[3];
    const float* c_batom = conv + ofs[4];
    const float* c_Wnei  = conv + ofs[5];
    const float* c_bnei  = conv + ofs[6];
    const float* c_Walign= conv + ofs[7];
    const float* c_balign= conv + ofs[8];
    const float* c_batt  = conv + ofs[10];
    const float* c_bih   = conv + ofs[11];
    const float* c_bhh   = conv + ofs[12];
    const float* c_Wma   = conv + ofs[13];
    const float* c_bma   = conv + ofs[14];
    const float* c_bmt   = conv + ofs[16];
    const float* c_mbih  = conv + ofs[19];
    const float* c_mbhh  = conv + ofs[20];
    const float* c_Wme   = conv + ofs[21];
    const float* c_bme   = conv + ofs[22];
    const float* c_Wout  = conv + ofs[23];
    const float* c_bout  = conv + ofs[24];

    const int prep_total = total + PREPB_N + PREPW_N + PREPB2_N + PREPW2_N;   // 3208965
    k_prep<<<(prep_total + 255)/256, 256, 0, stream>>>(ca, conv, d_in[13], d_in[14], B2t,
                                                       d_in[11], WatT, d_in[21], d_in[22], B2m,
                                                       d_in[19], WmtT, amtag, total);
    k_init<<<BL_/4, 256, 0, stream>>>(c_atom, c_Watom, c_batom, c_Wnei, c_bnei, c_Walign,
                                      h, cur, XH, P, s1, tb);

    for (int r=0; r<R_; r++){
        k_attn<<<BL_/4, 256, 0, stream>>>(cur, s1, tb, adl, bdl, P, c_bond,
                                          c_Wnei, c_Walign, c_balign, r, wnei, wsum);
        k_ctxmfma<<<(BL_/128)*(NC/64), 256, 0, stream>>>(wnei, wsum, WatT, c_batt, r, XH, 127, 7);
        k_gemm<<<(BL_/128)*(NP/128), 256, 0, stream>>>(XH, B2t, C, r, 127, 7);
        k_gru2<<<BL_/4, 256, 0, stream>>>(C, h, cur, XH, c_bih, c_bhh,
                                          c_Walign, c_Wma, r, s1, tb, curdot);
    }

    // molecule phase: batched across molecules
    k_molpool<<<(BD_ + 255)/256, 256, 0, stream>>>(cur, c_amask, mf, XHm);
    for (int t=0; t<T_; t++){
        k_molattn<<<B_, 256, 0, stream>>>(mf, curdot, c_amask, c_Wma, c_bma, wM, wsmM);
        k_molwc<<<(BD_ + 255)/256, 256, 0, stream>>>(cur, wM, wc16);
        k_ctxmfma<<<NC/64, 256, 0, stream>>>(wc16, wsmM, WmtT, c_bmt, 0, XHm, 0, 0);
        k_gemm<<<NP/128, 256, 0, stream>>>(XHm, B2m, Cm, 0, 0, 0);
        k_molcomb<<<(BD_ + 255)/256, 256, 0, stream>>>(Cm, mf, XHm, c_mbih, c_mbhh);
    }
    k_molhead<<<B_, 256, 0, stream>>>(mf, c_Wme, c_bme, c_Wout, c_bout, d_out, amtag);
}

// Round 11
// 572.729 us; speedup vs baseline: 1.0260x; 1.0260x over previous
//
#include <hip/hip_runtime.h>
#include <hip/hip_bf16.h>
#include <math.h>
#include <string.h>

#define B_ 128
#define L_ 128
#define N_ 6
#define FA_ 39
#define FB_ 10
#define D_ 200
#define MB_ 256
#define R_ 3
#define T_ 2
#define NEGV -9e8f
#define BL_ (B_*L_)        // 16384
#define BLD_ (BL_*D_)      // 3276800
#define G3D_ (3*D_)        // 600
#define FP32TAG 0x3F800000u
#define KP 416             // padded K for gate GEMM (400 -> 416 = 13*32)
#define NP 896             // padded N for gate GEMM (800 -> 896 = 7*128)
#define KC 224             // padded K for ctx GEMM (200 -> 224 = 7*32)
#define NC 256             // padded N for ctx GEMM (200 -> 256)

typedef __hip_bfloat16 bf16;
typedef __attribute__((ext_vector_type(8))) short short8;
typedef __attribute__((ext_vector_type(4))) float f32x4;

__device__ __forceinline__ float b2f(const bf16 x){ return __bfloat162float(x); }
__device__ __forceinline__ unsigned short f2b(float v){ bf16 t = __float2bfloat16(v); return *reinterpret_cast<unsigned short*>(&t); }
__device__ __forceinline__ float bu2f(unsigned short u){ unsigned x = ((unsigned)u)<<16; float f; memcpy(&f,&x,4); return f; }
__device__ __forceinline__ float lreluf(float x){ return x>=0.f ? x : 0.01f*x; }
__device__ __forceinline__ float eluf(float x){ return x>0.f ? x : expm1f(x); }
__device__ __forceinline__ float sigmf(float x){ return 1.f/(1.f+expf(-x)); }

#define NSEG 25
struct CvtArgs { const void* src[NSEG]; int ofs[NSEG+1]; };

#define PREPB_N (R_*NP*KP)     // 1118208
#define PREPW_N (R_*NC*KC)     // 172032
#define PREPM_N (D_*G3D_)      // 120000

// merged prep: convert -> B2t (atom gate W) -> WatT (atom ctx W) -> mTi/mTh (mol GRU transpose)
__global__ void k_prep(CvtArgs c, float* __restrict__ dst,
                       const void* __restrict__ Wih, const void* __restrict__ Whh,
                       unsigned short* __restrict__ B2t,
                       const void* __restrict__ Watt_r, unsigned short* __restrict__ WatT,
                       const void* __restrict__ mWih_r, const void* __restrict__ mWhh_r,
                       float* __restrict__ mTi, float* __restrict__ mTh,
                       const unsigned* __restrict__ amtag, int total){
    int i = blockIdx.x*blockDim.x + threadIdx.x;
    bool f32 = (*amtag == FP32TAG);
    if (i < total){
        int s = 0;
        while (i >= c.ofs[s+1]) s++;
        int j = i - c.ofs[s];
        dst[i] = f32 ? ((const float*)c.src[s])[j] : b2f(((const bf16*)c.src[s])[j]);
        return;
    }
    int i2 = i - total;
    if (i2 < PREPB_N){
        int kk = i2 % KP;
        int rest = i2 / KP;
        int n = rest % NP;
        int r = rest / NP;
        float v = 0.f;
        if (kk < 200){
            if (n < 600){
                size_t si = ((size_t)(r*G3D_ + n))*D_ + kk;
                v = f32 ? ((const float*)Wih)[si] : b2f(((const bf16*)Wih)[si]);
            }
        } else if (kk < 400){
            int j = -1;
            if (n < 400) j = n;
            else if (n >= 600 && n < 800) j = n - 200;
            if (j >= 0){
                size_t si = ((size_t)(r*G3D_ + j))*D_ + (kk-200);
                v = f32 ? ((const float*)Whh)[si] : b2f(((const bf16*)Whh)[si]);
            }
        }
        B2t[i2] = f2b(v);
        return;
    }
    int i3 = i2 - PREPB_N;
    if (i3 < PREPW_N){
        int kk = i3 % KC;
        int rest = i3 / KC;
        int n = rest % NC;
        int r = rest / NC;
        float v = 0.f;
        if (kk < 200 && n < 200){
            size_t si = ((size_t)r*D_ + kk)*D_ + n;
            v = f32 ? ((const float*)Watt_r)[si] : b2f(((const bf16*)Watt_r)[si]);
        }
        WatT[i3] = f2b(v);
        return;
    }
    int i4 = i3 - PREPW_N;
    if (i4 < PREPM_N){
        int j = i4 % G3D_, k = i4 / G3D_;
        size_t si = (size_t)j*D_ + k;
        mTi[i4] = f32 ? ((const float*)mWih_r)[si] : b2f(((const bf16*)mWih_r)[si]);
        mTh[i4] = f32 ? ((const float*)mWhh_r)[si] : b2f(((const bf16*)mWhh_r)[si]);
    }
}

// fused init, wave-per-atom: atom_feature + P + XH h-half + XH pad + round-0 s1/tb dots
__global__ void __launch_bounds__(256) k_init(const float* __restrict__ atom_list,
                       const float* __restrict__ W_atom, const float* __restrict__ b_atom,
                       const float* __restrict__ W_nei, const float* __restrict__ b_nei,
                       const float* __restrict__ W_align,
                       float* __restrict__ h, float* __restrict__ cur,
                       unsigned short* __restrict__ XH, float* __restrict__ P,
                       float* __restrict__ s1, float* __restrict__ tb){
    int wv = threadIdx.x >> 6, lane = threadIdx.x & 63;
    int al = blockIdx.x*4 + wv;
    const float* arow = atom_list + (size_t)al*FA_;
    float a1 = 0.f, a2 = 0.f;
    for (int d = lane; d < D_; d += 64){
        float acc1 = b_atom[d], acc2 = b_nei[d];
        for (int k=0;k<FA_;k++){
            float a = arow[k];
            acc1 += a * W_atom[k*D_ + d];
            acc2 += a * W_nei[k*D_ + d];
        }
        float v = lreluf(acc1);
        size_t gi = (size_t)al*D_ + d;
        h[gi] = v; cur[gi] = v;
        XH[(size_t)al*KP + 200 + d] = f2b(v);
        P[gi] = acc2;
        a1 += v * W_align[d];
        a2 += v * W_align[D_ + d];
    }
    if (lane < 16) XH[(size_t)al*KP + 400 + lane] = 0;
    for (int o=32;o>0;o>>=1){ a1 += __shfl_xor(a1,o); a2 += __shfl_xor(a2,o); }
    if (lane==0){ s1[al] = a1; tb[al] = a2; }
}

// round-0 attention: on-the-fly nei features + softmax + weighted sum -> bf16 wnei
__global__ void __launch_bounds__(256) k_attn(
        const float* __restrict__ s1, const float* __restrict__ tb,
        const int* __restrict__ adl, const int* __restrict__ bdl,
        const float* __restrict__ P, const float* __restrict__ bond_list,
        const float* __restrict__ W_nei,
        const float* __restrict__ W_align, const float* __restrict__ b_align,
        unsigned short* __restrict__ wnei, float* __restrict__ wsum){
    int wv = threadIdx.x >> 6;
    int lane = threadIdx.x & 63;
    int al = blockIdx.x*4 + wv;
    int bi = al >> 7;            // / L_
    __shared__ float s_nei[4][N_][D_];

    int idxn[N_]; bool pad[N_];
    for (int n=0;n<N_;n++){ idxn[n] = adl[al*N_ + n]; pad[n] = (idxn[n] == L_-1); }

    float s2[N_];
    const float* Wb = W_nei + FA_*D_;
    for (int j = lane; j < N_*D_; j += 64){
        int n = j / D_, d = j - n*D_;
        int bd = bdl[al*N_ + n];
        const float* brow = bond_list + ((size_t)bi*MB_ + bd)*FB_;
        float acc = P[((size_t)bi*L_ + idxn[n])*D_ + d];
        #pragma unroll
        for (int k=0;k<FB_;k++) acc += brow[k] * Wb[k*D_ + d];
        s_nei[wv][n][d] = lreluf(acc);
    }
    const float* Wab = W_align + D_;
    for (int n=0;n<N_;n++){
        float acc = 0.f;
        for (int d=lane; d<D_; d+=64) acc += s_nei[wv][n][d] * Wab[d];
        for (int o=32;o>0;o>>=1) acc += __shfl_xor(acc,o);
        s2[n] = acc;
    }

    float s1v = s1[al];
    float bav = b_align[0];
    float a[N_]; float mx = -1e30f;
    for (int n=0;n<N_;n++){
        float v = lreluf(s1v + s2[n] + bav);
        if (pad[n]) v += NEGV;
        a[n] = v; mx = fmaxf(mx, v);
    }
    float w[N_]; float se = 0.f;
    for (int n=0;n<N_;n++){ float e = expf(a[n]-mx); w[n]=e; se += e; }
    float inv = 1.f/se; float wsv = 0.f;
    for (int n=0;n<N_;n++){ w[n] = pad[n] ? 0.f : w[n]*inv; wsv += w[n]; }

    for (int d=lane; d<D_; d+=64){
        float acc = 0.f;
        #pragma unroll
        for (int n=0;n<N_;n++) acc += w[n] * s_nei[wv][n][d];
        wnei[(size_t)al*KC + d] = f2b(acc);
    }
    if (lane < 24) wnei[(size_t)al*KC + 200 + lane] = 0;
    if (lane==0) wsum[al] = wsv;
}

// r>=1 attention weights: softmax over 6 neighbors, scatter into dense S[b][l][l'] (bf16)
// 16 atoms per 256-thread block; 16 threads zero each row, thread sub==0 scatters.
__global__ void __launch_bounds__(256) k_attnw(const float* __restrict__ s1,
        const float* __restrict__ tb, const int* __restrict__ adl,
        const float* __restrict__ b_align, int r,
        unsigned short* __restrict__ S, float* __restrict__ wsum){
    int tid = threadIdx.x;
    int a = tid >> 4, sub = tid & 15;
    int al = blockIdx.x*16 + a;
    uint4 z; z.x=0; z.y=0; z.z=0; z.w=0;
    ((uint4*)(S + (size_t)al*L_))[sub] = z;
    __syncthreads();
    if (sub == 0){
        int bi = al >> 7;
        float bav = b_align[r];
        float s1v = s1[al];
        int idxn[N_]; bool pad[N_]; float s2[N_];
        for (int n=0;n<N_;n++){
            idxn[n] = adl[al*N_ + n];
            pad[n] = (idxn[n] == L_-1);
            s2[n] = tb[bi*L_ + idxn[n]];
        }
        float aa[N_]; float mx = -1e30f;
        for (int n=0;n<N_;n++){
            float v = lreluf(s1v + s2[n] + bav);
            if (pad[n]) v += NEGV;
            aa[n] = v; mx = fmaxf(mx, v);
        }
        float w[N_]; float se=0.f;
        for (int n=0;n<N_;n++){ float e = expf(aa[n]-mx); w[n]=e; se+=e; }
        float inv = 1.f/se; float wsv = 0.f;
        unsigned short* Srow = S + (size_t)al*L_;
        for (int n=0;n<N_;n++){
            if (!pad[n]){
                float wv = w[n]*inv;
                wsv += wv;
                int cidx = idxn[n];
                Srow[cidx] = f2b(bu2f(Srow[cidx]) + wv);
            }
        }
        wsum[al] = wsv;
    }
}

// MFMA: curWT[d][al] = sum_k Wat[r][k][d]*cur16[al][k]  (i.e. (cur@Wat)^T), d in [0,256)
__global__ void __launch_bounds__(256) k_curwT(const unsigned short* __restrict__ cur16,
        const unsigned short* __restrict__ WatT, int r, unsigned short* __restrict__ curWT){
    __shared__ unsigned short As[128][40];
    __shared__ unsigned short Bs[128][40];
    int tid = threadIdx.x;
    int m0 = ((int)blockIdx.x & 1) * 128;           // d tile
    int n0 = ((int)blockIdx.x >> 1) * 128;          // atom tile
    const unsigned short* At = WatT + (size_t)r*NC*KC;
    int lane = tid & 63, wv = tid >> 6;
    int quad = lane >> 4, lm = lane & 15;
    f32x4 acc[2][8];
    #pragma unroll
    for (int x=0;x<2;x++)
        #pragma unroll
        for (int y=0;y<8;y++) acc[x][y] = (f32x4){0.f,0.f,0.f,0.f};
    for (int ks = 0; ks < 7; ks++){
        int r0_ = tid >> 2, c0 = (tid & 3) * 8;
        int r1_ = (tid + 256) >> 2, c1 = ((tid + 256) & 3) * 8;
        uint4 a0 = *(const uint4*)&At[(size_t)(m0 + r0_)*KC + ks*32 + c0];
        uint4 a1 = *(const uint4*)&At[(size_t)(m0 + r1_)*KC + ks*32 + c1];
        uint4 b0 = *(const uint4*)&cur16[(size_t)(n0 + r0_)*KC + ks*32 + c0];
        uint4 b1 = *(const uint4*)&cur16[(size_t)(n0 + r1_)*KC + ks*32 + c1];
        __syncthreads();
        *(uint4*)&As[r0_][c0] = a0;
        *(uint4*)&As[r1_][c1] = a1;
        *(uint4*)&Bs[r0_][c0] = b0;
        *(uint4*)&Bs[r1_][c1] = b1;
        __syncthreads();
        short8 av0 = *(const short8*)&As[wv*32 + lm][quad*8];
        short8 av1 = *(const short8*)&As[wv*32 + 16 + lm][quad*8];
        #pragma unroll
        for (int ns=0; ns<8; ns++){
            short8 bv = *(const short8*)&Bs[ns*16 + lm][quad*8];
            acc[0][ns] = __builtin_amdgcn_mfma_f32_16x16x32_bf16(av0, bv, acc[0][ns], 0,0,0);
            acc[1][ns] = __builtin_amdgcn_mfma_f32_16x16x32_bf16(av1, bv, acc[1][ns], 0,0,0);
        }
    }
    #pragma unroll
    for (int ms=0; ms<2; ms++)
      #pragma unroll
      for (int ns=0; ns<8; ns++)
        #pragma unroll
        for (int i=0;i<4;i++){
            int d = m0 + wv*32 + ms*16 + quad*4 + i;
            int al = n0 + ns*16 + lm;
            curWT[(size_t)d*BL_ + al] = f2b(acc[ms][ns][i]);
        }
}

// MFMA: ctx = elu(S[b] @ curW + wsum*bias) -> XH x-half. Per-molecule dense attention GEMM.
__global__ void __launch_bounds__(256) k_sattn(const unsigned short* __restrict__ S,
        const unsigned short* __restrict__ curWT, const float* __restrict__ wsum,
        const float* __restrict__ b_attend, int r, unsigned short* __restrict__ XH){
    __shared__ unsigned short As[128][40];
    __shared__ unsigned short Bs[128][40];
    int tid = threadIdx.x;
    int b = (int)blockIdx.x >> 1;
    int n0 = ((int)blockIdx.x & 1) * 128;           // d tile
    const unsigned short* Sb = S + (size_t)b*L_*L_;
    int lane = tid & 63, wv = tid >> 6;
    int quad = lane >> 4, lm = lane & 15;
    f32x4 acc[2][8];
    #pragma unroll
    for (int x=0;x<2;x++)
        #pragma unroll
        for (int y=0;y<8;y++) acc[x][y] = (f32x4){0.f,0.f,0.f,0.f};
    for (int ks = 0; ks < 4; ks++){
        int r0_ = tid >> 2, c0 = (tid & 3) * 8;
        int r1_ = (tid + 256) >> 2, c1 = ((tid + 256) & 3) * 8;
        uint4 a0 = *(const uint4*)&Sb[(size_t)r0_*L_ + ks*32 + c0];
        uint4 a1 = *(const uint4*)&Sb[(size_t)r1_*L_ + ks*32 + c1];
        uint4 b0 = *(const uint4*)&curWT[(size_t)(n0 + r0_)*BL_ + b*L_ + ks*32 + c0];
        uint4 b1 = *(const uint4*)&curWT[(size_t)(n0 + r1_)*BL_ + b*L_ + ks*32 + c1];
        __syncthreads();
        *(uint4*)&As[r0_][c0] = a0;
        *(uint4*)&As[r1_][c1] = a1;
        *(uint4*)&Bs[r0_][c0] = b0;
        *(uint4*)&Bs[r1_][c1] = b1;
        __syncthreads();
        short8 av0 = *(const short8*)&As[wv*32 + lm][quad*8];
        short8 av1 = *(const short8*)&As[wv*32 + 16 + lm][quad*8];
        #pragma unroll
        for (int ns=0; ns<8; ns++){
            short8 bv = *(const short8*)&Bs[ns*16 + lm][quad*8];
            acc[0][ns] = __builtin_amdgcn_mfma_f32_16x16x32_bf16(av0, bv, acc[0][ns], 0,0,0);
            acc[1][ns] = __builtin_amdgcn_mfma_f32_16x16x32_bf16(av1, bv, acc[1][ns], 0,0,0);
        }
    }
    #pragma unroll
    for (int ms=0; ms<2; ms++)
      #pragma unroll
      for (int ns=0; ns<8; ns++){
        int n = n0 + ns*16 + lm;
        if (n < 200){
            float bv = b_attend[r*D_ + n];
            #pragma unroll
            for (int i=0;i<4;i++){
                int l = wv*32 + ms*16 + quad*4 + i;
                int al = b*L_ + l;
                XH[(size_t)al*KP + n] = f2b(eluf(acc[ms][ns][i] + wsum[al]*bv));
            }
        }
      }
}

// MFMA ctx GEMM (round 0 only): elu(wnei @ WatT[0]^T + wsum*bias) -> XH x-half. 128x64 tile.
__global__ void __launch_bounds__(256) k_ctxmfma(const unsigned short* __restrict__ Wn,
        const float* __restrict__ wsum, const unsigned short* __restrict__ WatT,
        const float* __restrict__ bias, unsigned short* __restrict__ XH){
    __shared__ unsigned short As[128][40];
    __shared__ unsigned short Bs[64][40];
    int tid = threadIdx.x;
    int m0 = ((int)blockIdx.x & 127) * 128;
    int n0 = ((int)blockIdx.x >> 7) * 64;
    const unsigned short* Bt = WatT;
    int lane = tid & 63, wv = tid >> 6;
    int quad = lane >> 4, lm = lane & 15;
    f32x4 acc[2][4];
    #pragma unroll
    for (int a=0;a<2;a++)
        #pragma unroll
        for (int b=0;b<4;b++) acc[a][b] = (f32x4){0.f,0.f,0.f,0.f};
    for (int ks = 0; ks < 7; ks++){
        int s0 = tid, s1_ = tid + 256;
        int r0_ = s0 >> 2, c0 = (s0 & 3) * 8;
        int r1_ = s1_ >> 2, c1 = (s1_ & 3) * 8;
        uint4 a0 = *(const uint4*)&Wn[(size_t)(m0 + r0_)*KC + ks*32 + c0];
        uint4 a1 = *(const uint4*)&Wn[(size_t)(m0 + r1_)*KC + ks*32 + c1];
        uint4 b0 = *(const uint4*)&Bt[(size_t)(n0 + (tid >> 2))*KC + ks*32 + (tid & 3)*8];
        __syncthreads();
        *(uint4*)&As[r0_][c0] = a0;
        *(uint4*)&As[r1_][c1] = a1;
        *(uint4*)&Bs[tid >> 2][(tid & 3)*8] = b0;
        __syncthreads();
        short8 av0 = *(const short8*)&As[wv*32 + lm][quad*8];
        short8 av1 = *(const short8*)&As[wv*32 + 16 + lm][quad*8];
        #pragma unroll
        for (int ns=0; ns<4; ns++){
            short8 bv = *(const short8*)&Bs[ns*16 + lm][quad*8];
            acc[0][ns] = __builtin_amdgcn_mfma_f32_16x16x32_bf16(av0, bv, acc[0][ns], 0,0,0);
            acc[1][ns] = __builtin_amdgcn_mfma_f32_16x16x32_bf16(av1, bv, acc[1][ns], 0,0,0);
        }
    }
    #pragma unroll
    for (int ms=0; ms<2; ms++)
      #pragma unroll
      for (int ns=0; ns<4; ns++){
        int n = n0 + ns*16 + lm;
        if (n < 200){
            float bv = bias[n];
            #pragma unroll
            for (int i=0;i<4;i++){
                int row = m0 + wv*32 + ms*16 + quad*4 + i;
                float v = acc[ms][ns][i] + wsum[row]*bv;
                XH[(size_t)row*KP + n] = f2b(eluf(v));
            }
        }
      }
}

// MFMA gate GEMM: C[16384,NP] = XH @ B2t[r]^T. 128x128 tile.
__global__ void __launch_bounds__(256) k_gemm(const unsigned short* __restrict__ XH,
        const unsigned short* __restrict__ B2t, unsigned short* __restrict__ C, int r){
    __shared__ unsigned short As[128][40];
    __shared__ unsigned short Bs[128][40];
    int tid = threadIdx.x;
    int m0 = ((int)blockIdx.x & 127) * 128;
    int n0 = ((int)blockIdx.x >> 7) * 128;
    const unsigned short* Bt = B2t + (size_t)r*NP*KP;
    int lane = tid & 63, wv = tid >> 6;
    int quad = lane >> 4, lm = lane & 15;
    f32x4 acc[2][8];
    #pragma unroll
    for (int a=0;a<2;a++)
        #pragma unroll
        for (int b=0;b<8;b++) acc[a][b] = (f32x4){0.f,0.f,0.f,0.f};
    for (int ks = 0; ks < 13; ks++){
        int s0 = tid, s1_ = tid + 256;
        int r0_ = s0 >> 2, c0 = (s0 & 3) * 8;
        int r1_ = s1_ >> 2, c1 = (s1_ & 3) * 8;
        uint4 a0 = *(const uint4*)&XH[(size_t)(m0 + r0_)*KP + ks*32 + c0];
        uint4 a1 = *(const uint4*)&XH[(size_t)(m0 + r1_)*KP + ks*32 + c1];
        uint4 b0 = *(const uint4*)&Bt[(size_t)(n0 + r0_)*KP + ks*32 + c0];
        uint4 b1 = *(const uint4*)&Bt[(size_t)(n0 + r1_)*KP + ks*32 + c1];
        __syncthreads();
        *(uint4*)&As[r0_][c0] = a0;
        *(uint4*)&As[r1_][c1] = a1;
        *(uint4*)&Bs[r0_][c0] = b0;
        *(uint4*)&Bs[r1_][c1] = b1;
        __syncthreads();
        short8 av0 = *(const short8*)&As[wv*32 + lm][quad*8];
        short8 av1 = *(const short8*)&As[wv*32 + 16 + lm][quad*8];
        #pragma unroll
        for (int ns=0; ns<8; ns++){
            short8 bv = *(const short8*)&Bs[ns*16 + lm][quad*8];
            acc[0][ns] = __builtin_amdgcn_mfma_f32_16x16x32_bf16(av0, bv, acc[0][ns], 0,0,0);
            acc[1][ns] = __builtin_amdgcn_mfma_f32_16x16x32_bf16(av1, bv, acc[1][ns], 0,0,0);
        }
    }
    #pragma unroll
    for (int ms=0; ms<2; ms++)
      #pragma unroll
      for (int ns=0; ns<8; ns++)
        #pragma unroll
        for (int i=0;i<4;i++){
            int row = m0 + wv*32 + ms*16 + quad*4 + i;
            C[(size_t)row*NP + n0 + ns*16 + lm] = f2b(acc[ms][ns][i]);
        }
}

// GRU combine, wave-per-atom; writes cur fp32 + cur16 (r<2) + XH h-half;
// fuses next-round s1/tb dots (r<2) or curdot (r==2)
__global__ void __launch_bounds__(256) k_gru2(const unsigned short* __restrict__ C,
        float* __restrict__ h, float* __restrict__ cur, unsigned short* __restrict__ XH,
        unsigned short* __restrict__ cur16,
        const float* __restrict__ bih, const float* __restrict__ bhh,
        const float* __restrict__ W_align, const float* __restrict__ Wma, int r,
        float* __restrict__ s1, float* __restrict__ tb, float* __restrict__ curdot){
    int wv = threadIdx.x >> 6, lane = threadIdx.x & 63;
    int al = blockIdx.x*4 + wv;
    size_t base = (size_t)al*NP;
    const float* bi = bih + r*G3D_;
    const float* bh = bhh + r*G3D_;
    const float* Wa = W_align + (r+1)*2*D_;   // dereferenced only when r<2
    bool last = (r == R_-1);
    float a1 = 0.f, a2 = 0.f;
    for (int j = lane; j < D_; j += 64){
        float rsum = bu2f(C[base + j]);
        float zsum = bu2f(C[base + 200 + j]);
        float gin  = bu2f(C[base + 400 + j]);
        float ghn  = bu2f(C[base + 600 + j]);
        float rr = sigmf(rsum + bi[j] + bh[j]);
        float zz = sigmf(zsum + bi[D_+j] + bh[D_+j]);
        float nn = tanhf(gin + bi[2*D_+j] + rr*(ghn + bh[2*D_+j]));
        size_t gi = (size_t)al*D_ + j;
        float hv = h[gi];
        float hn = (1.f-zz)*nn + zz*hv;
        h[gi] = hn;
        float cv = fmaxf(hn, 0.f);
        cur[gi] = cv;
        XH[(size_t)al*KP + 200 + j] = f2b(hn);
        if (!last) cur16[(size_t)al*KC + j] = f2b(cv);
        if (last){
            a1 += cv * Wma[D_+j];
        } else {
            a1 += cv * Wa[j];
            a2 += cv * Wa[D_+j];
        }
    }
    if (!last && lane < 24) cur16[(size_t)al*KC + 200 + lane] = 0;
    for (int o=32;o>0;o>>=1){ a1 += __shfl_xor(a1,o); a2 += __shfl_xor(a2,o); }
    if (lane==0){
        if (last) curdot[al] = a1;
        else { s1[al] = a1; tb[al] = a2; }
    }
}

__device__ __forceinline__ float brSum(float v, float* s_red){
    for (int o=32;o>0;o>>=1) v += __shfl_xor(v,o);
    int lane = threadIdx.x & 63, wid = threadIdx.x >> 6;
    __syncthreads();
    if (lane==0) s_red[wid] = v;
    __syncthreads();
    float r = 0.f;
    int nw = blockDim.x >> 6;
    for (int i=0;i<nw;i++) r += s_red[i];
    return r;
}

__device__ __forceinline__ float brMax(float v, float* s_red){
    for (int o=32;o>0;o>>=1) v = fmaxf(v, __shfl_xor(v,o));
    int lane = threadIdx.x & 63, wid = threadIdx.x >> 6;
    __syncthreads();
    if (lane==0) s_red[wid] = v;
    __syncthreads();
    float r = s_red[0];
    int nw = blockDim.x >> 6;
    for (int i=1;i<nw;i++) r = fmaxf(r, s_red[i]);
    return r;
}

// molecule phase (proven 256-thread round-7/9 version)
__global__ void __launch_bounds__(256) k_mol(const float* __restrict__ cur,
    const float* __restrict__ curdot, const float* __restrict__ atom_mask,
    const float* __restrict__ Wma, const float* __restrict__ bma,
    const float* __restrict__ Wmt, const float* __restrict__ bmt,
    const float* __restrict__ mTi, const float* __restrict__ mTh,
    const float* __restrict__ mbih, const float* __restrict__ mbhh,
    const float* __restrict__ Wme, const float* __restrict__ bme,
    const float* __restrict__ Wout, const float* __restrict__ bout,
    void* __restrict__ out, const unsigned* __restrict__ amtag){
    int b = blockIdx.x, tid = threadIdx.x;
    __shared__ float s_am[L_], s_neg[L_], s_cd[L_], s_w[L_];
    __shared__ float s_mf[D_], s_act[D_], s_wc[D_], s_ctx[D_];
    __shared__ float s_gi[G3D_], s_gh[G3D_], s_red[8];
    const float* curb = cur + (size_t)b*L_*D_;
    if (tid < L_){
        float am = atom_mask[b*L_ + tid];
        s_am[tid] = am;
        s_neg[tid] = (am == 0.f) ? NEGV : 0.f;
        s_cd[tid] = curdot[b*L_ + tid];
    }
    __syncthreads();
    for (int d=tid; d<D_; d+=256){
        float acc = 0.f;
        for (int l=0;l<L_;l++) acc += curb[l*D_ + d] * s_am[l];
        s_mf[d] = acc; s_act[d] = fmaxf(acc, 0.f);
    }
    __syncthreads();
    float bma0 = bma[0];
    for (int t=0;t<T_;t++){
        float p = 0.f;
        for (int d=tid; d<D_; d+=256) p += s_act[d] * Wma[d];
        float s1v = brSum(p, s_red);
        float sc = (tid < L_) ? (lreluf(s1v + s_cd[tid] + bma0) + s_neg[tid]) : -1e30f;
        float mx = brMax(sc, s_red);
        float e = (tid < L_) ? expf(sc - mx) : 0.f;
        float se = brSum(e, s_red);
        float wv_ = (tid < L_) ? e/se*s_am[tid] : 0.f;
        if (tid < L_) s_w[tid] = wv_;
        float wsm = brSum(wv_, s_red);
        __syncthreads();
        for (int d=tid; d<D_; d+=256){
            float acc = 0.f;
            for (int l=0;l<L_;l++) acc += s_w[l]*curb[l*D_ + d];
            s_wc[d] = acc;
        }
        __syncthreads();
        if (tid < D_){
            float acc = wsm * bmt[tid];
            for (int k=0;k<D_;k++) acc += s_wc[k] * Wmt[k*D_ + tid];
            s_ctx[tid] = eluf(acc);
        }
        __syncthreads();
        for (int j=tid; j<G3D_; j+=256){
            float ai0=0.f, ai1=0.f, ah0=0.f, ah1=0.f;
            for (int k=0;k<D_;k+=2){
                ai0 += s_ctx[k]   * mTi[(size_t)k*G3D_ + j];
                ai1 += s_ctx[k+1] * mTi[(size_t)(k+1)*G3D_ + j];
                ah0 += s_mf[k]    * mTh[(size_t)k*G3D_ + j];
                ah1 += s_mf[k+1]  * mTh[(size_t)(k+1)*G3D_ + j];
            }
            s_gi[j] = ai0+ai1; s_gh[j] = ah0+ah1;
        }
        __syncthreads();
        if (tid < D_){
            int d = tid;
            float rr = sigmf(s_gi[d] + mbih[d] + s_gh[d] + mbhh[d]);
            float zz = sigmf(s_gi[D_+d] + mbih[D_+d] + s_gh[D_+d] + mbhh[D_+d]);
            float nn = tanhf(s_gi[2*D_+d] + mbih[2*D_+d] + rr*(s_gh[2*D_+d] + mbhh[2*D_+d]));
            float nm = (1.f-zz)*nn + zz*s_mf[d];
            s_mf[d] = nm; s_act[d] = fmaxf(nm, 0.f);
        }
        __syncthreads();
    }
    const float dd = (float)(R_ - 2);
    float p = 0.f;
    for (int d=tid; d<D_; d+=256){
        float acc = bme[d];
        for (int k=0;k<D_;k++){
            float mf = s_mf[k];
            acc += mf * Wme[k*D_ + d];
            acc += (mf + dd) * Wme[(D_+k)*D_ + d];
        }
        p += acc * Wout[d];
    }
    float o = brSum(p, s_red);
    if (tid==0){
        o += bout[0];
        if (*amtag == FP32TAG) ((float*)out)[b] = o;
        else ((bf16*)out)[b] = __float2bfloat16(o);
    }
}

extern "C" void kernel_launch(void* const* d_in, const int* in_sizes, int n_in,
                              void* d_out, int out_size, void* d_ws, size_t ws_size,
                              hipStream_t stream) {
    const int* adl = (const int*)d_in[2];
    const int* bdl = (const int*)d_in[3];
    const unsigned* amtag = (const unsigned*)d_in[4];

    static const int srcidx[NSEG] = {0,1,4,5,6,7,8,9,10,11,12,15,16,17,18,19,20,21,22,23,24,25,26,27,28};
    static const int segsz[NSEG]  = {638976,327680,16384,7800,200,9800,200,1200,3,120000,600,
                                     1800,1800,400,1,40000,200,120000,120000,600,600,80000,200,200,1};
    CvtArgs ca;
    int ofs[NSEG+1]; ofs[0] = 0;
    for (int i=0;i<NSEG;i++){ ca.src[i] = d_in[srcidx[i]]; ca.ofs[i] = ofs[i]; ofs[i+1] = ofs[i] + segsz[i]; }
    ca.ofs[NSEG] = ofs[NSEG];
    const int total = ofs[NSEG];           // 1488645

    // ws layout (floats; offsets 16B aligned). ~86.3 MB total.
    float* ws   = (float*)d_ws;
    float* conv = ws;                                    // 1488648
    float* h    = conv + 1488648;                        // BLD_
    float* cur  = h + BLD_;                              // BLD_
    unsigned short* XH   = (unsigned short*)(cur + BLD_);        // BL_*KP sh
    unsigned short* B2t  = XH + (size_t)BL_*KP;                  // PREPB_N sh
    unsigned short* WatT = B2t + PREPB_N;                        // PREPW_N sh
    float* creg = (float*)(WatT + PREPW_N);              // C region: BL_*NP sh = 7340032 fl
    unsigned short* C = (unsigned short*)creg;
    unsigned short* wnei  = (unsigned short*)creg;       // r0: BL_*KC sh, overlays C head
    unsigned short* curWT = (unsigned short*)creg;       // r>=1: 256*BL_ sh, overlays C head
    unsigned short* S = (unsigned short*)creg + 4194304; // r>=1: B_*L_*L_ sh
    float* P    = creg + 1900032;                        // BLD_, overlays C mid (r0 only)
    float* s1   = creg + 7340032;
    float* tb   = s1 + BL_;
    float* wsum = tb + BL_;
    float* curdot = wsum + BL_;                          // BL_
    float* mTi  = curdot + BL_;                          // 120000
    float* mTh  = mTi + PREPM_N;
    unsigned short* cur16 = (unsigned short*)(mTh + PREPM_N);    // BL_*KC sh

    const float* c_atom  = conv + ofs[0];
    const float* c_bond  = conv + ofs[1];
    const float* c_amask = conv + ofs[2];
    const float* c_Watom = conv + ofs[3];
    const float* c_batom = conv + ofs[4];
    const float* c_Wnei  = conv + ofs[5];
    const float* c_bnei  = conv + ofs[6];
    const float* c_Walign= conv + ofs[7];
    const float* c_balign= conv + ofs[8];
    const float* c_batt  = conv + ofs[10];
    const float* c_bih   = conv + ofs[11];
    const float* c_bhh   = conv + ofs[12];
    const float* c_Wma   = conv + ofs[13];
    const float* c_bma   = conv + ofs[14];
    const float* c_Wmt   = conv + ofs[15];
    const float* c_bmt   = conv + ofs[16];
    const float* c_mbih  = conv + ofs[19];
    const float* c_mbhh  = conv + ofs[20];
    const float* c_Wme   = conv + ofs[21];
    const float* c_bme   = conv + ofs[22];
    const float* c_Wout  = conv + ofs[23];
    const float* c_bout  = conv + ofs[24];

    const int prep_total = total + PREPB_N + PREPW_N + PREPM_N;   // 2898885
    k_prep<<<(prep_total + 255)/256, 256, 0, stream>>>(ca, conv, d_in[13], d_in[14], B2t,
                                                       d_in[11], WatT, d_in[21], d_in[22],
                                                       mTi, mTh, amtag, total);
    k_init<<<BL_/4, 256, 0, stream>>>(c_atom, c_Watom, c_batom, c_Wnei, c_bnei, c_Walign,
                                      h, cur, XH, P, s1, tb);

    for (int r=0; r<R_; r++){
        if (r == 0){
            k_attn<<<BL_/4, 256, 0, stream>>>(s1, tb, adl, bdl, P, c_bond,
                                              c_Wnei, c_Walign, c_balign, wnei, wsum);
            k_ctxmfma<<<(BL_/128)*(NC/64), 256, 0, stream>>>(wnei, wsum, WatT, c_batt, XH);
        } else {
            k_attnw<<<BL_/16, 256, 0, stream>>>(s1, tb, adl, c_balign, r, S, wsum);
            k_curwT<<<2*(BL_/128), 256, 0, stream>>>(cur16, WatT, r, curWT);
            k_sattn<<<B_*2, 256, 0, stream>>>(S, curWT, wsum, c_batt, r, XH);
        }
        k_gemm<<<(BL_/128)*(NP/128), 256, 0, stream>>>(XH, B2t, C, r);
        k_gru2<<<BL_/4, 256, 0, stream>>>(C, h, cur, XH, cur16, c_bih, c_bhh,
                                          c_Walign, c_Wma, r, s1, tb, curdot);
    }

    k_mol<<<B_, 256, 0, stream>>>(cur, curdot, c_amask, c_Wma, c_bma, c_Wmt, c_bmt,
                                  mTi, mTh, c_mbih, c_mbhh, c_Wme, c_bme, c_Wout, c_bout,
                                  d_out, amtag);
}

// Round 12
// 544.673 us; speedup vs baseline: 1.0789x; 1.0515x over previous
//
#include <hip/hip_runtime.h>
#include <hip/hip_bf16.h>
#include <math.h>
#include <string.h>

#define B_ 128
#define L_ 128
#define N_ 6
#define FA_ 39
#define FB_ 10
#define D_ 200
#define MB_ 256
#define R_ 3
#define T_ 2
#define NEGV -9e8f
#define BL_ (B_*L_)        // 16384
#define BLD_ (BL_*D_)      // 3276800
#define G3D_ (3*D_)        // 600
#define FP32TAG 0x3F800000u
#define KP 416             // padded K for gate GEMM (400 -> 416 = 13*32)
#define NP 896             // padded N for gate GEMM (800 -> 896 = 7*128)
#define KC 224             // padded K for ctx GEMM (200 -> 224 = 7*32)
#define NC 256             // padded N for ctx GEMM (200 -> 256)

typedef __hip_bfloat16 bf16;
typedef __attribute__((ext_vector_type(8))) short short8;
typedef __attribute__((ext_vector_type(4))) float f32x4;

__device__ __forceinline__ float b2f(const bf16 x){ return __bfloat162float(x); }
__device__ __forceinline__ unsigned short f2b(float v){ bf16 t = __float2bfloat16(v); return *reinterpret_cast<unsigned short*>(&t); }
__device__ __forceinline__ float bu2f(unsigned short u){ unsigned x = ((unsigned)u)<<16; float f; memcpy(&f,&x,4); return f; }
__device__ __forceinline__ float lreluf(float x){ return x>=0.f ? x : 0.01f*x; }
__device__ __forceinline__ float eluf(float x){ return x>0.f ? x : expm1f(x); }
__device__ __forceinline__ float sigmf(float x){ return 1.f/(1.f+expf(-x)); }

#define NSEG 25
struct CvtArgs { const void* src[NSEG]; int ofs[NSEG+1]; };

#define PREPB_N (R_*NP*KP)     // 1118208
#define PREPW_N (R_*NC*KC)     // 172032
#define PREPM_N (D_*G3D_)      // 120000

// merged prep: convert -> B2t (atom gate W) -> WatT (atom ctx W) -> mTi/mTh (mol GRU transpose)
__global__ void k_prep(CvtArgs c, float* __restrict__ dst,
                       const void* __restrict__ Wih, const void* __restrict__ Whh,
                       unsigned short* __restrict__ B2t,
                       const void* __restrict__ Watt_r, unsigned short* __restrict__ WatT,
                       const void* __restrict__ mWih_r, const void* __restrict__ mWhh_r,
                       float* __restrict__ mTi, float* __restrict__ mTh,
                       const unsigned* __restrict__ amtag, int total){
    int i = blockIdx.x*blockDim.x + threadIdx.x;
    bool f32 = (*amtag == FP32TAG);
    if (i < total){
        int s = 0;
        while (i >= c.ofs[s+1]) s++;
        int j = i - c.ofs[s];
        dst[i] = f32 ? ((const float*)c.src[s])[j] : b2f(((const bf16*)c.src[s])[j]);
        return;
    }
    int i2 = i - total;
    if (i2 < PREPB_N){
        int kk = i2 % KP;
        int rest = i2 / KP;
        int n = rest % NP;
        int r = rest / NP;
        float v = 0.f;
        if (kk < 200){
            if (n < 600){
                size_t si = ((size_t)(r*G3D_ + n))*D_ + kk;
                v = f32 ? ((const float*)Wih)[si] : b2f(((const bf16*)Wih)[si]);
            }
        } else if (kk < 400){
            int j = -1;
            if (n < 400) j = n;
            else if (n >= 600 && n < 800) j = n - 200;
            if (j >= 0){
                size_t si = ((size_t)(r*G3D_ + j))*D_ + (kk-200);
                v = f32 ? ((const float*)Whh)[si] : b2f(((const bf16*)Whh)[si]);
            }
        }
        B2t[i2] = f2b(v);
        return;
    }
    int i3 = i2 - PREPB_N;
    if (i3 < PREPW_N){
        int kk = i3 % KC;
        int rest = i3 / KC;
        int n = rest % NC;
        int r = rest / NC;
        float v = 0.f;
        if (kk < 200 && n < 200){
            size_t si = ((size_t)r*D_ + kk)*D_ + n;
            v = f32 ? ((const float*)Watt_r)[si] : b2f(((const bf16*)Watt_r)[si]);
        }
        WatT[i3] = f2b(v);
        return;
    }
    int i4 = i3 - PREPW_N;
    if (i4 < PREPM_N){
        int j = i4 % G3D_, k = i4 / G3D_;
        size_t si = (size_t)j*D_ + k;
        mTi[i4] = f32 ? ((const float*)mWih_r)[si] : b2f(((const bf16*)mWih_r)[si]);
        mTh[i4] = f32 ? ((const float*)mWhh_r)[si] : b2f(((const bf16*)mWhh_r)[si]);
    }
}

// Q16[row][d] = bond_list[row] @ W_nei[FA:FA+FB]  (bond half of r0 nei features, no bias)
__global__ void k_qprep(const float* __restrict__ bond_list, const float* __restrict__ W_nei,
                        unsigned short* __restrict__ Q16){
    int idx = blockIdx.x*blockDim.x + threadIdx.x;
    if (idx >= B_*MB_*D_) return;
    int d = idx % D_;
    int row = idx / D_;
    const float* br = bond_list + (size_t)row*FB_;
    const float* Wb = W_nei + FA_*D_;
    float acc = 0.f;
    #pragma unroll
    for (int k=0;k<FB_;k++) acc += br[k] * Wb[k*D_ + d];
    Q16[idx] = f2b(acc);
}

// fused init, wave-per-atom: atom_feature -> h + XH h-half + pad; P16 bf16; round-0 s1/tb dots
__global__ void __launch_bounds__(256) k_init(const float* __restrict__ atom_list,
                       const float* __restrict__ W_atom, const float* __restrict__ b_atom,
                       const float* __restrict__ W_nei, const float* __restrict__ b_nei,
                       const float* __restrict__ W_align,
                       float* __restrict__ h, unsigned short* __restrict__ XH,
                       unsigned short* __restrict__ P16,
                       float* __restrict__ s1, float* __restrict__ tb){
    int wv = threadIdx.x >> 6, lane = threadIdx.x & 63;
    int al = blockIdx.x*4 + wv;
    const float* arow = atom_list + (size_t)al*FA_;
    float a1 = 0.f, a2 = 0.f;
    for (int d = lane; d < D_; d += 64){
        float acc1 = b_atom[d], acc2 = b_nei[d];
        for (int k=0;k<FA_;k++){
            float a = arow[k];
            acc1 += a * W_atom[k*D_ + d];
            acc2 += a * W_nei[k*D_ + d];
        }
        float v = lreluf(acc1);
        size_t gi = (size_t)al*D_ + d;
        h[gi] = v;
        XH[(size_t)al*KP + 200 + d] = f2b(v);
        P16[gi] = f2b(acc2);
        a1 += v * W_align[d];
        a2 += v * W_align[D_ + d];
    }
    if (lane < 16) XH[(size_t)al*KP + 400 + lane] = 0;
    for (int o=32;o>0;o>>=1){ a1 += __shfl_xor(a1,o); a2 += __shfl_xor(a2,o); }
    if (lane==0){ s1[al] = a1; tb[al] = a2; }
}

// attention (all rounds): softmax + weighted neighbor sum -> bf16 wnei (stride KC, zero pad).
// XCD-locality swizzle: mol = bid&127 so all 32 blocks of a molecule share one XCD L2.
// r==0: nei = lrelu(P16[atom] + Q16[bond]); r>=1: gather cur16.
__global__ void __launch_bounds__(256) k_attn(
        const unsigned short* __restrict__ cur16,
        const float* __restrict__ s1, const float* __restrict__ tb,
        const int* __restrict__ adl, const int* __restrict__ bdl,
        const unsigned short* __restrict__ P16, const unsigned short* __restrict__ Q16,
        const float* __restrict__ W_align, const float* __restrict__ b_align, int r,
        unsigned short* __restrict__ wnei, float* __restrict__ wsum){
    int bid = blockIdx.x;
    int mol = bid & (B_-1), chunk = bid >> 7;
    int wv = threadIdx.x >> 6, lane = threadIdx.x & 63;
    int al = mol*L_ + chunk*4 + wv;
    __shared__ float s_nei[4][N_][D_];

    int idxn[N_]; bool pad[N_];
    for (int n=0;n<N_;n++){ idxn[n] = adl[al*N_ + n]; pad[n] = (idxn[n] == L_-1); }

    float s2[N_];
    if (r == 0){
        for (int j = lane; j < N_*D_; j += 64){
            int n = j / D_, d = j - n*D_;
            int bd = bdl[al*N_ + n];
            float acc = bu2f(P16[((size_t)mol*L_ + idxn[n])*D_ + d])
                      + bu2f(Q16[((size_t)mol*MB_ + bd)*D_ + d]);
            s_nei[wv][n][d] = lreluf(acc);
        }
        const float* Wab = W_align + D_;
        for (int n=0;n<N_;n++){
            float acc = 0.f;
            for (int d=lane; d<D_; d+=64) acc += s_nei[wv][n][d] * Wab[d];
            for (int o=32;o>0;o>>=1) acc += __shfl_xor(acc,o);
            s2[n] = acc;
        }
    } else {
        float tmp = 0.f;
        if (lane < N_) tmp = tb[mol*L_ + idxn[lane]];
        for (int n=0;n<N_;n++) s2[n] = __shfl(tmp, n);
    }

    float s1v = s1[al];
    float bav = b_align[r];
    float a[N_]; float mx = -1e30f;
    for (int n=0;n<N_;n++){
        float v = lreluf(s1v + s2[n] + bav);
        if (pad[n]) v += NEGV;
        a[n] = v; mx = fmaxf(mx, v);
    }
    float w[N_]; float se = 0.f;
    for (int n=0;n<N_;n++){ float e = expf(a[n]-mx); w[n]=e; se += e; }
    float inv = 1.f/se; float wsv = 0.f;
    for (int n=0;n<N_;n++){ w[n] = pad[n] ? 0.f : w[n]*inv; wsv += w[n]; }

    if (r == 0){
        for (int d=lane; d<D_; d+=64){
            float acc = 0.f;
            #pragma unroll
            for (int n=0;n<N_;n++) acc += w[n] * s_nei[wv][n][d];
            wnei[(size_t)al*KC + d] = f2b(acc);
        }
    } else {
        for (int d=lane; d<D_; d+=64){
            float acc = 0.f;
            #pragma unroll
            for (int n=0;n<N_;n++) acc += w[n] * bu2f(cur16[((size_t)mol*L_ + idxn[n])*KC + d]);
            wnei[(size_t)al*KC + d] = f2b(acc);
        }
    }
    if (lane < 24) wnei[(size_t)al*KC + 200 + lane] = 0;
    if (lane==0) wsum[al] = wsv;
}

// MFMA ctx GEMM: elu(wnei[16384,KC] @ WatT[r]^T + wsum*bias) -> XH x-half. 128x64 tile.
__global__ void __launch_bounds__(256) k_ctxmfma(const unsigned short* __restrict__ Wn,
        const float* __restrict__ wsum, const unsigned short* __restrict__ WatT,
        const float* __restrict__ bias, int r, unsigned short* __restrict__ XH){
    __shared__ unsigned short As[128][40];
    __shared__ unsigned short Bs[64][40];
    int tid = threadIdx.x;
    int m0 = ((int)blockIdx.x & 127) * 128;
    int n0 = ((int)blockIdx.x >> 7) * 64;
    const unsigned short* Bt = WatT + (size_t)r*NC*KC;
    int lane = tid & 63, wv = tid >> 6;
    int quad = lane >> 4, lm = lane & 15;
    f32x4 acc[2][4];
    #pragma unroll
    for (int a=0;a<2;a++)
        #pragma unroll
        for (int b=0;b<4;b++) acc[a][b] = (f32x4){0.f,0.f,0.f,0.f};
    for (int ks = 0; ks < 7; ks++){
        int r0_ = tid >> 2, c0 = (tid & 3) * 8;
        int r1_ = (tid + 256) >> 2, c1 = ((tid + 256) & 3) * 8;
        uint4 a0 = *(const uint4*)&Wn[(size_t)(m0 + r0_)*KC + ks*32 + c0];
        uint4 a1 = *(const uint4*)&Wn[(size_t)(m0 + r1_)*KC + ks*32 + c1];
        uint4 b0 = *(const uint4*)&Bt[(size_t)(n0 + (tid >> 2))*KC + ks*32 + (tid & 3)*8];
        __syncthreads();
        *(uint4*)&As[r0_][c0] = a0;
        *(uint4*)&As[r1_][c1] = a1;
        *(uint4*)&Bs[tid >> 2][(tid & 3)*8] = b0;
        __syncthreads();
        short8 av0 = *(const short8*)&As[wv*32 + lm][quad*8];
        short8 av1 = *(const short8*)&As[wv*32 + 16 + lm][quad*8];
        #pragma unroll
        for (int ns=0; ns<4; ns++){
            short8 bv = *(const short8*)&Bs[ns*16 + lm][quad*8];
            acc[0][ns] = __builtin_amdgcn_mfma_f32_16x16x32_bf16(av0, bv, acc[0][ns], 0,0,0);
            acc[1][ns] = __builtin_amdgcn_mfma_f32_16x16x32_bf16(av1, bv, acc[1][ns], 0,0,0);
        }
    }
    #pragma unroll
    for (int ms=0; ms<2; ms++)
      #pragma unroll
      for (int ns=0; ns<4; ns++){
        int n = n0 + ns*16 + lm;
        if (n < 200){
            float bv = bias[r*D_ + n];
            #pragma unroll
            for (int i=0;i<4;i++){
                int row = m0 + wv*32 + ms*16 + quad*4 + i;
                float v = acc[ms][ns][i] + wsum[row]*bv;
                XH[(size_t)row*KP + n] = f2b(eluf(v));
            }
        }
      }
}

// MFMA gate GEMM: C[16384,NP] = XH @ B2t[r]^T. 128x128 tile.
__global__ void __launch_bounds__(256) k_gemm(const unsigned short* __restrict__ XH,
        const unsigned short* __restrict__ B2t, unsigned short* __restrict__ C, int r){
    __shared__ unsigned short As[128][40];
    __shared__ unsigned short Bs[128][40];
    int tid = threadIdx.x;
    int m0 = ((int)blockIdx.x & 127) * 128;
    int n0 = ((int)blockIdx.x >> 7) * 128;
    const unsigned short* Bt = B2t + (size_t)r*NP*KP;
    int lane = tid & 63, wv = tid >> 6;
    int quad = lane >> 4, lm = lane & 15;
    f32x4 acc[2][8];
    #pragma unroll
    for (int a=0;a<2;a++)
        #pragma unroll
        for (int b=0;b<8;b++) acc[a][b] = (f32x4){0.f,0.f,0.f,0.f};
    for (int ks = 0; ks < 13; ks++){
        int r0_ = tid >> 2, c0 = (tid & 3) * 8;
        int r1_ = (tid + 256) >> 2, c1 = ((tid + 256) & 3) * 8;
        uint4 a0 = *(const uint4*)&XH[(size_t)(m0 + r0_)*KP + ks*32 + c0];
        uint4 a1 = *(const uint4*)&XH[(size_t)(m0 + r1_)*KP + ks*32 + c1];
        uint4 b0 = *(const uint4*)&Bt[(size_t)(n0 + r0_)*KP + ks*32 + c0];
        uint4 b1 = *(const uint4*)&Bt[(size_t)(n0 + r1_)*KP + ks*32 + c1];
        __syncthreads();
        *(uint4*)&As[r0_][c0] = a0;
        *(uint4*)&As[r1_][c1] = a1;
        *(uint4*)&Bs[r0_][c0] = b0;
        *(uint4*)&Bs[r1_][c1] = b1;
        __syncthreads();
        short8 av0 = *(const short8*)&As[wv*32 + lm][quad*8];
        short8 av1 = *(const short8*)&As[wv*32 + 16 + lm][quad*8];
        #pragma unroll
        for (int ns=0; ns<8; ns++){
            short8 bv = *(const short8*)&Bs[ns*16 + lm][quad*8];
            acc[0][ns] = __builtin_amdgcn_mfma_f32_16x16x32_bf16(av0, bv, acc[0][ns], 0,0,0);
            acc[1][ns] = __builtin_amdgcn_mfma_f32_16x16x32_bf16(av1, bv, acc[1][ns], 0,0,0);
        }
    }
    #pragma unroll
    for (int ms=0; ms<2; ms++)
      #pragma unroll
      for (int ns=0; ns<8; ns++)
        #pragma unroll
        for (int i=0;i<4;i++){
            int row = m0 + wv*32 + ms*16 + quad*4 + i;
            C[(size_t)row*NP + n0 + ns*16 + lm] = f2b(acc[ms][ns][i]);
        }
}

// GRU combine, wave-per-atom; writes h + XH h-half + cur16 (all rounds);
// fuses next-round s1/tb dots (r<2) or curdot (r==2)
__global__ void __launch_bounds__(256) k_gru2(const unsigned short* __restrict__ C,
        float* __restrict__ h, unsigned short* __restrict__ XH,
        unsigned short* __restrict__ cur16,
        const float* __restrict__ bih, const float* __restrict__ bhh,
        const float* __restrict__ W_align, const float* __restrict__ Wma, int r,
        float* __restrict__ s1, float* __restrict__ tb, float* __restrict__ curdot){
    int wv = threadIdx.x >> 6, lane = threadIdx.x & 63;
    int al = blockIdx.x*4 + wv;
    size_t base = (size_t)al*NP;
    const float* bi = bih + r*G3D_;
    const float* bh = bhh + r*G3D_;
    const float* Wa = W_align + (r+1)*2*D_;   // dereferenced only when r<2
    bool last = (r == R_-1);
    float a1 = 0.f, a2 = 0.f;
    for (int j = lane; j < D_; j += 64){
        float rsum = bu2f(C[base + j]);
        float zsum = bu2f(C[base + 200 + j]);
        float gin  = bu2f(C[base + 400 + j]);
        float ghn  = bu2f(C[base + 600 + j]);
        float rr = sigmf(rsum + bi[j] + bh[j]);
        float zz = sigmf(zsum + bi[D_+j] + bh[D_+j]);
        float nn = tanhf(gin + bi[2*D_+j] + rr*(ghn + bh[2*D_+j]));
        size_t gi = (size_t)al*D_ + j;
        float hv = h[gi];
        float hn = (1.f-zz)*nn + zz*hv;
        h[gi] = hn;
        float cv = fmaxf(hn, 0.f);
        XH[(size_t)al*KP + 200 + j] = f2b(hn);
        cur16[(size_t)al*KC + j] = f2b(cv);
        if (last){
            a1 += cv * Wma[D_+j];
        } else {
            a1 += cv * Wa[j];
            a2 += cv * Wa[D_+j];
        }
    }
    if (lane < 24) cur16[(size_t)al*KC + 200 + lane] = 0;
    for (int o=32;o>0;o>>=1){ a1 += __shfl_xor(a1,o); a2 += __shfl_xor(a2,o); }
    if (lane==0){
        if (last) curdot[al] = a1;
        else { s1[al] = a1; tb[al] = a2; }
    }
}

__device__ __forceinline__ float brSum(float v, float* s_red){
    for (int o=32;o>0;o>>=1) v += __shfl_xor(v,o);
    int lane = threadIdx.x & 63, wid = threadIdx.x >> 6;
    __syncthreads();
    if (lane==0) s_red[wid] = v;
    __syncthreads();
    float r = 0.f;
    int nw = blockDim.x >> 6;
    for (int i=0;i<nw;i++) r += s_red[i];
    return r;
}

__device__ __forceinline__ float brMax(float v, float* s_red){
    for (int o=32;o>0;o>>=1) v = fmaxf(v, __shfl_xor(v,o));
    int lane = threadIdx.x & 63, wid = threadIdx.x >> 6;
    __syncthreads();
    if (lane==0) s_red[wid] = v;
    __syncthreads();
    float r = s_red[0];
    int nw = blockDim.x >> 6;
    for (int i=1;i<nw;i++) r = fmaxf(r, s_red[i]);
    return r;
}

// molecule phase; bf16 cur16 tile staged in LDS (57 KB), pooling/wc loops run from LDS
__global__ void __launch_bounds__(256) k_mol(const unsigned short* __restrict__ cur16,
    const float* __restrict__ curdot, const float* __restrict__ atom_mask,
    const float* __restrict__ Wma, const float* __restrict__ bma,
    const float* __restrict__ Wmt, const float* __restrict__ bmt,
    const float* __restrict__ mTi, const float* __restrict__ mTh,
    const float* __restrict__ mbih, const float* __restrict__ mbhh,
    const float* __restrict__ Wme, const float* __restrict__ bme,
    const float* __restrict__ Wout, const float* __restrict__ bout,
    void* __restrict__ out, const unsigned* __restrict__ amtag){
    int b = blockIdx.x, tid = threadIdx.x;
    __shared__ unsigned short s_cur[L_*KC];    // 57344 B
    __shared__ float s_am[L_], s_neg[L_], s_cd[L_], s_w[L_];
    __shared__ float s_mf[D_], s_act[D_], s_wc[D_], s_ctx[D_];
    __shared__ float s_gi[G3D_], s_gh[G3D_], s_red[8];
    const uint4* src = (const uint4*)(cur16 + (size_t)b*L_*KC);
    for (int i = tid; i < L_*KC/8; i += 256) ((uint4*)s_cur)[i] = src[i];
    if (tid < L_){
        float am = atom_mask[b*L_ + tid];
        s_am[tid] = am;
        s_neg[tid] = (am == 0.f) ? NEGV : 0.f;
        s_cd[tid] = curdot[b*L_ + tid];
    }
    __syncthreads();
    if (tid < D_){
        float acc = 0.f;
        #pragma unroll 4
        for (int l=0;l<L_;l++) acc += bu2f(s_cur[l*KC + tid]) * s_am[l];
        s_mf[tid] = acc; s_act[tid] = fmaxf(acc, 0.f);
    }
    __syncthreads();
    float bma0 = bma[0];
    for (int t=0;t<T_;t++){
        float p = (tid < D_) ? s_act[tid] * Wma[tid] : 0.f;
        float s1v = brSum(p, s_red);
        float sc = (tid < L_) ? (lreluf(s1v + s_cd[tid] + bma0) + s_neg[tid]) : -1e30f;
        float mx = brMax(sc, s_red);
        float e = (tid < L_) ? expf(sc - mx) : 0.f;
        float se = brSum(e, s_red);
        float wv_ = (tid < L_) ? e/se*s_am[tid] : 0.f;
        if (tid < L_) s_w[tid] = wv_;
        float wsm = brSum(wv_, s_red);
        __syncthreads();
        if (tid < D_){
            float acc = 0.f;
            #pragma unroll 4
            for (int l=0;l<L_;l++) acc += s_w[l] * bu2f(s_cur[l*KC + tid]);
            s_wc[tid] = acc;
        }
        __syncthreads();
        if (tid < D_){
            float acc = wsm * bmt[tid];
            for (int k=0;k<D_;k++) acc += s_wc[k] * Wmt[k*D_ + tid];
            s_ctx[tid] = eluf(acc);
        }
        __syncthreads();
        for (int j=tid; j<G3D_; j+=256){
            float ai0=0.f, ai1=0.f, ah0=0.f, ah1=0.f;
            for (int k=0;k<D_;k+=2){
                ai0 += s_ctx[k]   * mTi[(size_t)k*G3D_ + j];
                ai1 += s_ctx[k+1] * mTi[(size_t)(k+1)*G3D_ + j];
                ah0 += s_mf[k]    * mTh[(size_t)k*G3D_ + j];
                ah1 += s_mf[k+1]  * mTh[(size_t)(k+1)*G3D_ + j];
            }
            s_gi[j] = ai0+ai1; s_gh[j] = ah0+ah1;
        }
        __syncthreads();
        if (tid < D_){
            int d = tid;
            float rr = sigmf(s_gi[d] + mbih[d] + s_gh[d] + mbhh[d]);
            float zz = sigmf(s_gi[D_+d] + mbih[D_+d] + s_gh[D_+d] + mbhh[D_+d]);
            float nn = tanhf(s_gi[2*D_+d] + mbih[2*D_+d] + rr*(s_gh[2*D_+d] + mbhh[2*D_+d]));
            float nm = (1.f-zz)*nn + zz*s_mf[d];
            s_mf[d] = nm; s_act[d] = fmaxf(nm, 0.f);
        }
        __syncthreads();
    }
    const float dd = (float)(R_ - 2);
    float p = 0.f;
    if (tid < D_){
        float acc = bme[tid];
        for (int k=0;k<D_;k++){
            float mf = s_mf[k];
            acc += mf * Wme[(size_t)k*D_ + tid];
            acc += (mf + dd) * Wme[(size_t)(D_+k)*D_ + tid];
        }
        p = acc * Wout[tid];
    }
    float o = brSum(p, s_red);
    if (tid==0){
        o += bout[0];
        if (*amtag == FP32TAG) ((float*)out)[b] = o;
        else ((bf16*)out)[b] = __float2bfloat16(o);
    }
}

extern "C" void kernel_launch(void* const* d_in, const int* in_sizes, int n_in,
                              void* d_out, int out_size, void* d_ws, size_t ws_size,
                              hipStream_t stream) {
    const int* adl = (const int*)d_in[2];
    const int* bdl = (const int*)d_in[3];
    const unsigned* amtag = (const unsigned*)d_in[4];

    static const int srcidx[NSEG] = {0,1,4,5,6,7,8,9,10,11,12,15,16,17,18,19,20,21,22,23,24,25,26,27,28};
    static const int segsz[NSEG]  = {638976,327680,16384,7800,200,9800,200,1200,3,120000,600,
                                     1800,1800,400,1,40000,200,120000,120000,600,600,80000,200,200,1};
    CvtArgs ca;
    int ofs[NSEG+1]; ofs[0] = 0;
    for (int i=0;i<NSEG;i++){ ca.src[i] = d_in[srcidx[i]]; ca.ofs[i] = ofs[i]; ofs[i+1] = ofs[i] + segsz[i]; }
    ca.ofs[NSEG] = ofs[NSEG];
    const int total = ofs[NSEG];           // 1488645

    // ws layout (floats; all offsets 16B aligned). ~73.2 MB total.
    float* ws   = (float*)d_ws;
    float* conv = ws;                                    // 1488648
    float* h    = conv + 1488648;                        // BLD_
    unsigned short* XH   = (unsigned short*)(h + BLD_);          // BL_*KP sh = 3407872 fl
    unsigned short* B2t  = XH + (size_t)BL_*KP;                  // PREPB_N sh = 559104 fl
    unsigned short* WatT = B2t + PREPB_N;                        // PREPW_N sh = 86016 fl
    float* creg = (float*)(WatT + PREPW_N);              // C region: BL_*NP sh = 7340032 fl
    unsigned short* C = (unsigned short*)creg;
    unsigned short* wnei = (unsigned short*)creg;        // BL_*KC sh, overlays C head
    unsigned short* Q16  = (unsigned short*)creg + 3670016;      // B_*MB_*D_ sh (r0 only)
    unsigned short* P16  = Q16 + (size_t)B_*MB_*D_;              // BLD_ sh (r0 only)
    float* s1   = creg + 7340032;
    float* tb   = s1 + BL_;
    float* wsum = tb + BL_;
    float* curdot = wsum + BL_;                          // BL_
    float* mTi  = curdot + BL_;                          // 120000
    float* mTh  = mTi + PREPM_N;
    unsigned short* cur16 = (unsigned short*)(mTh + PREPM_N);    // BL_*KC sh

    const float* c_atom  = conv + ofs[0];
    const float* c_bond  = conv + ofs[1];
    const float* c_amask = conv + ofs[2];
    const float* c_Watom = conv + ofs[3];
    const float* c_batom = conv + ofs[4];
    const float* c_Wnei  = conv + ofs[5];
    const float* c_bnei  = conv + ofs[6];
    const float* c_Walign= conv + ofs[7];
    const float* c_balign= conv + ofs[8];
    const float* c_batt  = conv + ofs[10];
    const float* c_bih   = conv + ofs[11];
    const float* c_bhh   = conv + ofs[12];
    const float* c_Wma   = conv + ofs[13];
    const float* c_bma   = conv + ofs[14];
    const float* c_Wmt   = conv + ofs[15];
    const float* c_bmt   = conv + ofs[16];
    const float* c_mbih  = conv + ofs[19];
    const float* c_mbhh  = conv + ofs[20];
    const float* c_Wme   = conv + ofs[21];
    const float* c_bme   = conv + ofs[22];
    const float* c_Wout  = conv + ofs[23];
    const float* c_bout  = conv + ofs[24];

    const int prep_total = total + PREPB_N + PREPW_N + PREPM_N;   // 2898885
    k_prep<<<(prep_total + 255)/256, 256, 0, stream>>>(ca, conv, d_in[13], d_in[14], B2t,
                                                       d_in[11], WatT, d_in[21], d_in[22],
                                                       mTi, mTh, amtag, total);
    k_qprep<<<(B_*MB_*D_ + 255)/256, 256, 0, stream>>>(c_bond, c_Wnei, Q16);
    k_init<<<BL_/4, 256, 0, stream>>>(c_atom, c_Watom, c_batom, c_Wnei, c_bnei, c_Walign,
                                      h, XH, P16, s1, tb);

    for (int r=0; r<R_; r++){
        k_attn<<<BL_/4, 256, 0, stream>>>(cur16, s1, tb, adl, bdl, P16, Q16,
                                          c_Walign, c_balign, r, wnei, wsum);
        k_ctxmfma<<<(BL_/128)*(NC/64), 256, 0, stream>>>(wnei, wsum, WatT, c_batt, r, XH);
        k_gemm<<<(BL_/128)*(NP/128), 256, 0, stream>>>(XH, B2t, C, r);
        k_gru2<<<BL_/4, 256, 0, stream>>>(C, h, XH, cur16, c_bih, c_bhh,
                                          c_Walign, c_Wma, r, s1, tb, curdot);
    }

    k_mol<<<B_, 256, 0, stream>>>(cur16, curdot, c_amask, c_Wma, c_bma, c_Wmt, c_bmt,
                                  mTi, mTh, c_mbih, c_mbhh, c_Wme, c_bme, c_Wout, c_bout,
                                  d_out, amtag);
}

// Round 13
// 522.428 us; speedup vs baseline: 1.1248x; 1.0426x over previous
//
#include <hip/hip_runtime.h>
#include <hip/hip_bf16.h>
#include <math.h>
#include <string.h>

#define B_ 128
#define L_ 128
#define N_ 6
#define FA_ 39
#define FB_ 10
#define D_ 200
#define MB_ 256
#define R_ 3
#define T_ 2
#define NEGV -9e8f
#define BL_ (B_*L_)        // 16384
#define BLD_ (BL_*D_)      // 3276800
#define G3D_ (3*D_)        // 600
#define FP32TAG 0x3F800000u
#define KP 416             // padded K for gate GEMM (400 -> 416 = 13*32)
#define NP 896             // padded N for gate GEMM (800 -> 896 = 7*128)
#define KC 224             // padded K for ctx GEMM (200 -> 224 = 7*32)
#define NC 256             // padded N for ctx GEMM (200 -> 256)

typedef __hip_bfloat16 bf16;
typedef __attribute__((ext_vector_type(8))) short short8;
typedef __attribute__((ext_vector_type(4))) float f32x4;

__device__ __forceinline__ float b2f(const bf16 x){ return __bfloat162float(x); }
__device__ __forceinline__ unsigned short f2b(float v){ bf16 t = __float2bfloat16(v); return *reinterpret_cast<unsigned short*>(&t); }
__device__ __forceinline__ float bu2f(unsigned short u){ unsigned x = ((unsigned)u)<<16; float f; memcpy(&f,&x,4); return f; }
__device__ __forceinline__ float lreluf(float x){ return x>=0.f ? x : 0.01f*x; }
__device__ __forceinline__ float eluf(float x){ return x>0.f ? x : expm1f(x); }
__device__ __forceinline__ float sigmf(float x){ return 1.f/(1.f+expf(-x)); }

#define NSEG 25
struct CvtArgs { const void* src[NSEG]; int ofs[NSEG+1]; };

#define PREPB_N (R_*NP*KP)     // 1118208
#define PREPW_N (R_*NC*KC)     // 172032
#define PREPM_N (D_*G3D_)      // 120000

// merged prep: convert -> B2t (atom gate W) -> WatT (atom ctx W) -> mTi/mTh (mol GRU transpose, bf16)
__global__ void k_prep(CvtArgs c, float* __restrict__ dst,
                       const void* __restrict__ Wih, const void* __restrict__ Whh,
                       unsigned short* __restrict__ B2t,
                       const void* __restrict__ Watt_r, unsigned short* __restrict__ WatT,
                       const void* __restrict__ mWih_r, const void* __restrict__ mWhh_r,
                       unsigned short* __restrict__ mTi, unsigned short* __restrict__ mTh,
                       const unsigned* __restrict__ amtag, int total){
    int i = blockIdx.x*blockDim.x + threadIdx.x;
    bool f32 = (*amtag == FP32TAG);
    if (i < total){
        int s = 0;
        while (i >= c.ofs[s+1]) s++;
        int j = i - c.ofs[s];
        dst[i] = f32 ? ((const float*)c.src[s])[j] : b2f(((const bf16*)c.src[s])[j]);
        return;
    }
    int i2 = i - total;
    if (i2 < PREPB_N){
        int kk = i2 % KP;
        int rest = i2 / KP;
        int n = rest % NP;
        int r = rest / NP;
        float v = 0.f;
        if (kk < 200){
            if (n < 600){
                size_t si = ((size_t)(r*G3D_ + n))*D_ + kk;
                v = f32 ? ((const float*)Wih)[si] : b2f(((const bf16*)Wih)[si]);
            }
        } else if (kk < 400){
            int j = -1;
            if (n < 400) j = n;
            else if (n >= 600 && n < 800) j = n - 200;
            if (j >= 0){
                size_t si = ((size_t)(r*G3D_ + j))*D_ + (kk-200);
                v = f32 ? ((const float*)Whh)[si] : b2f(((const bf16*)Whh)[si]);
            }
        }
        B2t[i2] = f2b(v);
        return;
    }
    int i3 = i2 - PREPB_N;
    if (i3 < PREPW_N){
        int kk = i3 % KC;
        int rest = i3 / KC;
        int n = rest % NC;
        int r = rest / NC;
        float v = 0.f;
        if (kk < 200 && n < 200){
            size_t si = ((size_t)r*D_ + kk)*D_ + n;
            v = f32 ? ((const float*)Watt_r)[si] : b2f(((const bf16*)Watt_r)[si]);
        }
        WatT[i3] = f2b(v);
        return;
    }
    int i4 = i3 - PREPW_N;
    if (i4 < PREPM_N){
        int j = i4 % G3D_, k = i4 / G3D_;
        size_t si = (size_t)j*D_ + k;
        float vi = f32 ? ((const float*)mWih_r)[si] : b2f(((const bf16*)mWih_r)[si]);
        float vh = f32 ? ((const float*)mWhh_r)[si] : b2f(((const bf16*)mWhh_r)[si]);
        mTi[i4] = f2b(vi);
        mTh[i4] = f2b(vh);
    }
}

// Q16[row][d] = bond_list[row] @ W_nei[FA:FA+FB]  (bond half of r0 nei features, no bias)
__global__ void k_qprep(const float* __restrict__ bond_list, const float* __restrict__ W_nei,
                        unsigned short* __restrict__ Q16){
    int idx = blockIdx.x*blockDim.x + threadIdx.x;
    if (idx >= B_*MB_*D_) return;
    int d = idx % D_;
    int row = idx / D_;
    const float* br = bond_list + (size_t)row*FB_;
    const float* Wb = W_nei + FA_*D_;
    float acc = 0.f;
    #pragma unroll
    for (int k=0;k<FB_;k++) acc += br[k] * Wb[k*D_ + d];
    Q16[idx] = f2b(acc);
}

// fused init, wave-per-atom: atom_feature -> h + XH h-half + pad; P16 bf16; round-0 s1/tb dots
__global__ void __launch_bounds__(256) k_init(const float* __restrict__ atom_list,
                       const float* __restrict__ W_atom, const float* __restrict__ b_atom,
                       const float* __restrict__ W_nei, const float* __restrict__ b_nei,
                       const float* __restrict__ W_align,
                       float* __restrict__ h, unsigned short* __restrict__ XH,
                       unsigned short* __restrict__ P16,
                       float* __restrict__ s1, float* __restrict__ tb){
    int wv = threadIdx.x >> 6, lane = threadIdx.x & 63;
    int al = blockIdx.x*4 + wv;
    const float* arow = atom_list + (size_t)al*FA_;
    float a1 = 0.f, a2 = 0.f;
    for (int d = lane; d < D_; d += 64){
        float acc1 = b_atom[d], acc2 = b_nei[d];
        for (int k=0;k<FA_;k++){
            float a = arow[k];
            acc1 += a * W_atom[k*D_ + d];
            acc2 += a * W_nei[k*D_ + d];
        }
        float v = lreluf(acc1);
        size_t gi = (size_t)al*D_ + d;
        h[gi] = v;
        XH[(size_t)al*KP + 200 + d] = f2b(v);
        P16[gi] = f2b(acc2);
        a1 += v * W_align[d];
        a2 += v * W_align[D_ + d];
    }
    if (lane < 16) XH[(size_t)al*KP + 400 + lane] = 0;
    for (int o=32;o>0;o>>=1){ a1 += __shfl_xor(a1,o); a2 += __shfl_xor(a2,o); }
    if (lane==0){ s1[al] = a1; tb[al] = a2; }
}

// attention (all rounds): softmax + weighted neighbor sum -> bf16 wnei (stride KC, zero pad).
// XCD-locality swizzle: mol = bid&127 so all 32 blocks of a molecule share one XCD L2.
__global__ void __launch_bounds__(256) k_attn(
        const unsigned short* __restrict__ cur16,
        const float* __restrict__ s1, const float* __restrict__ tb,
        const int* __restrict__ adl, const int* __restrict__ bdl,
        const unsigned short* __restrict__ P16, const unsigned short* __restrict__ Q16,
        const float* __restrict__ W_align, const float* __restrict__ b_align, int r,
        unsigned short* __restrict__ wnei, float* __restrict__ wsum){
    int bid = blockIdx.x;
    int mol = bid & (B_-1), chunk = bid >> 7;
    int wv = threadIdx.x >> 6, lane = threadIdx.x & 63;
    int al = mol*L_ + chunk*4 + wv;
    __shared__ float s_nei[4][N_][D_];

    int idxn[N_]; bool pad[N_];
    for (int n=0;n<N_;n++){ idxn[n] = adl[al*N_ + n]; pad[n] = (idxn[n] == L_-1); }

    float s2[N_];
    if (r == 0){
        for (int j = lane; j < N_*D_; j += 64){
            int n = j / D_, d = j - n*D_;
            int bd = bdl[al*N_ + n];
            float acc = bu2f(P16[((size_t)mol*L_ + idxn[n])*D_ + d])
                      + bu2f(Q16[((size_t)mol*MB_ + bd)*D_ + d]);
            s_nei[wv][n][d] = lreluf(acc);
        }
        const float* Wab = W_align + D_;
        for (int n=0;n<N_;n++){
            float acc = 0.f;
            for (int d=lane; d<D_; d+=64) acc += s_nei[wv][n][d] * Wab[d];
            for (int o=32;o>0;o>>=1) acc += __shfl_xor(acc,o);
            s2[n] = acc;
        }
    } else {
        float tmp = 0.f;
        if (lane < N_) tmp = tb[mol*L_ + idxn[lane]];
        for (int n=0;n<N_;n++) s2[n] = __shfl(tmp, n);
    }

    float s1v = s1[al];
    float bav = b_align[r];
    float a[N_]; float mx = -1e30f;
    for (int n=0;n<N_;n++){
        float v = lreluf(s1v + s2[n] + bav);
        if (pad[n]) v += NEGV;
        a[n] = v; mx = fmaxf(mx, v);
    }
    float w[N_]; float se = 0.f;
    for (int n=0;n<N_;n++){ float e = expf(a[n]-mx); w[n]=e; se += e; }
    float inv = 1.f/se; float wsv = 0.f;
    for (int n=0;n<N_;n++){ w[n] = pad[n] ? 0.f : w[n]*inv; wsv += w[n]; }

    if (r == 0){
        for (int d=lane; d<D_; d+=64){
            float acc = 0.f;
            #pragma unroll
            for (int n=0;n<N_;n++) acc += w[n] * s_nei[wv][n][d];
            wnei[(size_t)al*KC + d] = f2b(acc);
        }
    } else {
        for (int d=lane; d<D_; d+=64){
            float acc = 0.f;
            #pragma unroll
            for (int n=0;n<N_;n++) acc += w[n] * bu2f(cur16[((size_t)mol*L_ + idxn[n])*KC + d]);
            wnei[(size_t)al*KC + d] = f2b(acc);
        }
    }
    if (lane < 24) wnei[(size_t)al*KC + 200 + lane] = 0;
    if (lane==0) wsum[al] = wsv;
}

// MFMA ctx GEMM: elu(wnei[16384,KC] @ WatT[r]^T + wsum*bias) -> XH x-half. 128x64 tile.
__global__ void __launch_bounds__(256) k_ctxmfma(const unsigned short* __restrict__ Wn,
        const float* __restrict__ wsum, const unsigned short* __restrict__ WatT,
        const float* __restrict__ bias, int r, unsigned short* __restrict__ XH){
    __shared__ unsigned short As[128][40];
    __shared__ unsigned short Bs[64][40];
    int tid = threadIdx.x;
    int m0 = ((int)blockIdx.x & 127) * 128;
    int n0 = ((int)blockIdx.x >> 7) * 64;
    const unsigned short* Bt = WatT + (size_t)r*NC*KC;
    int lane = tid & 63, wv = tid >> 6;
    int quad = lane >> 4, lm = lane & 15;
    f32x4 acc[2][4];
    #pragma unroll
    for (int a=0;a<2;a++)
        #pragma unroll
        for (int b=0;b<4;b++) acc[a][b] = (f32x4){0.f,0.f,0.f,0.f};
    for (int ks = 0; ks < 7; ks++){
        int r0_ = tid >> 2, c0 = (tid & 3) * 8;
        int r1_ = (tid + 256) >> 2, c1 = ((tid + 256) & 3) * 8;
        uint4 a0 = *(const uint4*)&Wn[(size_t)(m0 + r0_)*KC + ks*32 + c0];
        uint4 a1 = *(const uint4*)&Wn[(size_t)(m0 + r1_)*KC + ks*32 + c1];
        uint4 b0 = *(const uint4*)&Bt[(size_t)(n0 + (tid >> 2))*KC + ks*32 + (tid & 3)*8];
        __syncthreads();
        *(uint4*)&As[r0_][c0] = a0;
        *(uint4*)&As[r1_][c1] = a1;
        *(uint4*)&Bs[tid >> 2][(tid & 3)*8] = b0;
        __syncthreads();
        short8 av0 = *(const short8*)&As[wv*32 + lm][quad*8];
        short8 av1 = *(const short8*)&As[wv*32 + 16 + lm][quad*8];
        #pragma unroll
        for (int ns=0; ns<4; ns++){
            short8 bv = *(const short8*)&Bs[ns*16 + lm][quad*8];
            acc[0][ns] = __builtin_amdgcn_mfma_f32_16x16x32_bf16(av0, bv, acc[0][ns], 0,0,0);
            acc[1][ns] = __builtin_amdgcn_mfma_f32_16x16x32_bf16(av1, bv, acc[1][ns], 0,0,0);
        }
    }
    #pragma unroll
    for (int ms=0; ms<2; ms++)
      #pragma unroll
      for (int ns=0; ns<4; ns++){
        int n = n0 + ns*16 + lm;
        if (n < 200){
            float bv = bias[r*D_ + n];
            #pragma unroll
            for (int i=0;i<4;i++){
                int row = m0 + wv*32 + ms*16 + quad*4 + i;
                float v = acc[ms][ns][i] + wsum[row]*bv;
                XH[(size_t)row*KP + n] = f2b(eluf(v));
            }
        }
      }
}

// MFMA gate GEMM: C[16384,NP] = XH @ B2t[r]^T. 128x128 tile.
__global__ void __launch_bounds__(256) k_gemm(const unsigned short* __restrict__ XH,
        const unsigned short* __restrict__ B2t, unsigned short* __restrict__ C, int r){
    __shared__ unsigned short As[128][40];
    __shared__ unsigned short Bs[128][40];
    int tid = threadIdx.x;
    int m0 = ((int)blockIdx.x & 127) * 128;
    int n0 = ((int)blockIdx.x >> 7) * 128;
    const unsigned short* Bt = B2t + (size_t)r*NP*KP;
    int lane = tid & 63, wv = tid >> 6;
    int quad = lane >> 4, lm = lane & 15;
    f32x4 acc[2][8];
    #pragma unroll
    for (int a=0;a<2;a++)
        #pragma unroll
        for (int b=0;b<8;b++) acc[a][b] = (f32x4){0.f,0.f,0.f,0.f};
    for (int ks = 0; ks < 13; ks++){
        int r0_ = tid >> 2, c0 = (tid & 3) * 8;
        int r1_ = (tid + 256) >> 2, c1 = ((tid + 256) & 3) * 8;
        uint4 a0 = *(const uint4*)&XH[(size_t)(m0 + r0_)*KP + ks*32 + c0];
        uint4 a1 = *(const uint4*)&XH[(size_t)(m0 + r1_)*KP + ks*32 + c1];
        uint4 b0 = *(const uint4*)&Bt[(size_t)(n0 + r0_)*KP + ks*32 + c0];
        uint4 b1 = *(const uint4*)&Bt[(size_t)(n0 + r1_)*KP + ks*32 + c1];
        __syncthreads();
        *(uint4*)&As[r0_][c0] = a0;
        *(uint4*)&As[r1_][c1] = a1;
        *(uint4*)&Bs[r0_][c0] = b0;
        *(uint4*)&Bs[r1_][c1] = b1;
        __syncthreads();
        short8 av0 = *(const short8*)&As[wv*32 + lm][quad*8];
        short8 av1 = *(const short8*)&As[wv*32 + 16 + lm][quad*8];
        #pragma unroll
        for (int ns=0; ns<8; ns++){
            short8 bv = *(const short8*)&Bs[ns*16 + lm][quad*8];
            acc[0][ns] = __builtin_amdgcn_mfma_f32_16x16x32_bf16(av0, bv, acc[0][ns], 0,0,0);
            acc[1][ns] = __builtin_amdgcn_mfma_f32_16x16x32_bf16(av1, bv, acc[1][ns], 0,0,0);
        }
    }
    #pragma unroll
    for (int ms=0; ms<2; ms++)
      #pragma unroll
      for (int ns=0; ns<8; ns++)
        #pragma unroll
        for (int i=0;i<4;i++){
            int row = m0 + wv*32 + ms*16 + quad*4 + i;
            C[(size_t)row*NP + n0 + ns*16 + lm] = f2b(acc[ms][ns][i]);
        }
}

// GRU combine, wave-per-atom; writes h + XH h-half + cur16; fuses next-round dots / curdot
__global__ void __launch_bounds__(256) k_gru2(const unsigned short* __restrict__ C,
        float* __restrict__ h, unsigned short* __restrict__ XH,
        unsigned short* __restrict__ cur16,
        const float* __restrict__ bih, const float* __restrict__ bhh,
        const float* __restrict__ W_align, const float* __restrict__ Wma, int r,
        float* __restrict__ s1, float* __restrict__ tb, float* __restrict__ curdot){
    int wv = threadIdx.x >> 6, lane = threadIdx.x & 63;
    int al = blockIdx.x*4 + wv;
    size_t base = (size_t)al*NP;
    const float* bi = bih + r*G3D_;
    const float* bh = bhh + r*G3D_;
    const float* Wa = W_align + (r+1)*2*D_;   // dereferenced only when r<2
    bool last = (r == R_-1);
    float a1 = 0.f, a2 = 0.f;
    for (int j = lane; j < D_; j += 64){
        float rsum = bu2f(C[base + j]);
        float zsum = bu2f(C[base + 200 + j]);
        float gin  = bu2f(C[base + 400 + j]);
        float ghn  = bu2f(C[base + 600 + j]);
        float rr = sigmf(rsum + bi[j] + bh[j]);
        float zz = sigmf(zsum + bi[D_+j] + bh[D_+j]);
        float nn = tanhf(gin + bi[2*D_+j] + rr*(ghn + bh[2*D_+j]));
        size_t gi = (size_t)al*D_ + j;
        float hv = h[gi];
        float hn = (1.f-zz)*nn + zz*hv;
        h[gi] = hn;
        float cv = fmaxf(hn, 0.f);
        XH[(size_t)al*KP + 200 + j] = f2b(hn);
        cur16[(size_t)al*KC + j] = f2b(cv);
        if (last){
            a1 += cv * Wma[D_+j];
        } else {
            a1 += cv * Wa[j];
            a2 += cv * Wa[D_+j];
        }
    }
    if (lane < 24) cur16[(size_t)al*KC + 200 + lane] = 0;
    for (int o=32;o>0;o>>=1){ a1 += __shfl_xor(a1,o); a2 += __shfl_xor(a2,o); }
    if (lane==0){
        if (last) curdot[al] = a1;
        else { s1[al] = a1; tb[al] = a2; }
    }
}

__device__ __forceinline__ float brSum(float v, float* s_red){
    for (int o=32;o>0;o>>=1) v += __shfl_xor(v,o);
    int lane = threadIdx.x & 63, wid = threadIdx.x >> 6;
    __syncthreads();
    if (lane==0) s_red[wid] = v;
    __syncthreads();
    float r = 0.f;
    int nw = blockDim.x >> 6;
    for (int i=0;i<nw;i++) r += s_red[i];
    return r;
}

__device__ __forceinline__ float brMax(float v, float* s_red){
    for (int o=32;o>0;o>>=1) v = fmaxf(v, __shfl_xor(v,o));
    int lane = threadIdx.x & 63, wid = threadIdx.x >> 6;
    __syncthreads();
    if (lane==0) s_red[wid] = v;
    __syncthreads();
    float r = s_red[0];
    int nw = blockDim.x >> 6;
    for (int i=1;i<nw;i++) r = fmaxf(r, s_red[i]);
    return r;
}

// molecule phase, 512 threads (8 waves): cur16 tile in LDS; serial loops split 2-way by chunk;
// mol GRU gate weights bf16. r8's spill came from 1024-thread chunk arrays; this is mild.
__global__ void __launch_bounds__(512) k_mol(const unsigned short* __restrict__ cur16,
    const float* __restrict__ curdot, const float* __restrict__ atom_mask,
    const float* __restrict__ Wma, const float* __restrict__ bma,
    const float* __restrict__ Wmt, const float* __restrict__ bmt,
    const unsigned short* __restrict__ mTi, const unsigned short* __restrict__ mTh,
    const float* __restrict__ mbih, const float* __restrict__ mbhh,
    const float* __restrict__ Wme, const float* __restrict__ bme,
    const float* __restrict__ Wout, const float* __restrict__ bout,
    void* __restrict__ out, const unsigned* __restrict__ amtag){
    int b = blockIdx.x, tid = threadIdx.x;
    int dq = tid & 255, cq = tid >> 8;      // chunk 0..1
    __shared__ unsigned short s_cur[L_*KC];    // 57344 B
    __shared__ float s_am[L_], s_neg[L_], s_cd[L_], s_w[L_];
    __shared__ float s_mf[D_], s_act[D_], s_wc[D_], s_ctx[D_];
    __shared__ float s_gi[G3D_], s_gh[G3D_];
    __shared__ float s_part[2][256];
    __shared__ float s_red[8];
    const uint4* src = (const uint4*)(cur16 + (size_t)b*L_*KC);
    for (int i = tid; i < L_*KC/8; i += 512) ((uint4*)s_cur)[i] = src[i];
    if (tid < L_){
        float am = atom_mask[b*L_ + tid];
        s_am[tid] = am;
        s_neg[tid] = (am == 0.f) ? NEGV : 0.f;
        s_cd[tid] = curdot[b*L_ + tid];
    }
    __syncthreads();
    // masked pooling: (dq, cq) x 64 l each
    {
        float acc = 0.f;
        if (dq < D_)
            for (int l=cq*64; l<cq*64+64; l++) acc += bu2f(s_cur[l*KC + dq]) * s_am[l];
        s_part[cq][dq] = acc;
        __syncthreads();
        if (tid < D_){
            float v = s_part[0][tid] + s_part[1][tid];
            s_mf[tid] = v; s_act[tid] = fmaxf(v, 0.f);
        }
        __syncthreads();
    }
    float bma0 = bma[0];
    for (int t=0;t<T_;t++){
        float p = (tid < D_) ? s_act[tid] * Wma[tid] : 0.f;
        float s1v = brSum(p, s_red);
        float sc = (tid < L_) ? (lreluf(s1v + s_cd[tid] + bma0) + s_neg[tid]) : -1e30f;
        float mx = brMax(sc, s_red);
        float e = (tid < L_) ? expf(sc - mx) : 0.f;
        float se = brSum(e, s_red);
        float wv_ = (tid < L_) ? e/se*s_am[tid] : 0.f;
        if (tid < L_) s_w[tid] = wv_;
        float wsm = brSum(wv_, s_red);
        __syncthreads();
        // weighted context: (dq, cq) x 64 l
        {
            float acc = 0.f;
            if (dq < D_)
                for (int l=cq*64; l<cq*64+64; l++) acc += s_w[l] * bu2f(s_cur[l*KC + dq]);
            s_part[cq][dq] = acc;
            __syncthreads();
            if (tid < D_) s_wc[tid] = s_part[0][tid] + s_part[1][tid];
            __syncthreads();
        }
        // ctx GEMV: (dq=j, cq) x 100 k
        {
            float acc = 0.f;
            if (dq < D_)
                for (int k=cq*100; k<cq*100+100; k++) acc += s_wc[k] * Wmt[(size_t)k*D_ + dq];
            s_part[cq][dq] = acc;
            __syncthreads();
            if (tid < D_)
                s_ctx[tid] = eluf(s_part[0][tid] + s_part[1][tid] + wsm * bmt[tid]);
            __syncthreads();
        }
        // gates: j over 600 with 512 threads, full k loop, bf16 weights, 2x unroll
        for (int j=tid; j<G3D_; j+=512){
            float ai0=0.f, ai1=0.f, ah0=0.f, ah1=0.f;
            for (int k=0;k<D_;k+=2){
                ai0 += s_ctx[k]   * bu2f(mTi[(size_t)k*G3D_ + j]);
                ai1 += s_ctx[k+1] * bu2f(mTi[(size_t)(k+1)*G3D_ + j]);
                ah0 += s_mf[k]    * bu2f(mTh[(size_t)k*G3D_ + j]);
                ah1 += s_mf[k+1]  * bu2f(mTh[(size_t)(k+1)*G3D_ + j]);
            }
            s_gi[j] = ai0+ai1; s_gh[j] = ah0+ah1;
        }
        __syncthreads();
        if (tid < D_){
            int d = tid;
            float rr = sigmf(s_gi[d] + mbih[d] + s_gh[d] + mbhh[d]);
            float zz = sigmf(s_gi[D_+d] + mbih[D_+d] + s_gh[D_+d] + mbhh[D_+d]);
            float nn = tanhf(s_gi[2*D_+d] + mbih[2*D_+d] + rr*(s_gh[2*D_+d] + mbhh[2*D_+d]));
            float nm = (1.f-zz)*nn + zz*s_mf[d];
            s_mf[d] = nm; s_act[d] = fmaxf(nm, 0.f);
        }
        __syncthreads();
    }
    // head: (dq=d, cq) x 100 k over both Wme halves
    const float dd = (float)(R_ - 2);
    {
        float acc = 0.f;
        if (dq < D_)
            for (int k=cq*100; k<cq*100+100; k++){
                float mf = s_mf[k];
                acc += mf * Wme[(size_t)k*D_ + dq];
                acc += (mf + dd) * Wme[(size_t)(D_+k)*D_ + dq];
            }
        s_part[cq][dq] = acc;
        __syncthreads();
        float p = 0.f;
        if (tid < D_)
            p = (s_part[0][tid] + s_part[1][tid] + bme[tid]) * Wout[tid];
        float o = brSum(p, s_red);
        if (tid==0){
            o += bout[0];
            if (*amtag == FP32TAG) ((float*)out)[b] = o;
            else ((bf16*)out)[b] = __float2bfloat16(o);
        }
    }
}

extern "C" void kernel_launch(void* const* d_in, const int* in_sizes, int n_in,
                              void* d_out, int out_size, void* d_ws, size_t ws_size,
                              hipStream_t stream) {
    const int* adl = (const int*)d_in[2];
    const int* bdl = (const int*)d_in[3];
    const unsigned* amtag = (const unsigned*)d_in[4];

    static const int srcidx[NSEG] = {0,1,4,5,6,7,8,9,10,11,12,15,16,17,18,19,20,21,22,23,24,25,26,27,28};
    static const int segsz[NSEG]  = {638976,327680,16384,7800,200,9800,200,1200,3,120000,600,
                                     1800,1800,400,1,40000,200,120000,120000,600,600,80000,200,200,1};
    CvtArgs ca;
    int ofs[NSEG+1]; ofs[0] = 0;
    for (int i=0;i<NSEG;i++){ ca.src[i] = d_in[srcidx[i]]; ca.ofs[i] = ofs[i]; ofs[i+1] = ofs[i] + segsz[i]; }
    ca.ofs[NSEG] = ofs[NSEG];
    const int total = ofs[NSEG];           // 1488645

    // ws layout (floats; all offsets 16B aligned). ~73 MB total.
    float* ws   = (float*)d_ws;
    float* conv = ws;                                    // 1488648
    float* h    = conv + 1488648;                        // BLD_
    unsigned short* XH   = (unsigned short*)(h + BLD_);          // BL_*KP sh
    unsigned short* B2t  = XH + (size_t)BL_*KP;                  // PREPB_N sh
    unsigned short* WatT = B2t + PREPB_N;                        // PREPW_N sh
    float* creg = (float*)(WatT + PREPW_N);              // C region: BL_*NP sh = 7340032 fl
    unsigned short* C = (unsigned short*)creg;
    unsigned short* wnei = (unsigned short*)creg;        // BL_*KC sh, overlays C head
    unsigned short* Q16  = (unsigned short*)creg + 3670016;      // B_*MB_*D_ sh (r0 only)
    unsigned short* P16  = Q16 + (size_t)B_*MB_*D_;              // BLD_ sh (r0 only)
    float* s1   = creg + 7340032;
    float* tb   = s1 + BL_;
    float* wsum = tb + BL_;
    float* curdot = wsum + BL_;                          // BL_
    unsigned short* mTi = (unsigned short*)(curdot + BL_);       // PREPM_N sh (bf16)
    unsigned short* mTh = mTi + PREPM_N;                         // PREPM_N sh
    unsigned short* cur16 = mTh + PREPM_N;                       // BL_*KC sh

    const float* c_atom  = conv + ofs[0];
    const float* c_bond  = conv + ofs[1];
    const float* c_amask = conv + ofs[2];
    const float* c_Watom = conv + ofs[3];
    const float* c_batom = conv + ofs[4];
    const float* c_Wnei  = conv + ofs[5];
    const float* c_bnei  = conv + ofs[6];
    const float* c_Walign= conv + ofs[7];
    const float* c_balign= conv + ofs[8];
    const float* c_batt  = conv + ofs[10];
    const float* c_bih   = conv + ofs[11];
    const float* c_bhh   = conv + ofs[12];
    const float* c_Wma   = conv + ofs[13];
    const float* c_bma   = conv + ofs[14];
    const float* c_Wmt   = conv + ofs[15];
    const float* c_bmt   = conv + ofs[16];
    const float* c_mbih  = conv + ofs[19];
    const float* c_mbhh  = conv + ofs[20];
    const float* c_Wme   = conv + ofs[21];
    const float* c_bme   = conv + ofs[22];
    const float* c_Wout  = conv + ofs[23];
    const float* c_bout  = conv + ofs[24];

    const int prep_total = total + PREPB_N + PREPW_N + PREPM_N;   // 2898885
    k_prep<<<(prep_total + 255)/256, 256, 0, stream>>>(ca, conv, d_in[13], d_in[14], B2t,
                                                       d_in[11], WatT, d_in[21], d_in[22],
                                                       mTi, mTh, amtag, total);
    k_qprep<<<(B_*MB_*D_ + 255)/256, 256, 0, stream>>>(c_bond, c_Wnei, Q16);
    k_init<<<BL_/4, 256, 0, stream>>>(c_atom, c_Watom, c_batom, c_Wnei, c_bnei, c_Walign,
                                      h, XH, P16, s1, tb);

    for (int r=0; r<R_; r++){
        k_attn<<<BL_/4, 256, 0, stream>>>(cur16, s1, tb, adl, bdl, P16, Q16,
                                          c_Walign, c_balign, r, wnei, wsum);
        k_ctxmfma<<<(BL_/128)*(NC/64), 256, 0, stream>>>(wnei, wsum, WatT, c_batt, r, XH);
        k_gemm<<<(BL_/128)*(NP/128), 256, 0, stream>>>(XH, B2t, C, r);
        k_gru2<<<BL_/4, 256, 0, stream>>>(C, h, XH, cur16, c_bih, c_bhh,
                                          c_Walign, c_Wma, r, s1, tb, curdot);
    }

    k_mol<<<B_, 512, 0, stream>>>(cur16, curdot, c_amask, c_Wma, c_bma, c_Wmt, c_bmt,
                                  mTi, mTh, c_mbih, c_mbhh, c_Wme, c_bme, c_Wout, c_bout,
                                  d_out, amtag);
}

// Round 14
// 502.043 us; speedup vs baseline: 1.1705x; 1.0406x over previous
//
#include <hip/hip_runtime.h>
#include <hip/hip_bf16.h>
#include <math.h>
#include <string.h>

#define B_ 128
#define L_ 128
#define N_ 6
#define FA_ 39
#define FB_ 10
#define D_ 200
#define MB_ 256
#define R_ 3
#define T_ 2
#define NEGV -9e8f
#define BL_ (B_*L_)        // 16384
#define BLD_ (BL_*D_)      // 3276800
#define G3D_ (3*D_)        // 600
#define FP32TAG 0x3F800000u
#define KP 416             // padded K for gate GEMM (400 -> 416 = 13*32)
#define NP 896             // padded N for gate GEMM (800 -> 896 = 7*128)
#define KC 224             // padded K for ctx GEMM (200 -> 224 = 7*32)
#define NC 256             // padded N for ctx GEMM (200 -> 256)

typedef __hip_bfloat16 bf16;
typedef __attribute__((ext_vector_type(8))) short short8;
typedef __attribute__((ext_vector_type(4))) float f32x4;

__device__ __forceinline__ float b2f(const bf16 x){ return __bfloat162float(x); }
__device__ __forceinline__ unsigned short f2b(float v){ bf16 t = __float2bfloat16(v); return *reinterpret_cast<unsigned short*>(&t); }
__device__ __forceinline__ float bu2f(unsigned short u){ unsigned x = ((unsigned)u)<<16; float f; memcpy(&f,&x,4); return f; }
__device__ __forceinline__ float lreluf(float x){ return x>=0.f ? x : 0.01f*x; }
__device__ __forceinline__ float eluf(float x){ return x>0.f ? x : expm1f(x); }
__device__ __forceinline__ float sigmf(float x){ return 1.f/(1.f+expf(-x)); }

#define NSEG 25
struct CvtArgs { const void* src[NSEG]; int ofs[NSEG+1]; };

#define PREPB_N (R_*NP*KP)     // 1118208
#define PREPW_N (R_*NC*KC)     // 172032
#define PREPM_N (D_*G3D_)      // 120000

// merged prep: convert -> B2t (atom gate W) -> WatT (atom ctx W) -> mTi/mTh (mol GRU transpose, bf16)
__global__ void k_prep(CvtArgs c, float* __restrict__ dst,
                       const void* __restrict__ Wih, const void* __restrict__ Whh,
                       unsigned short* __restrict__ B2t,
                       const void* __restrict__ Watt_r, unsigned short* __restrict__ WatT,
                       const void* __restrict__ mWih_r, const void* __restrict__ mWhh_r,
                       unsigned short* __restrict__ mTi, unsigned short* __restrict__ mTh,
                       const unsigned* __restrict__ amtag, int total){
    int i = blockIdx.x*blockDim.x + threadIdx.x;
    bool f32 = (*amtag == FP32TAG);
    if (i < total){
        int s = 0;
        while (i >= c.ofs[s+1]) s++;
        int j = i - c.ofs[s];
        dst[i] = f32 ? ((const float*)c.src[s])[j] : b2f(((const bf16*)c.src[s])[j]);
        return;
    }
    int i2 = i - total;
    if (i2 < PREPB_N){
        int kk = i2 % KP;
        int rest = i2 / KP;
        int n = rest % NP;
        int r = rest / NP;
        float v = 0.f;
        if (kk < 200){
            if (n < 600){
                size_t si = ((size_t)(r*G3D_ + n))*D_ + kk;
                v = f32 ? ((const float*)Wih)[si] : b2f(((const bf16*)Wih)[si]);
            }
        } else if (kk < 400){
            int j = -1;
            if (n < 400) j = n;
            else if (n >= 600 && n < 800) j = n - 200;
            if (j >= 0){
                size_t si = ((size_t)(r*G3D_ + j))*D_ + (kk-200);
                v = f32 ? ((const float*)Whh)[si] : b2f(((const bf16*)Whh)[si]);
            }
        }
        B2t[i2] = f2b(v);
        return;
    }
    int i3 = i2 - PREPB_N;
    if (i3 < PREPW_N){
        int kk = i3 % KC;
        int rest = i3 / KC;
        int n = rest % NC;
        int r = rest / NC;
        float v = 0.f;
        if (kk < 200 && n < 200){
            size_t si = ((size_t)r*D_ + kk)*D_ + n;
            v = f32 ? ((const float*)Watt_r)[si] : b2f(((const bf16*)Watt_r)[si]);
        }
        WatT[i3] = f2b(v);
        return;
    }
    int i4 = i3 - PREPW_N;
    if (i4 < PREPM_N){
        int j = i4 % G3D_, k = i4 / G3D_;
        size_t si = (size_t)j*D_ + k;
        float vi = f32 ? ((const float*)mWih_r)[si] : b2f(((const bf16*)mWih_r)[si]);
        float vh = f32 ? ((const float*)mWhh_r)[si] : b2f(((const bf16*)mWhh_r)[si]);
        mTi[i4] = f2b(vi);
        mTh[i4] = f2b(vh);
    }
}

// Q16[row][d] = bond_list[row] @ W_nei[FA:FA+FB]  (bond half of r0 nei features, no bias)
__global__ void k_qprep(const float* __restrict__ bond_list, const float* __restrict__ W_nei,
                        unsigned short* __restrict__ Q16){
    int idx = blockIdx.x*blockDim.x + threadIdx.x;
    if (idx >= B_*MB_*D_) return;
    int d = idx % D_;
    int row = idx / D_;
    const float* br = bond_list + (size_t)row*FB_;
    const float* Wb = W_nei + FA_*D_;
    float acc = 0.f;
    #pragma unroll
    for (int k=0;k<FB_;k++) acc += br[k] * Wb[k*D_ + d];
    Q16[idx] = f2b(acc);
}

// fused init, wave-per-atom: atom features preloaded to registers; writes XH h-half (bf16 GRU
// state — no fp32 h array) + pad, P16, round-0 s1/tb dots.
__global__ void __launch_bounds__(256) k_init(const float* __restrict__ atom_list,
                       const float* __restrict__ W_atom, const float* __restrict__ b_atom,
                       const float* __restrict__ W_nei, const float* __restrict__ b_nei,
                       const float* __restrict__ W_align,
                       unsigned short* __restrict__ XH, unsigned short* __restrict__ P16,
                       float* __restrict__ s1, float* __restrict__ tb){
    int wv = threadIdx.x >> 6, lane = threadIdx.x & 63;
    int al = blockIdx.x*4 + wv;
    const float* arow = atom_list + (size_t)al*FA_;
    float areg[FA_];
    #pragma unroll
    for (int k=0;k<FA_;k++) areg[k] = arow[k];
    float a1 = 0.f, a2 = 0.f;
    for (int d = lane; d < D_; d += 64){
        float acc1 = b_atom[d], acc2 = b_nei[d];
        #pragma unroll
        for (int k=0;k<FA_;k++){
            acc1 += areg[k] * W_atom[k*D_ + d];
            acc2 += areg[k] * W_nei[k*D_ + d];
        }
        float v = lreluf(acc1);
        XH[(size_t)al*KP + 200 + d] = f2b(v);
        P16[(size_t)al*D_ + d] = f2b(acc2);
        a1 += v * W_align[d];
        a2 += v * W_align[D_ + d];
    }
    if (lane < 16) XH[(size_t)al*KP + 400 + lane] = 0;
    for (int o=32;o>0;o>>=1){ a1 += __shfl_xor(a1,o); a2 += __shfl_xor(a2,o); }
    if (lane==0){ s1[al] = a1; tb[al] = a2; }
}

// attention (all rounds): softmax + weighted neighbor sum -> bf16 wnei (stride KC, zero pad).
// XCD-locality swizzle: mol = bid&127 so all 32 blocks of a molecule share one XCD L2.
__global__ void __launch_bounds__(256) k_attn(
        const unsigned short* __restrict__ cur16,
        const float* __restrict__ s1, const float* __restrict__ tb,
        const int* __restrict__ adl, const int* __restrict__ bdl,
        const unsigned short* __restrict__ P16, const unsigned short* __restrict__ Q16,
        const float* __restrict__ W_align, const float* __restrict__ b_align, int r,
        unsigned short* __restrict__ wnei, float* __restrict__ wsum){
    int bid = blockIdx.x;
    int mol = bid & (B_-1), chunk = bid >> 7;
    int wv = threadIdx.x >> 6, lane = threadIdx.x & 63;
    int al = mol*L_ + chunk*4 + wv;
    __shared__ float s_nei[4][N_][D_];

    int idxn[N_]; bool pad[N_];
    for (int n=0;n<N_;n++){ idxn[n] = adl[al*N_ + n]; pad[n] = (idxn[n] == L_-1); }

    float s2[N_];
    if (r == 0){
        for (int j = lane; j < N_*D_; j += 64){
            int n = j / D_, d = j - n*D_;
            int bd = bdl[al*N_ + n];
            float acc = bu2f(P16[((size_t)mol*L_ + idxn[n])*D_ + d])
                      + bu2f(Q16[((size_t)mol*MB_ + bd)*D_ + d]);
            s_nei[wv][n][d] = lreluf(acc);
        }
        const float* Wab = W_align + D_;
        for (int n=0;n<N_;n++){
            float acc = 0.f;
            for (int d=lane; d<D_; d+=64) acc += s_nei[wv][n][d] * Wab[d];
            for (int o=32;o>0;o>>=1) acc += __shfl_xor(acc,o);
            s2[n] = acc;
        }
    } else {
        float tmp = 0.f;
        if (lane < N_) tmp = tb[mol*L_ + idxn[lane]];
        for (int n=0;n<N_;n++) s2[n] = __shfl(tmp, n);
    }

    float s1v = s1[al];
    float bav = b_align[r];
    float a[N_]; float mx = -1e30f;
    for (int n=0;n<N_;n++){
        float v = lreluf(s1v + s2[n] + bav);
        if (pad[n]) v += NEGV;
        a[n] = v; mx = fmaxf(mx, v);
    }
    float w[N_]; float se = 0.f;
    for (int n=0;n<N_;n++){ float e = expf(a[n]-mx); w[n]=e; se += e; }
    float inv = 1.f/se; float wsv = 0.f;
    for (int n=0;n<N_;n++){ w[n] = pad[n] ? 0.f : w[n]*inv; wsv += w[n]; }

    if (r == 0){
        for (int d=lane; d<D_; d+=64){
            float acc = 0.f;
            #pragma unroll
            for (int n=0;n<N_;n++) acc += w[n] * s_nei[wv][n][d];
            wnei[(size_t)al*KC + d] = f2b(acc);
        }
    } else {
        for (int d=lane; d<D_; d+=64){
            float acc = 0.f;
            #pragma unroll
            for (int n=0;n<N_;n++) acc += w[n] * bu2f(cur16[((size_t)mol*L_ + idxn[n])*KC + d]);
            wnei[(size_t)al*KC + d] = f2b(acc);
        }
    }
    if (lane < 24) wnei[(size_t)al*KC + 200 + lane] = 0;
    if (lane==0) wsum[al] = wsv;
}

// MFMA ctx GEMM: elu(wnei[16384,KC] @ WatT[r]^T + wsum*bias) -> XH x-half. 128x64 tile.
__global__ void __launch_bounds__(256) k_ctxmfma(const unsigned short* __restrict__ Wn,
        const float* __restrict__ wsum, const unsigned short* __restrict__ WatT,
        const float* __restrict__ bias, int r, unsigned short* __restrict__ XH){
    __shared__ unsigned short As[128][40];
    __shared__ unsigned short Bs[64][40];
    int tid = threadIdx.x;
    int m0 = ((int)blockIdx.x & 127) * 128;
    int n0 = ((int)blockIdx.x >> 7) * 64;
    const unsigned short* Bt = WatT + (size_t)r*NC*KC;
    int lane = tid & 63, wv = tid >> 6;
    int quad = lane >> 4, lm = lane & 15;
    f32x4 acc[2][4];
    #pragma unroll
    for (int a=0;a<2;a++)
        #pragma unroll
        for (int b=0;b<4;b++) acc[a][b] = (f32x4){0.f,0.f,0.f,0.f};
    for (int ks = 0; ks < 7; ks++){
        int r0_ = tid >> 2, c0 = (tid & 3) * 8;
        int r1_ = (tid + 256) >> 2, c1 = ((tid + 256) & 3) * 8;
        uint4 a0 = *(const uint4*)&Wn[(size_t)(m0 + r0_)*KC + ks*32 + c0];
        uint4 a1 = *(const uint4*)&Wn[(size_t)(m0 + r1_)*KC + ks*32 + c1];
        uint4 b0 = *(const uint4*)&Bt[(size_t)(n0 + (tid >> 2))*KC + ks*32 + (tid & 3)*8];
        __syncthreads();
        *(uint4*)&As[r0_][c0] = a0;
        *(uint4*)&As[r1_][c1] = a1;
        *(uint4*)&Bs[tid >> 2][(tid & 3)*8] = b0;
        __syncthreads();
        short8 av0 = *(const short8*)&As[wv*32 + lm][quad*8];
        short8 av1 = *(const short8*)&As[wv*32 + 16 + lm][quad*8];
        #pragma unroll
        for (int ns=0; ns<4; ns++){
            short8 bv = *(const short8*)&Bs[ns*16 + lm][quad*8];
            acc[0][ns] = __builtin_amdgcn_mfma_f32_16x16x32_bf16(av0, bv, acc[0][ns], 0,0,0);
            acc[1][ns] = __builtin_amdgcn_mfma_f32_16x16x32_bf16(av1, bv, acc[1][ns], 0,0,0);
        }
    }
    #pragma unroll
    for (int ms=0; ms<2; ms++)
      #pragma unroll
      for (int ns=0; ns<4; ns++){
        int n = n0 + ns*16 + lm;
        if (n < 200){
            float bv = bias[r*D_ + n];
            #pragma unroll
            for (int i=0;i<4;i++){
                int row = m0 + wv*32 + ms*16 + quad*4 + i;
                float v = acc[ms][ns][i] + wsum[row]*bv;
                XH[(size_t)row*KP + n] = f2b(eluf(v));
            }
        }
      }
}

// MFMA gate GEMM: C[16384,NP] = XH @ B2t[r]^T. 128x128 tile.
__global__ void __launch_bounds__(256) k_gemm(const unsigned short* __restrict__ XH,
        const unsigned short* __restrict__ B2t, unsigned short* __restrict__ C, int r){
    __shared__ unsigned short As[128][40];
    __shared__ unsigned short Bs[128][40];
    int tid = threadIdx.x;
    int m0 = ((int)blockIdx.x & 127) * 128;
    int n0 = ((int)blockIdx.x >> 7) * 128;
    const unsigned short* Bt = B2t + (size_t)r*NP*KP;
    int lane = tid & 63, wv = tid >> 6;
    int quad = lane >> 4, lm = lane & 15;
    f32x4 acc[2][8];
    #pragma unroll
    for (int a=0;a<2;a++)
        #pragma unroll
        for (int b=0;b<8;b++) acc[a][b] = (f32x4){0.f,0.f,0.f,0.f};
    for (int ks = 0; ks < 13; ks++){
        int r0_ = tid >> 2, c0 = (tid & 3) * 8;
        int r1_ = (tid + 256) >> 2, c1 = ((tid + 256) & 3) * 8;
        uint4 a0 = *(const uint4*)&XH[(size_t)(m0 + r0_)*KP + ks*32 + c0];
        uint4 a1 = *(const uint4*)&XH[(size_t)(m0 + r1_)*KP + ks*32 + c1];
        uint4 b0 = *(const uint4*)&Bt[(size_t)(n0 + r0_)*KP + ks*32 + c0];
        uint4 b1 = *(const uint4*)&Bt[(size_t)(n0 + r1_)*KP + ks*32 + c1];
        __syncthreads();
        *(uint4*)&As[r0_][c0] = a0;
        *(uint4*)&As[r1_][c1] = a1;
        *(uint4*)&Bs[r0_][c0] = b0;
        *(uint4*)&Bs[r1_][c1] = b1;
        __syncthreads();
        short8 av0 = *(const short8*)&As[wv*32 + lm][quad*8];
        short8 av1 = *(const short8*)&As[wv*32 + 16 + lm][quad*8];
        #pragma unroll
        for (int ns=0; ns<8; ns++){
            short8 bv = *(const short8*)&Bs[ns*16 + lm][quad*8];
            acc[0][ns] = __builtin_amdgcn_mfma_f32_16x16x32_bf16(av0, bv, acc[0][ns], 0,0,0);
            acc[1][ns] = __builtin_amdgcn_mfma_f32_16x16x32_bf16(av1, bv, acc[1][ns], 0,0,0);
        }
    }
    #pragma unroll
    for (int ms=0; ms<2; ms++)
      #pragma unroll
      for (int ns=0; ns<8; ns++)
        #pragma unroll
        for (int i=0;i<4;i++){
            int row = m0 + wv*32 + ms*16 + quad*4 + i;
            C[(size_t)row*NP + n0 + ns*16 + lm] = f2b(acc[ms][ns][i]);
        }
}

// GRU combine, wave-per-atom; GRU state lives in XH h-half (bf16). Writes cur16;
// fuses next-round s1/tb dots (r<2) or curdot (r==2).
__global__ void __launch_bounds__(256) k_gru2(const unsigned short* __restrict__ C,
        unsigned short* __restrict__ XH, unsigned short* __restrict__ cur16,
        const float* __restrict__ bih, const float* __restrict__ bhh,
        const float* __restrict__ W_align, const float* __restrict__ Wma, int r,
        float* __restrict__ s1, float* __restrict__ tb, float* __restrict__ curdot){
    int wv = threadIdx.x >> 6, lane = threadIdx.x & 63;
    int al = blockIdx.x*4 + wv;
    size_t base = (size_t)al*NP;
    const float* bi = bih + r*G3D_;
    const float* bh = bhh + r*G3D_;
    const float* Wa = W_align + (r+1)*2*D_;   // dereferenced only when r<2
    bool last = (r == R_-1);
    float a1 = 0.f, a2 = 0.f;
    for (int j = lane; j < D_; j += 64){
        float rsum = bu2f(C[base + j]);
        float zsum = bu2f(C[base + 200 + j]);
        float gin  = bu2f(C[base + 400 + j]);
        float ghn  = bu2f(C[base + 600 + j]);
        float rr = sigmf(rsum + bi[j] + bh[j]);
        float zz = sigmf(zsum + bi[D_+j] + bh[D_+j]);
        float nn = tanhf(gin + bi[2*D_+j] + rr*(ghn + bh[2*D_+j]));
        size_t hx = (size_t)al*KP + 200 + j;
        float hv = bu2f(XH[hx]);
        float hn = (1.f-zz)*nn + zz*hv;
        XH[hx] = f2b(hn);
        float cv = fmaxf(hn, 0.f);
        cur16[(size_t)al*KC + j] = f2b(cv);
        if (last){
            a1 += cv * Wma[D_+j];
        } else {
            a1 += cv * Wa[j];
            a2 += cv * Wa[D_+j];
        }
    }
    if (lane < 24) cur16[(size_t)al*KC + 200 + lane] = 0;
    for (int o=32;o>0;o>>=1){ a1 += __shfl_xor(a1,o); a2 += __shfl_xor(a2,o); }
    if (lane==0){
        if (last) curdot[al] = a1;
        else { s1[al] = a1; tb[al] = a2; }
    }
}

__device__ __forceinline__ float brSum(float v, float* s_red){
    for (int o=32;o>0;o>>=1) v += __shfl_xor(v,o);
    int lane = threadIdx.x & 63, wid = threadIdx.x >> 6;
    __syncthreads();
    if (lane==0) s_red[wid] = v;
    __syncthreads();
    float r = 0.f;
    int nw = blockDim.x >> 6;
    for (int i=0;i<nw;i++) r += s_red[i];
    return r;
}

__device__ __forceinline__ float brMax(float v, float* s_red){
    for (int o=32;o>0;o>>=1) v = fmaxf(v, __shfl_xor(v,o));
    int lane = threadIdx.x & 63, wid = threadIdx.x >> 6;
    __syncthreads();
    if (lane==0) s_red[wid] = v;
    __syncthreads();
    float r = s_red[0];
    int nw = blockDim.x >> 6;
    for (int i=1;i<nw;i++) r = fmaxf(r, s_red[i]);
    return r;
}

// molecule phase, 512 threads (8 waves): cur16 tile in LDS; serial loops split 2-way by chunk.
__global__ void __launch_bounds__(512) k_mol(const unsigned short* __restrict__ cur16,
    const float* __restrict__ curdot, const float* __restrict__ atom_mask,
    const float* __restrict__ Wma, const float* __restrict__ bma,
    const float* __restrict__ Wmt, const float* __restrict__ bmt,
    const unsigned short* __restrict__ mTi, const unsigned short* __restrict__ mTh,
    const float* __restrict__ mbih, const float* __restrict__ mbhh,
    const float* __restrict__ Wme, const float* __restrict__ bme,
    const float* __restrict__ Wout, const float* __restrict__ bout,
    void* __restrict__ out, const unsigned* __restrict__ amtag){
    int b = blockIdx.x, tid = threadIdx.x;
    int dq = tid & 255, cq = tid >> 8;      // chunk 0..1
    __shared__ unsigned short s_cur[L_*KC];    // 57344 B
    __shared__ float s_am[L_], s_neg[L_], s_cd[L_], s_w[L_];
    __shared__ float s_mf[D_], s_act[D_], s_wc[D_], s_ctx[D_];
    __shared__ float s_gi[G3D_], s_gh[G3D_];
    __shared__ float s_part[2][256];
    __shared__ float s_red[8];
    const uint4* src = (const uint4*)(cur16 + (size_t)b*L_*KC);
    for (int i = tid; i < L_*KC/8; i += 512) ((uint4*)s_cur)[i] = src[i];
    if (tid < L_){
        float am = atom_mask[b*L_ + tid];
        s_am[tid] = am;
        s_neg[tid] = (am == 0.f) ? NEGV : 0.f;
        s_cd[tid] = curdot[b*L_ + tid];
    }
    __syncthreads();
    {
        float acc = 0.f;
        if (dq < D_)
            for (int l=cq*64; l<cq*64+64; l++) acc += bu2f(s_cur[l*KC + dq]) * s_am[l];
        s_part[cq][dq] = acc;
        __syncthreads();
        if (tid < D_){
            float v = s_part[0][tid] + s_part[1][tid];
            s_mf[tid] = v; s_act[tid] = fmaxf(v, 0.f);
        }
        __syncthreads();
    }
    float bma0 = bma[0];
    for (int t=0;t<T_;t++){
        float p = (tid < D_) ? s_act[tid] * Wma[tid] : 0.f;
        float s1v = brSum(p, s_red);
        float sc = (tid < L_) ? (lreluf(s1v + s_cd[tid] + bma0) + s_neg[tid]) : -1e30f;
        float mx = brMax(sc, s_red);
        float e = (tid < L_) ? expf(sc - mx) : 0.f;
        float se = brSum(e, s_red);
        float wv_ = (tid < L_) ? e/se*s_am[tid] : 0.f;
        if (tid < L_) s_w[tid] = wv_;
        float wsm = brSum(wv_, s_red);
        __syncthreads();
        {
            float acc = 0.f;
            if (dq < D_)
                for (int l=cq*64; l<cq*64+64; l++) acc += s_w[l] * bu2f(s_cur[l*KC + dq]);
            s_part[cq][dq] = acc;
            __syncthreads();
            if (tid < D_) s_wc[tid] = s_part[0][tid] + s_part[1][tid];
            __syncthreads();
        }
        {
            float acc = 0.f;
            if (dq < D_)
                for (int k=cq*100; k<cq*100+100; k++) acc += s_wc[k] * Wmt[(size_t)k*D_ + dq];
            s_part[cq][dq] = acc;
            __syncthreads();
            if (tid < D_)
                s_ctx[tid] = eluf(s_part[0][tid] + s_part[1][tid] + wsm * bmt[tid]);
            __syncthreads();
        }
        for (int j=tid; j<G3D_; j+=512){
            float ai0=0.f, ai1=0.f, ah0=0.f, ah1=0.f;
            for (int k=0;k<D_;k+=2){
                ai0 += s_ctx[k]   * bu2f(mTi[(size_t)k*G3D_ + j]);
                ai1 += s_ctx[k+1] * bu2f(mTi[(size_t)(k+1)*G3D_ + j]);
                ah0 += s_mf[k]    * bu2f(mTh[(size_t)k*G3D_ + j]);
                ah1 += s_mf[k+1]  * bu2f(mTh[(size_t)(k+1)*G3D_ + j]);
            }
            s_gi[j] = ai0+ai1; s_gh[j] = ah0+ah1;
        }
        __syncthreads();
        if (tid < D_){
            int d = tid;
            float rr = sigmf(s_gi[d] + mbih[d] + s_gh[d] + mbhh[d]);
            float zz = sigmf(s_gi[D_+d] + mbih[D_+d] + s_gh[D_+d] + mbhh[D_+d]);
            float nn = tanhf(s_gi[2*D_+d] + mbih[2*D_+d] + rr*(s_gh[2*D_+d] + mbhh[2*D_+d]));
            float nm = (1.f-zz)*nn + zz*s_mf[d];
            s_mf[d] = nm; s_act[d] = fmaxf(nm, 0.f);
        }
        __syncthreads();
    }
    const float dd = (float)(R_ - 2);
    {
        float acc = 0.f;
        if (dq < D_)
            for (int k=cq*100; k<cq*100+100; k++){
                float mf = s_mf[k];
                acc += mf * Wme[(size_t)k*D_ + dq];
                acc += (mf + dd) * Wme[(size_t)(D_+k)*D_ + dq];
            }
        s_part[cq][dq] = acc;
        __syncthreads();
        float p = 0.f;
        if (tid < D_)
            p = (s_part[0][tid] + s_part[1][tid] + bme[tid]) * Wout[tid];
        float o = brSum(p, s_red);
        if (tid==0){
            o += bout[0];
            if (*amtag == FP32TAG) ((float*)out)[b] = o;
            else ((bf16*)out)[b] = __float2bfloat16(o);
        }
    }
}

extern "C" void kernel_launch(void* const* d_in, const int* in_sizes, int n_in,
                              void* d_out, int out_size, void* d_ws, size_t ws_size,
                              hipStream_t stream) {
    const int* adl = (const int*)d_in[2];
    const int* bdl = (const int*)d_in[3];
    const unsigned* amtag = (const unsigned*)d_in[4];

    static const int srcidx[NSEG] = {0,1,4,5,6,7,8,9,10,11,12,15,16,17,18,19,20,21,22,23,24,25,26,27,28};
    static const int segsz[NSEG]  = {638976,327680,16384,7800,200,9800,200,1200,3,120000,600,
                                     1800,1800,400,1,40000,200,120000,120000,600,600,80000,200,200,1};
    CvtArgs ca;
    int ofs[NSEG+1]; ofs[0] = 0;
    for (int i=0;i<NSEG;i++){ ca.src[i] = d_in[srcidx[i]]; ca.ofs[i] = ofs[i]; ofs[i+1] = ofs[i] + segsz[i]; }
    ca.ofs[NSEG] = ofs[NSEG];
    const int total = ofs[NSEG];           // 1488645

    // ws layout (floats; all offsets 16B aligned). ~60 MB total.
    float* ws   = (float*)d_ws;
    float* conv = ws;                                    // 1488648
    unsigned short* XH   = (unsigned short*)(conv + 1488648);    // BL_*KP sh
    unsigned short* B2t  = XH + (size_t)BL_*KP;                  // PREPB_N sh
    unsigned short* WatT = B2t + PREPB_N;                        // PREPW_N sh
    float* creg = (float*)(WatT + PREPW_N);              // C region: BL_*NP sh = 7340032 fl
    unsigned short* C = (unsigned short*)creg;
    unsigned short* wnei = (unsigned short*)creg;        // BL_*KC sh, overlays C head
    unsigned short* Q16  = (unsigned short*)creg + 3670016;      // B_*MB_*D_ sh (r0 only)
    unsigned short* P16  = Q16 + (size_t)B_*MB_*D_;              // BLD_ sh (r0 only)
    float* s1   = creg + 7340032;
    float* tb   = s1 + BL_;
    float* wsum = tb + BL_;
    float* curdot = wsum + BL_;                          // BL_
    unsigned short* mTi = (unsigned short*)(curdot + BL_);       // PREPM_N sh (bf16)
    unsigned short* mTh = mTi + PREPM_N;                         // PREPM_N sh
    unsigned short* cur16 = mTh + PREPM_N;                       // BL_*KC sh

    const float* c_atom  = conv + ofs[0];
    const float* c_bond  = conv + ofs[1];
    const float* c_amask = conv + ofs[2];
    const float* c_Watom = conv + ofs[3];
    const float* c_batom = conv + ofs[4];
    const float* c_Wnei  = conv + ofs[5];
    const float* c_bnei  = conv + ofs[6];
    const float* c_Walign= conv + ofs[7];
    const float* c_balign= conv + ofs[8];
    const float* c_batt  = conv + ofs[10];
    const float* c_bih   = conv + ofs[11];
    const float* c_bhh   = conv + ofs[12];
    const float* c_Wma   = conv + ofs[13];
    const float* c_bma   = conv + ofs[14];
    const float* c_Wmt   = conv + ofs[15];
    const float* c_bmt   = conv + ofs[16];
    const float* c_mbih  = conv + ofs[19];
    const float* c_mbhh  = conv + ofs[20];
    const float* c_Wme   = conv + ofs[21];
    const float* c_bme   = conv + ofs[22];
    const float* c_Wout  = conv + ofs[23];
    const float* c_bout  = conv + ofs[24];

    const int prep_total = total + PREPB_N + PREPW_N + PREPM_N;   // 2898885
    k_prep<<<(prep_total + 255)/256, 256, 0, stream>>>(ca, conv, d_in[13], d_in[14], B2t,
                                                       d_in[11], WatT, d_in[21], d_in[22],
                                                       mTi, mTh, amtag, total);
    k_qprep<<<(B_*MB_*D_ + 255)/256, 256, 0, stream>>>(c_bond, c_Wnei, Q16);
    k_init<<<BL_/4, 256, 0, stream>>>(c_atom, c_Watom, c_batom, c_Wnei, c_bnei, c_Walign,
                                      XH, P16, s1, tb);

    for (int r=0; r<R_; r++){
        k_attn<<<BL_/4, 256, 0, stream>>>(cur16, s1, tb, adl, bdl, P16, Q16,
                                          c_Walign, c_balign, r, wnei, wsum);
        k_ctxmfma<<<(BL_/128)*(NC/64), 256, 0, stream>>>(wnei, wsum, WatT, c_batt, r, XH);
        k_gemm<<<(BL_/128)*(NP/128), 256, 0, stream>>>(XH, B2t, C, r);
        k_gru2<<<BL_/4, 256, 0, stream>>>(C, XH, cur16, c_bih, c_bhh,
                                          c_Walign, c_Wma, r, s1, tb, curdot);
    }

    k_mol<<<B_, 512, 0, stream>>>(cur16, curdot, c_amask, c_Wma, c_bma, c_Wmt, c_bmt,
                                  mTi, mTh, c_mbih, c_mbhh, c_Wme, c_bme, c_Wout, c_bout,
                                  d_out, amtag);
}

// Round 15
// 494.103 us; speedup vs baseline: 1.1893x; 1.0161x over previous
//
#include <hip/hip_runtime.h>
#include <hip/hip_bf16.h>
#include <math.h>
#include <string.h>

#define B_ 128
#define L_ 128
#define N_ 6
#define FA_ 39
#define FB_ 10
#define D_ 200
#define MB_ 256
#define R_ 3
#define T_ 2
#define NEGV -9e8f
#define BL_ (B_*L_)        // 16384
#define BLD_ (BL_*D_)      // 3276800
#define G3D_ (3*D_)        // 600
#define FP32TAG 0x3F800000u
#define KP 416             // padded K for gate GEMM (400 -> 416 = 13*32)
#define NP 896             // padded N for gate GEMM (800 -> 896 = 7*128)
#define KC 224             // padded K for ctx GEMM (200 -> 224 = 7*32)
#define NC 256             // padded N for ctx GEMM (200 -> 256)

typedef __hip_bfloat16 bf16;
typedef __attribute__((ext_vector_type(8))) short short8;
typedef __attribute__((ext_vector_type(4))) float f32x4;

__device__ __forceinline__ float b2f(const bf16 x){ return __bfloat162float(x); }
__device__ __forceinline__ unsigned short f2b(float v){ bf16 t = __float2bfloat16(v); return *reinterpret_cast<unsigned short*>(&t); }
__device__ __forceinline__ float bu2f(unsigned short u){ unsigned x = ((unsigned)u)<<16; float f; memcpy(&f,&x,4); return f; }
__device__ __forceinline__ float lreluf(float x){ return x>=0.f ? x : 0.01f*x; }
__device__ __forceinline__ float eluf(float x){ return x>0.f ? x : expm1f(x); }
__device__ __forceinline__ float sigmf(float x){ return 1.f/(1.f+expf(-x)); }

#define NSEG 14
struct CvtArgs { const void* src[NSEG]; int ofs[NSEG+1]; };

#define PREPB_N (R_*NP*KP)     // 1118208
#define PREPW_N (R_*NC*KC)     // 172032
#define PREPM_N (D_*G3D_)      // 120000
#define PREPT_N 40000          // Wmt16
#define PREPE_N 80000          // Wme16
#define PREPQ_N (B_*MB_*D_)    // 6553600
#define CONV_N 23989

struct PrepArgs {
    CvtArgs cvt;
    const void *Wih, *Whh, *Watt, *mWih, *mWhh, *Wmt, *Wme;
    const void *bond, *Wnei, *atom, *Watom, *batom, *bnei, *Walign;
    float* conv;
    unsigned short *B2t, *WatT, *mTi, *mTh, *Wmt16, *Wme16, *Q16, *XH, *P16;
    float *s1, *tb;
    const unsigned* amtag;
    int ew_total;      // 8107829
    int ew_blocks;     // 31672
};

__device__ __forceinline__ float ldd(const void* p, size_t i, bool f32){
    return f32 ? ((const float*)p)[i] : b2f(((const bf16*)p)[i]);
}

// ONE prologue kernel: small-param convert, B2t, WatT, mTi/mTh, Wmt16, Wme16, Q16, and
// the fused per-atom init (atom_feature -> XH h-half + pad, P16, round-0 s1/tb dots).
// Init blocks read RAW inputs (dual-dtype) so there is no intra-kernel dependency.
__global__ void __launch_bounds__(256) k_prep(PrepArgs A){
    bool f32 = (*A.amtag == FP32TAG);
    int bid = blockIdx.x;
    if (bid < A.ew_blocks){
        int i = bid*256 + (int)threadIdx.x;
        if (i >= A.ew_total) return;
        if (i < CONV_N){
            int s = 0;
            while (i >= A.cvt.ofs[s+1]) s++;
            A.conv[i] = ldd(A.cvt.src[s], i - A.cvt.ofs[s], f32);
            return;
        }
        int i2 = i - CONV_N;
        if (i2 < PREPB_N){
            int kk = i2 % KP;
            int rest = i2 / KP;
            int n = rest % NP;
            int r = rest / NP;
            float v = 0.f;
            if (kk < 200){
                if (n < 600) v = ldd(A.Wih, ((size_t)(r*G3D_ + n))*D_ + kk, f32);
            } else if (kk < 400){
                int j = -1;
                if (n < 400) j = n;
                else if (n >= 600 && n < 800) j = n - 200;
                if (j >= 0) v = ldd(A.Whh, ((size_t)(r*G3D_ + j))*D_ + (kk-200), f32);
            }
            A.B2t[i2] = f2b(v);
            return;
        }
        int i3 = i2 - PREPB_N;
        if (i3 < PREPW_N){
            int kk = i3 % KC;
            int rest = i3 / KC;
            int n = rest % NC;
            int r = rest / NC;
            float v = 0.f;
            if (kk < 200 && n < 200) v = ldd(A.Watt, ((size_t)r*D_ + kk)*D_ + n, f32);
            A.WatT[i3] = f2b(v);
            return;
        }
        int i4 = i3 - PREPW_N;
        if (i4 < PREPM_N){
            int j = i4 % G3D_, k = i4 / G3D_;
            size_t si = (size_t)j*D_ + k;
            A.mTi[i4] = f2b(ldd(A.mWih, si, f32));
            A.mTh[i4] = f2b(ldd(A.mWhh, si, f32));
            return;
        }
        int i5 = i4 - PREPM_N;
        if (i5 < PREPT_N){
            A.Wmt16[i5] = f2b(ldd(A.Wmt, i5, f32));
            return;
        }
        int i6 = i5 - PREPT_N;
        if (i6 < PREPE_N){
            A.Wme16[i6] = f2b(ldd(A.Wme, i6, f32));
            return;
        }
        int i7 = i6 - PREPE_N;   // Q16 range
        {
            int d = i7 % D_;
            int row = i7 / D_;
            float acc = 0.f;
            if (f32){
                const float* br = (const float*)A.bond + (size_t)row*FB_;
                const float* Wb = (const float*)A.Wnei;
                #pragma unroll
                for (int k=0;k<FB_;k++) acc += br[k] * Wb[(FA_+k)*D_ + d];
            } else {
                const bf16* br = (const bf16*)A.bond + (size_t)row*FB_;
                const bf16* Wb = (const bf16*)A.Wnei;
                #pragma unroll
                for (int k=0;k<FB_;k++) acc += b2f(br[k]) * b2f(Wb[(FA_+k)*D_ + d]);
            }
            A.Q16[i7] = f2b(acc);
            return;
        }
    }
    // ---- init part: 4 atoms per block, one wave each ----
    int ib = bid - A.ew_blocks;
    int wv = threadIdx.x >> 6, lane = threadIdx.x & 63;
    int al = ib*4 + wv;
    float areg[FA_];
    if (f32){
        const float* a = (const float*)A.atom + (size_t)al*FA_;
        #pragma unroll
        for (int k=0;k<FA_;k++) areg[k] = a[k];
    } else {
        const bf16* a = (const bf16*)A.atom + (size_t)al*FA_;
        #pragma unroll
        for (int k=0;k<FA_;k++) areg[k] = b2f(a[k]);
    }
    float a1 = 0.f, a2 = 0.f;
    if (f32){
        const float* WA = (const float*)A.Watom;
        const float* WN = (const float*)A.Wnei;
        const float* ba = (const float*)A.batom;
        const float* bn = (const float*)A.bnei;
        const float* Wl = (const float*)A.Walign;
        for (int d = lane; d < D_; d += 64){
            float acc1 = ba[d], acc2 = bn[d];
            #pragma unroll
            for (int k=0;k<FA_;k++){
                acc1 += areg[k] * WA[k*D_ + d];
                acc2 += areg[k] * WN[k*D_ + d];
            }
            float v = lreluf(acc1);
            A.XH[(size_t)al*KP + 200 + d] = f2b(v);
            A.P16[(size_t)al*D_ + d] = f2b(acc2);
            a1 += v * Wl[d];
            a2 += v * Wl[D_ + d];
        }
    } else {
        const bf16* WA = (const bf16*)A.Watom;
        const bf16* WN = (const bf16*)A.Wnei;
        const bf16* ba = (const bf16*)A.batom;
        const bf16* bn = (const bf16*)A.bnei;
        const bf16* Wl = (const bf16*)A.Walign;
        for (int d = lane; d < D_; d += 64){
            float acc1 = b2f(ba[d]), acc2 = b2f(bn[d]);
            #pragma unroll
            for (int k=0;k<FA_;k++){
                acc1 += areg[k] * b2f(WA[k*D_ + d]);
                acc2 += areg[k] * b2f(WN[k*D_ + d]);
            }
            float v = lreluf(acc1);
            A.XH[(size_t)al*KP + 200 + d] = f2b(v);
            A.P16[(size_t)al*D_ + d] = f2b(acc2);
            a1 += v * b2f(Wl[d]);
            a2 += v * b2f(Wl[D_ + d]);
        }
    }
    if (lane < 16) A.XH[(size_t)al*KP + 400 + lane] = 0;
    for (int o=32;o>0;o>>=1){ a1 += __shfl_xor(a1,o); a2 += __shfl_xor(a2,o); }
    if (lane==0){ A.s1[al] = a1; A.tb[al] = a2; }
}

// attention (all rounds): softmax + weighted neighbor sum -> bf16 wnei (stride KC, zero pad).
// XCD-locality swizzle: mol = bid&127 so all 32 blocks of a molecule share one XCD L2.
__global__ void __launch_bounds__(256) k_attn(
        const unsigned short* __restrict__ cur16,
        const float* __restrict__ s1, const float* __restrict__ tb,
        const int* __restrict__ adl, const int* __restrict__ bdl,
        const unsigned short* __restrict__ P16, const unsigned short* __restrict__ Q16,
        const float* __restrict__ W_align, const float* __restrict__ b_align, int r,
        unsigned short* __restrict__ wnei, float* __restrict__ wsum){
    int bid = blockIdx.x;
    int mol = bid & (B_-1), chunk = bid >> 7;
    int wv = threadIdx.x >> 6, lane = threadIdx.x & 63;
    int al = mol*L_ + chunk*4 + wv;
    __shared__ float s_nei[4][N_][D_];

    int idxn[N_]; bool pad[N_];
    for (int n=0;n<N_;n++){ idxn[n] = adl[al*N_ + n]; pad[n] = (idxn[n] == L_-1); }

    float s2[N_];
    if (r == 0){
        for (int j = lane; j < N_*D_; j += 64){
            int n = j / D_, d = j - n*D_;
            int bd = bdl[al*N_ + n];
            float acc = bu2f(P16[((size_t)mol*L_ + idxn[n])*D_ + d])
                      + bu2f(Q16[((size_t)mol*MB_ + bd)*D_ + d]);
            s_nei[wv][n][d] = lreluf(acc);
        }
        const float* Wab = W_align + D_;
        for (int n=0;n<N_;n++){
            float acc = 0.f;
            for (int d=lane; d<D_; d+=64) acc += s_nei[wv][n][d] * Wab[d];
            for (int o=32;o>0;o>>=1) acc += __shfl_xor(acc,o);
            s2[n] = acc;
        }
    } else {
        float tmp = 0.f;
        if (lane < N_) tmp = tb[mol*L_ + idxn[lane]];
        for (int n=0;n<N_;n++) s2[n] = __shfl(tmp, n);
    }

    float s1v = s1[al];
    float bav = b_align[r];
    float a[N_]; float mx = -1e30f;
    for (int n=0;n<N_;n++){
        float v = lreluf(s1v + s2[n] + bav);
        if (pad[n]) v += NEGV;
        a[n] = v; mx = fmaxf(mx, v);
    }
    float w[N_]; float se = 0.f;
    for (int n=0;n<N_;n++){ float e = expf(a[n]-mx); w[n]=e; se += e; }
    float inv = 1.f/se; float wsv = 0.f;
    for (int n=0;n<N_;n++){ w[n] = pad[n] ? 0.f : w[n]*inv; wsv += w[n]; }

    if (r == 0){
        for (int d=lane; d<D_; d+=64){
            float acc = 0.f;
            #pragma unroll
            for (int n=0;n<N_;n++) acc += w[n] * s_nei[wv][n][d];
            wnei[(size_t)al*KC + d] = f2b(acc);
        }
    } else {
        for (int d=lane; d<D_; d+=64){
            float acc = 0.f;
            #pragma unroll
            for (int n=0;n<N_;n++) acc += w[n] * bu2f(cur16[((size_t)mol*L_ + idxn[n])*KC + d]);
            wnei[(size_t)al*KC + d] = f2b(acc);
        }
    }
    if (lane < 24) wnei[(size_t)al*KC + 200 + lane] = 0;
    if (lane==0) wsum[al] = wsv;
}

// MFMA ctx GEMM: elu(wnei[16384,KC] @ WatT[r]^T + wsum*bias) -> XH x-half. 128x64 tile.
__global__ void __launch_bounds__(256) k_ctxmfma(const unsigned short* __restrict__ Wn,
        const float* __restrict__ wsum, const unsigned short* __restrict__ WatT,
        const float* __restrict__ bias, int r, unsigned short* __restrict__ XH){
    __shared__ unsigned short As[128][40];
    __shared__ unsigned short Bs[64][40];
    int tid = threadIdx.x;
    int m0 = ((int)blockIdx.x & 127) * 128;
    int n0 = ((int)blockIdx.x >> 7) * 64;
    const unsigned short* Bt = WatT + (size_t)r*NC*KC;
    int lane = tid & 63, wv = tid >> 6;
    int quad = lane >> 4, lm = lane & 15;
    f32x4 acc[2][4];
    #pragma unroll
    for (int a=0;a<2;a++)
        #pragma unroll
        for (int b=0;b<4;b++) acc[a][b] = (f32x4){0.f,0.f,0.f,0.f};
    for (int ks = 0; ks < 7; ks++){
        int r0_ = tid >> 2, c0 = (tid & 3) * 8;
        int r1_ = (tid + 256) >> 2, c1 = ((tid + 256) & 3) * 8;
        uint4 a0 = *(const uint4*)&Wn[(size_t)(m0 + r0_)*KC + ks*32 + c0];
        uint4 a1 = *(const uint4*)&Wn[(size_t)(m0 + r1_)*KC + ks*32 + c1];
        uint4 b0 = *(const uint4*)&Bt[(size_t)(n0 + (tid >> 2))*KC + ks*32 + (tid & 3)*8];
        __syncthreads();
        *(uint4*)&As[r0_][c0] = a0;
        *(uint4*)&As[r1_][c1] = a1;
        *(uint4*)&Bs[tid >> 2][(tid & 3)*8] = b0;
        __syncthreads();
        short8 av0 = *(const short8*)&As[wv*32 + lm][quad*8];
        short8 av1 = *(const short8*)&As[wv*32 + 16 + lm][quad*8];
        #pragma unroll
        for (int ns=0; ns<4; ns++){
            short8 bv = *(const short8*)&Bs[ns*16 + lm][quad*8];
            acc[0][ns] = __builtin_amdgcn_mfma_f32_16x16x32_bf16(av0, bv, acc[0][ns], 0,0,0);
            acc[1][ns] = __builtin_amdgcn_mfma_f32_16x16x32_bf16(av1, bv, acc[1][ns], 0,0,0);
        }
    }
    #pragma unroll
    for (int ms=0; ms<2; ms++)
      #pragma unroll
      for (int ns=0; ns<4; ns++){
        int n = n0 + ns*16 + lm;
        if (n < 200){
            float bv = bias[r*D_ + n];
            #pragma unroll
            for (int i=0;i<4;i++){
                int row = m0 + wv*32 + ms*16 + quad*4 + i;
                float v = acc[ms][ns][i] + wsum[row]*bv;
                XH[(size_t)row*KP + n] = f2b(eluf(v));
            }
        }
      }
}

// MFMA gate GEMM: C[16384,NP] = XH @ B2t[r]^T. 128x128 tile.
__global__ void __launch_bounds__(256) k_gemm(const unsigned short* __restrict__ XH,
        const unsigned short* __restrict__ B2t, unsigned short* __restrict__ C, int r){
    __shared__ unsigned short As[128][40];
    __shared__ unsigned short Bs[128][40];
    int tid = threadIdx.x;
    int m0 = ((int)blockIdx.x & 127) * 128;
    int n0 = ((int)blockIdx.x >> 7) * 128;
    const unsigned short* Bt = B2t + (size_t)r*NP*KP;
    int lane = tid & 63, wv = tid >> 6;
    int quad = lane >> 4, lm = lane & 15;
    f32x4 acc[2][8];
    #pragma unroll
    for (int a=0;a<2;a++)
        #pragma unroll
        for (int b=0;b<8;b++) acc[a][b] = (f32x4){0.f,0.f,0.f,0.f};
    for (int ks = 0; ks < 13; ks++){
        int r0_ = tid >> 2, c0 = (tid & 3) * 8;
        int r1_ = (tid + 256) >> 2, c1 = ((tid + 256) & 3) * 8;
        uint4 a0 = *(const uint4*)&XH[(size_t)(m0 + r0_)*KP + ks*32 + c0];
        uint4 a1 = *(const uint4*)&XH[(size_t)(m0 + r1_)*KP + ks*32 + c1];
        uint4 b0 = *(const uint4*)&Bt[(size_t)(n0 + r0_)*KP + ks*32 + c0];
        uint4 b1 = *(const uint4*)&Bt[(size_t)(n0 + r1_)*KP + ks*32 + c1];
        __syncthreads();
        *(uint4*)&As[r0_][c0] = a0;
        *(uint4*)&As[r1_][c1] = a1;
        *(uint4*)&Bs[r0_][c0] = b0;
        *(uint4*)&Bs[r1_][c1] = b1;
        __syncthreads();
        short8 av0 = *(const short8*)&As[wv*32 + lm][quad*8];
        short8 av1 = *(const short8*)&As[wv*32 + 16 + lm][quad*8];
        #pragma unroll
        for (int ns=0; ns<8; ns++){
            short8 bv = *(const short8*)&Bs[ns*16 + lm][quad*8];
            acc[0][ns] = __builtin_amdgcn_mfma_f32_16x16x32_bf16(av0, bv, acc[0][ns], 0,0,0);
            acc[1][ns] = __builtin_amdgcn_mfma_f32_16x16x32_bf16(av1, bv, acc[1][ns], 0,0,0);
        }
    }
    #pragma unroll
    for (int ms=0; ms<2; ms++)
      #pragma unroll
      for (int ns=0; ns<8; ns++)
        #pragma unroll
        for (int i=0;i<4;i++){
            int row = m0 + wv*32 + ms*16 + quad*4 + i;
            C[(size_t)row*NP + n0 + ns*16 + lm] = f2b(acc[ms][ns][i]);
        }
}

// GRU combine, wave-per-atom; GRU state lives in XH h-half (bf16). Writes cur16;
// fuses next-round s1/tb dots (r<2) or curdot (r==2).
__global__ void __launch_bounds__(256) k_gru2(const unsigned short* __restrict__ C,
        unsigned short* __restrict__ XH, unsigned short* __restrict__ cur16,
        const float* __restrict__ bih, const float* __restrict__ bhh,
        const float* __restrict__ W_align, const float* __restrict__ Wma, int r,
        float* __restrict__ s1, float* __restrict__ tb, float* __restrict__ curdot){
    int wv = threadIdx.x >> 6, lane = threadIdx.x & 63;
    int al = blockIdx.x*4 + wv;
    size_t base = (size_t)al*NP;
    const float* bi = bih + r*G3D_;
    const float* bh = bhh + r*G3D_;
    const float* Wa = W_align + (r+1)*2*D_;   // dereferenced only when r<2
    bool last = (r == R_-1);
    float a1 = 0.f, a2 = 0.f;
    for (int j = lane; j < D_; j += 64){
        float rsum = bu2f(C[base + j]);
        float zsum = bu2f(C[base + 200 + j]);
        float gin  = bu2f(C[base + 400 + j]);
        float ghn  = bu2f(C[base + 600 + j]);
        float rr = sigmf(rsum + bi[j] + bh[j]);
        float zz = sigmf(zsum + bi[D_+j] + bh[D_+j]);
        float nn = tanhf(gin + bi[2*D_+j] + rr*(ghn + bh[2*D_+j]));
        size_t hx = (size_t)al*KP + 200 + j;
        float hv = bu2f(XH[hx]);
        float hn = (1.f-zz)*nn + zz*hv;
        XH[hx] = f2b(hn);
        float cv = fmaxf(hn, 0.f);
        cur16[(size_t)al*KC + j] = f2b(cv);
        if (last){
            a1 += cv * Wma[D_+j];
        } else {
            a1 += cv * Wa[j];
            a2 += cv * Wa[D_+j];
        }
    }
    if (lane < 24) cur16[(size_t)al*KC + 200 + lane] = 0;
    for (int o=32;o>0;o>>=1){ a1 += __shfl_xor(a1,o); a2 += __shfl_xor(a2,o); }
    if (lane==0){
        if (last) curdot[al] = a1;
        else { s1[al] = a1; tb[al] = a2; }
    }
}

__device__ __forceinline__ float brSum(float v, float* s_red){
    for (int o=32;o>0;o>>=1) v += __shfl_xor(v,o);
    int lane = threadIdx.x & 63, wid = threadIdx.x >> 6;
    __syncthreads();
    if (lane==0) s_red[wid] = v;
    __syncthreads();
    float r = 0.f;
    int nw = blockDim.x >> 6;
    for (int i=0;i<nw;i++) r += s_red[i];
    return r;
}

__device__ __forceinline__ float brMax(float v, float* s_red){
    for (int o=32;o>0;o>>=1) v = fmaxf(v, __shfl_xor(v,o));
    int lane = threadIdx.x & 63, wid = threadIdx.x >> 6;
    __syncthreads();
    if (lane==0) s_red[wid] = v;
    __syncthreads();
    float r = s_red[0];
    int nw = blockDim.x >> 6;
    for (int i=1;i<nw;i++) r = fmaxf(r, s_red[i]);
    return r;
}

// molecule phase, 512 threads (8 waves): cur16 tile in LDS; 2-way chunk splits; bf16 weights;
// gates GEMV unroll-4 (8 independent chains) for latency hiding at 2 waves/SIMD.
__global__ void __launch_bounds__(512) k_mol(const unsigned short* __restrict__ cur16,
    const float* __restrict__ curdot, const float* __restrict__ atom_mask,
    const float* __restrict__ Wma, const float* __restrict__ bma,
    const unsigned short* __restrict__ Wmt16, const float* __restrict__ bmt,
    const unsigned short* __restrict__ mTi, const unsigned short* __restrict__ mTh,
    const float* __restrict__ mbih, const float* __restrict__ mbhh,
    const unsigned short* __restrict__ Wme16, const float* __restrict__ bme,
    const float* __restrict__ Wout, const float* __restrict__ bout,
    void* __restrict__ out, const unsigned* __restrict__ amtag){
    int b = blockIdx.x, tid = threadIdx.x;
    int dq = tid & 255, cq = tid >> 8;      // chunk 0..1
    __shared__ unsigned short s_cur[L_*KC];    // 57344 B
    __shared__ float s_am[L_], s_neg[L_], s_cd[L_], s_w[L_];
    __shared__ float s_mf[D_], s_act[D_], s_wc[D_], s_ctx[D_];
    __shared__ float s_gi[G3D_], s_gh[G3D_];
    __shared__ float s_part[2][256];
    __shared__ float s_red[8];
    const uint4* src = (const uint4*)(cur16 + (size_t)b*L_*KC);
    for (int i = tid; i < L_*KC/8; i += 512) ((uint4*)s_cur)[i] = src[i];
    if (tid < L_){
        float am = atom_mask[b*L_ + tid];
        s_am[tid] = am;
        s_neg[tid] = (am == 0.f) ? NEGV : 0.f;
        s_cd[tid] = curdot[b*L_ + tid];
    }
    __syncthreads();
    {
        float a0 = 0.f, a1 = 0.f;
        if (dq < D_)
            for (int l=cq*64; l<cq*64+64; l+=2){
                a0 += bu2f(s_cur[l*KC + dq]) * s_am[l];
                a1 += bu2f(s_cur[(l+1)*KC + dq]) * s_am[l+1];
            }
        s_part[cq][dq] = a0 + a1;
        __syncthreads();
        if (tid < D_){
            float v = s_part[0][tid] + s_part[1][tid];
            s_mf[tid] = v; s_act[tid] = fmaxf(v, 0.f);
        }
        __syncthreads();
    }
    float bma0 = bma[0];
    for (int t=0;t<T_;t++){
        float p = (tid < D_) ? s_act[tid] * Wma[tid] : 0.f;
        float s1v = brSum(p, s_red);
        float sc = (tid < L_) ? (lreluf(s1v + s_cd[tid] + bma0) + s_neg[tid]) : -1e30f;
        float mx = brMax(sc, s_red);
        float e = (tid < L_) ? expf(sc - mx) : 0.f;
        float se = brSum(e, s_red);
        float wv_ = (tid < L_) ? e/se*s_am[tid] : 0.f;
        if (tid < L_) s_w[tid] = wv_;
        float wsm = brSum(wv_, s_red);
        __syncthreads();
        {
            float a0 = 0.f, a1 = 0.f;
            if (dq < D_)
                for (int l=cq*64; l<cq*64+64; l+=2){
                    a0 += s_w[l] * bu2f(s_cur[l*KC + dq]);
                    a1 += s_w[l+1] * bu2f(s_cur[(l+1)*KC + dq]);
                }
            s_part[cq][dq] = a0 + a1;
            __syncthreads();
            if (tid < D_) s_wc[tid] = s_part[0][tid] + s_part[1][tid];
            __syncthreads();
        }
        {
            float a0 = 0.f, a1 = 0.f;
            if (dq < D_)
                for (int k=cq*100; k<cq*100+100; k+=2){
                    a0 += s_wc[k] * bu2f(Wmt16[(size_t)k*D_ + dq]);
                    a1 += s_wc[k+1] * bu2f(Wmt16[(size_t)(k+1)*D_ + dq]);
                }
            s_part[cq][dq] = a0 + a1;
            __syncthreads();
            if (tid < D_)
                s_ctx[tid] = eluf(s_part[0][tid] + s_part[1][tid] + wsm * bmt[tid]);
            __syncthreads();
        }
        for (int j=tid; j<G3D_; j+=512){
            float ai0=0.f, ai1=0.f, ai2=0.f, ai3=0.f;
            float ah0=0.f, ah1=0.f, ah2=0.f, ah3=0.f;
            for (int k=0;k<D_;k+=4){
                ai0 += s_ctx[k]   * bu2f(mTi[(size_t)k*G3D_ + j]);
                ai1 += s_ctx[k+1] * bu2f(mTi[(size_t)(k+1)*G3D_ + j]);
                ai2 += s_ctx[k+2] * bu2f(mTi[(size_t)(k+2)*G3D_ + j]);
                ai3 += s_ctx[k+3] * bu2f(mTi[(size_t)(k+3)*G3D_ + j]);
                ah0 += s_mf[k]    * bu2f(mTh[(size_t)k*G3D_ + j]);
                ah1 += s_mf[k+1]  * bu2f(mTh[(size_t)(k+1)*G3D_ + j]);
                ah2 += s_mf[k+2]  * bu2f(mTh[(size_t)(k+2)*G3D_ + j]);
                ah3 += s_mf[k+3]  * bu2f(mTh[(size_t)(k+3)*G3D_ + j]);
            }
            s_gi[j] = (ai0+ai1)+(ai2+ai3); s_gh[j] = (ah0+ah1)+(ah2+ah3);
        }
        __syncthreads();
        if (tid < D_){
            int d = tid;
            float rr = sigmf(s_gi[d] + mbih[d] + s_gh[d] + mbhh[d]);
            float zz = sigmf(s_gi[D_+d] + mbih[D_+d] + s_gh[D_+d] + mbhh[D_+d]);
            float nn = tanhf(s_gi[2*D_+d] + mbih[2*D_+d] + rr*(s_gh[2*D_+d] + mbhh[2*D_+d]));
            float nm = (1.f-zz)*nn + zz*s_mf[d];
            s_mf[d] = nm; s_act[d] = fmaxf(nm, 0.f);
        }
        __syncthreads();
    }
    const float dd = (float)(R_ - 2);
    {
        float a0 = 0.f, a1 = 0.f;
        if (dq < D_)
            for (int k=cq*100; k<cq*100+100; k+=2){
                float mf0 = s_mf[k], mf1 = s_mf[k+1];
                a0 += mf0 * bu2f(Wme16[(size_t)k*D_ + dq])
                    + (mf0 + dd) * bu2f(Wme16[(size_t)(D_+k)*D_ + dq]);
                a1 += mf1 * bu2f(Wme16[(size_t)(k+1)*D_ + dq])
                    + (mf1 + dd) * bu2f(Wme16[(size_t)(D_+k+1)*D_ + dq]);
            }
        s_part[cq][dq] = a0 + a1;
        __syncthreads();
        float p = 0.f;
        if (tid < D_)
            p = (s_part[0][tid] + s_part[1][tid] + bme[tid]) * Wout[tid];
        float o = brSum(p, s_red);
        if (tid==0){
            o += bout[0];
            if (*amtag == FP32TAG) ((float*)out)[b] = o;
            else ((bf16*)out)[b] = __float2bfloat16(o);
        }
    }
}

extern "C" void kernel_launch(void* const* d_in, const int* in_sizes, int n_in,
                              void* d_out, int out_size, void* d_ws, size_t ws_size,
                              hipStream_t stream) {
    const int* adl = (const int*)d_in[2];
    const int* bdl = (const int*)d_in[3];
    const unsigned* amtag = (const unsigned*)d_in[4];

    // small-param convert segments (d_in index -> element count)
    static const int srcidx[NSEG] = {4,9,10,12,15,16,17,18,20,23,24,26,27,28};
    static const int segsz[NSEG]  = {16384,1200,3,600,1800,1800,400,1,200,600,600,200,200,1};
    CvtArgs ca;
    int ofs[NSEG+1]; ofs[0] = 0;
    for (int i=0;i<NSEG;i++){ ca.src[i] = d_in[srcidx[i]]; ca.ofs[i] = ofs[i]; ofs[i+1] = ofs[i] + segsz[i]; }
    ca.ofs[NSEG] = ofs[NSEG];   // 23989

    // ws layout. ~54 MB total.
    float* ws   = (float*)d_ws;
    float* conv = ws;                                            // 24000 fl
    unsigned short* XH    = (unsigned short*)(conv + 24000);     // BL_*KP sh
    unsigned short* B2t   = XH + (size_t)BL_*KP;                 // PREPB_N sh
    unsigned short* WatT  = B2t + PREPB_N;                       // PREPW_N sh
    unsigned short* mTi   = WatT + PREPW_N;                      // PREPM_N sh
    unsigned short* mTh   = mTi + PREPM_N;                       // PREPM_N sh
    unsigned short* Wmt16 = mTh + PREPM_N;                       // PREPT_N sh
    unsigned short* Wme16 = Wmt16 + PREPT_N;                     // PREPE_N sh
    unsigned short* cur16 = Wme16 + PREPE_N;                     // BL_*KC sh
    unsigned short* creg  = cur16 + (size_t)BL_*KC;              // C region: BL_*NP sh
    unsigned short* C = creg;
    unsigned short* wnei = creg;                                 // BL_*KC sh overlay
    unsigned short* Q16  = creg + (size_t)BL_*KC;                // PREPQ_N sh overlay
    unsigned short* P16  = Q16 + PREPQ_N;                        // BLD_ sh overlay
    float* s1     = (float*)(creg + (size_t)BL_*NP);
    float* tb     = s1 + BL_;
    float* wsum   = tb + BL_;
    float* curdot = wsum + BL_;

    const float* c_amask = conv + ofs[0];
    const float* c_Walign= conv + ofs[1];
    const float* c_balign= conv + ofs[2];
    const float* c_batt  = conv + ofs[3];
    const float* c_bih   = conv + ofs[4];
    const float* c_bhh   = conv + ofs[5];
    const float* c_Wma   = conv + ofs[6];
    const float* c_bma   = conv + ofs[7];
    const float* c_bmt   = conv + ofs[8];
    const float* c_mbih  = conv + ofs[9];
    const float* c_mbhh  = conv + ofs[10];
    const float* c_bme   = conv + ofs[11];
    const float* c_Wout  = conv + ofs[12];
    const float* c_bout  = conv + ofs[13];

    PrepArgs A;
    A.cvt = ca;
    A.Wih = d_in[13]; A.Whh = d_in[14]; A.Watt = d_in[11];
    A.mWih = d_in[21]; A.mWhh = d_in[22]; A.Wmt = d_in[19]; A.Wme = d_in[25];
    A.bond = d_in[1]; A.Wnei = d_in[7]; A.atom = d_in[0];
    A.Watom = d_in[5]; A.batom = d_in[6]; A.bnei = d_in[8]; A.Walign = d_in[9];
    A.conv = conv;
    A.B2t = B2t; A.WatT = WatT; A.mTi = mTi; A.mTh = mTh;
    A.Wmt16 = Wmt16; A.Wme16 = Wme16; A.Q16 = Q16; A.XH = XH; A.P16 = P16;
    A.s1 = s1; A.tb = tb;
    A.amtag = amtag;
    A.ew_total = CONV_N + PREPB_N + PREPW_N + PREPM_N + PREPT_N + PREPE_N + PREPQ_N; // 8107829
    A.ew_blocks = (A.ew_total + 255) / 256;   // 31672
    int grid = A.ew_blocks + BL_/4;           // + 4096 init blocks

    k_prep<<<grid, 256, 0, stream>>>(A);

    for (int r=0; r<R_; r++){
        k_attn<<<BL_/4, 256, 0, stream>>>(cur16, s1, tb, adl, bdl, P16, Q16,
                                          c_Walign, c_balign, r, wnei, wsum);
        k_ctxmfma<<<(BL_/128)*(NC/64), 256, 0, stream>>>(wnei, wsum, WatT, c_batt, r, XH);
        k_gemm<<<(BL_/128)*(NP/128), 256, 0, stream>>>(XH, B2t, C, r);
        k_gru2<<<BL_/4, 256, 0, stream>>>(C, XH, cur16, c_bih, c_bhh,
                                          c_Walign, c_Wma, r, s1, tb, curdot);
    }

    k_mol<<<B_, 512, 0, stream>>>(cur16, curdot, c_amask, c_Wma, c_bma, Wmt16, c_bmt,
                                  mTi, mTh, c_mbih, c_mbhh, Wme16, c_bme, c_Wout, c_bout,
                                  d_out, amtag);
}

// Round 16
// 454.533 us; speedup vs baseline: 1.2928x; 1.0871x over previous
//
#include <hip/hip_runtime.h>
#include <hip/hip_bf16.h>
#include <math.h>
#include <string.h>

#define B_ 128
#define L_ 128
#define N_ 6
#define FA_ 39
#define FB_ 10
#define D_ 200
#define MB_ 256
#define R_ 3
#define T_ 2
#define NEGV -9e8f
#define BL_ (B_*L_)        // 16384
#define G3D_ (3*D_)        // 600
#define FP32TAG 0x3F800000u
#define KP 416             // padded K for gate GEMM
#define NP 896             // padded N for gate GEMM (7*128)
#define KC 224             // padded K for ctx GEMM (7*32)
#define NC 256             // padded N for ctx GEMM

typedef __hip_bfloat16 bf16;
typedef __attribute__((ext_vector_type(8))) short short8;
typedef __attribute__((ext_vector_type(4))) float f32x4;

__device__ __forceinline__ float b2f(const bf16 x){ return __bfloat162float(x); }
__device__ __forceinline__ unsigned short f2b(float v){ bf16 t = __float2bfloat16(v); return *reinterpret_cast<unsigned short*>(&t); }
__device__ __forceinline__ float bu2f(unsigned short u){ unsigned x = ((unsigned)u)<<16; float f; memcpy(&f,&x,4); return f; }
__device__ __forceinline__ float lreluf(float x){ return x>=0.f ? x : 0.01f*x; }
__device__ __forceinline__ float eluf(float x){ return x>0.f ? x : expm1f(x); }
__device__ __forceinline__ float sigmf(float x){ return 1.f/(1.f+expf(-x)); }

#define NSEG 14
struct CvtArgs { const void* src[NSEG]; int ofs[NSEG+1]; };

#define PREPB_N (R_*NP*KP)     // 1118208
#define PREPW_N (R_*NC*KC)     // 172032
#define PREPM_N (D_*G3D_)      // 120000
#define PREPT_N 40000          // Wmt16
#define PREPE_N 80000          // Wme16
#define CONV_N 23989
#define XHPAD_N (BL_*16)       // 262144
#define AROWS (BL_ + B_*MB_)   // 49152
#define A_N (AROWS*64)         // 3145728
#define BI_N (448*64)          // 28672

struct PrepArgs {
    CvtArgs cvt;
    const void *Wih, *Whh, *Watt, *mWih, *mWhh, *Wmt, *Wme;
    const void *bond, *Wnei, *atom, *Watom;
    float* conv;
    unsigned short *B2t, *WatT, *mTi, *mTh, *Wmt16, *Wme16, *XH, *A16, *Bi16;
    const unsigned* amtag;
    int ew_total;
};

__device__ __forceinline__ float ldd(const void* p, size_t i, bool f32){
    return f32 ? ((const float*)p)[i] : b2f(((const bf16*)p)[i]);
}

// prologue elementwise: small-param convert + all weight repacks + XH pad + A16/Bi16 packing
__global__ void __launch_bounds__(256) k_prep(PrepArgs A){
    bool f32 = (*A.amtag == FP32TAG);
    int i = blockIdx.x*256 + (int)threadIdx.x;
    if (i >= A.ew_total) return;
    if (i < CONV_N){
        int s = 0;
        while (i >= A.cvt.ofs[s+1]) s++;
        A.conv[i] = ldd(A.cvt.src[s], i - A.cvt.ofs[s], f32);
        return;
    }
    int i2 = i - CONV_N;
    if (i2 < PREPB_N){
        int kk = i2 % KP;
        int rest = i2 / KP;
        int n = rest % NP;
        int r = rest / NP;
        float v = 0.f;
        if (kk < 200){
            if (n < 600) v = ldd(A.Wih, ((size_t)(r*G3D_ + n))*D_ + kk, f32);
        } else if (kk < 400){
            int j = -1;
            if (n < 400) j = n;
            else if (n >= 600 && n < 800) j = n - 200;
            if (j >= 0) v = ldd(A.Whh, ((size_t)(r*G3D_ + j))*D_ + (kk-200), f32);
        }
        A.B2t[i2] = f2b(v);
        return;
    }
    int i3 = i2 - PREPB_N;
    if (i3 < PREPW_N){
        int kk = i3 % KC;
        int rest = i3 / KC;
        int n = rest % NC;
        int r = rest / NC;
        float v = 0.f;
        if (kk < 200 && n < 200) v = ldd(A.Watt, ((size_t)r*D_ + kk)*D_ + n, f32);
        A.WatT[i3] = f2b(v);
        return;
    }
    int i4 = i3 - PREPW_N;
    if (i4 < PREPM_N){
        int j = i4 % G3D_, k = i4 / G3D_;
        size_t si = (size_t)j*D_ + k;
        A.mTi[i4] = f2b(ldd(A.mWih, si, f32));
        A.mTh[i4] = f2b(ldd(A.mWhh, si, f32));
        return;
    }
    int i5 = i4 - PREPM_N;
    if (i5 < PREPT_N){
        A.Wmt16[i5] = f2b(ldd(A.Wmt, i5, f32));
        return;
    }
    int i6 = i5 - PREPT_N;
    if (i6 < PREPE_N){
        A.Wme16[i6] = f2b(ldd(A.Wme, i6, f32));
        return;
    }
    int i7 = i6 - PREPE_N;
    if (i7 < XHPAD_N){
        int al = i7 >> 4, j = i7 & 15;
        A.XH[(size_t)al*KP + 400 + j] = 0;
        return;
    }
    int i8 = i7 - XHPAD_N;
    if (i8 < A_N){
        int row = i8 >> 6, k = i8 & 63;
        float v = 0.f;
        if (row < BL_){
            if (k < FA_) v = ldd(A.atom, (size_t)row*FA_ + k, f32);
        } else {
            int rb = row - BL_;
            if (k >= FA_ && k < FA_+FB_) v = ldd(A.bond, (size_t)rb*FB_ + (k-FA_), f32);
        }
        A.A16[i8] = f2b(v);
        return;
    }
    int i9 = i8 - A_N;
    if (i9 < BI_N){
        int n = i9 >> 6, k = i9 & 63;
        float v = 0.f;
        if (n < 200){
            if (k < FA_) v = ldd(A.Watom, (size_t)k*D_ + n, f32);
        } else if (n < 400){
            if (k < FA_+FB_) v = ldd(A.Wnei, (size_t)k*D_ + (n-200), f32);
        }
        A.Bi16[i9] = f2b(v);
    }
}

// MFMA init GEMM: C[49152,448] = A16 @ Bi16^T. Atom rows -> XH h-half (lrelu+b_atom) and
// P16 (+b_nei); bond rows -> Q16. 128x64 tile, K=64 (2 steps).
__global__ void __launch_bounds__(256) k_initmm(const unsigned short* __restrict__ A16,
        const unsigned short* __restrict__ Bi16,
        const void* __restrict__ batom, const void* __restrict__ bnei,
        unsigned short* __restrict__ XH, unsigned short* __restrict__ P16,
        unsigned short* __restrict__ Q16, const unsigned* __restrict__ amtag){
    __shared__ unsigned short As[128][40];
    __shared__ unsigned short Bs[64][40];
    bool f32 = (*amtag == FP32TAG);
    int tid = threadIdx.x;
    int mt = (int)blockIdx.x / 7, nt = (int)blockIdx.x % 7;
    int m0 = mt*128, n0 = nt*64;
    if (m0 >= BL_ && n0 + 64 <= 200) return;   // bond rows x atom-feature cols: all dead
    int lane = tid & 63, wv = tid >> 6;
    int quad = lane >> 4, lm = lane & 15;
    f32x4 acc[2][4];
    #pragma unroll
    for (int a=0;a<2;a++)
        #pragma unroll
        for (int b=0;b<4;b++) acc[a][b] = (f32x4){0.f,0.f,0.f,0.f};
    for (int ks = 0; ks < 2; ks++){
        int r0_ = tid >> 2, c0 = (tid & 3) * 8;
        int r1_ = (tid + 256) >> 2, c1 = ((tid + 256) & 3) * 8;
        uint4 a0 = *(const uint4*)&A16[(size_t)(m0 + r0_)*64 + ks*32 + c0];
        uint4 a1 = *(const uint4*)&A16[(size_t)(m0 + r1_)*64 + ks*32 + c1];
        uint4 b0 = *(const uint4*)&Bi16[(size_t)(n0 + (tid >> 2))*64 + ks*32 + (tid & 3)*8];
        __syncthreads();
        *(uint4*)&As[r0_][c0] = a0;
        *(uint4*)&As[r1_][c1] = a1;
        *(uint4*)&Bs[tid >> 2][(tid & 3)*8] = b0;
        __syncthreads();
        short8 av0 = *(const short8*)&As[wv*32 + lm][quad*8];
        short8 av1 = *(const short8*)&As[wv*32 + 16 + lm][quad*8];
        #pragma unroll
        for (int ns=0; ns<4; ns++){
            short8 bv = *(const short8*)&Bs[ns*16 + lm][quad*8];
            acc[0][ns] = __builtin_amdgcn_mfma_f32_16x16x32_bf16(av0, bv, acc[0][ns], 0,0,0);
            acc[1][ns] = __builtin_amdgcn_mfma_f32_16x16x32_bf16(av1, bv, acc[1][ns], 0,0,0);
        }
    }
    #pragma unroll
    for (int ms=0; ms<2; ms++)
      #pragma unroll
      for (int ns=0; ns<4; ns++){
        int n = n0 + ns*16 + lm;
        #pragma unroll
        for (int i=0;i<4;i++){
            int row = m0 + wv*32 + ms*16 + quad*4 + i;
            float v = acc[ms][ns][i];
            if (row < BL_){
                if (n < 200){
                    XH[(size_t)row*KP + 200 + n] = f2b(lreluf(v + ldd(batom, n, f32)));
                } else if (n < 400){
                    P16[(size_t)row*D_ + (n-200)] = f2b(v + ldd(bnei, n-200, f32));
                }
            } else if (n >= 200 && n < 400){
                Q16[(size_t)(row-BL_)*D_ + (n-200)] = f2b(v);
            }
        }
      }
}

// attention (all rounds): softmax + weighted neighbor sum -> bf16 wnei (stride KC, zero pad).
// XCD-locality swizzle: mol = bid&127. r0: s1 computed inline from XH h-half.
__global__ void __launch_bounds__(256) k_attn(
        const unsigned short* __restrict__ cur16, const unsigned short* __restrict__ XH,
        const float* __restrict__ s1, const float* __restrict__ tb,
        const int* __restrict__ adl, const int* __restrict__ bdl,
        const unsigned short* __restrict__ P16, const unsigned short* __restrict__ Q16,
        const float* __restrict__ W_align, const float* __restrict__ b_align, int r,
        unsigned short* __restrict__ wnei, float* __restrict__ wsum){
    int bid = blockIdx.x;
    int mol = bid & (B_-1), chunk = bid >> 7;
    int wv = threadIdx.x >> 6, lane = threadIdx.x & 63;
    int al = mol*L_ + chunk*4 + wv;
    __shared__ float s_nei[4][N_][D_];

    int idxn[N_]; bool pad[N_];
    for (int n=0;n<N_;n++){ idxn[n] = adl[al*N_ + n]; pad[n] = (idxn[n] == L_-1); }

    float s2[N_];
    float s1v;
    if (r == 0){
        for (int j = lane; j < N_*D_; j += 64){
            int n = j / D_, d = j - n*D_;
            int bd = bdl[al*N_ + n];
            float acc = bu2f(P16[((size_t)mol*L_ + idxn[n])*D_ + d])
                      + bu2f(Q16[((size_t)mol*MB_ + bd)*D_ + d]);
            s_nei[wv][n][d] = lreluf(acc);
        }
        const float* Wab = W_align + D_;
        for (int n=0;n<N_;n++){
            float acc = 0.f;
            for (int d=lane; d<D_; d+=64) acc += s_nei[wv][n][d] * Wab[d];
            for (int o=32;o>0;o>>=1) acc += __shfl_xor(acc,o);
            s2[n] = acc;
        }
        float a1 = 0.f;
        for (int d=lane; d<D_; d+=64) a1 += bu2f(XH[(size_t)al*KP + 200 + d]) * W_align[d];
        for (int o=32;o>0;o>>=1) a1 += __shfl_xor(a1,o);
        s1v = a1;
    } else {
        float tmp = 0.f;
        if (lane < N_) tmp = tb[mol*L_ + idxn[lane]];
        for (int n=0;n<N_;n++) s2[n] = __shfl(tmp, n);
        s1v = s1[al];
    }

    float bav = b_align[r];
    float a[N_]; float mx = -1e30f;
    for (int n=0;n<N_;n++){
        float v = lreluf(s1v + s2[n] + bav);
        if (pad[n]) v += NEGV;
        a[n] = v; mx = fmaxf(mx, v);
    }
    float w[N_]; float se = 0.f;
    for (int n=0;n<N_;n++){ float e = expf(a[n]-mx); w[n]=e; se += e; }
    float inv = 1.f/se; float wsv = 0.f;
    for (int n=0;n<N_;n++){ w[n] = pad[n] ? 0.f : w[n]*inv; wsv += w[n]; }

    if (r == 0){
        for (int d=lane; d<D_; d+=64){
            float acc = 0.f;
            #pragma unroll
            for (int n=0;n<N_;n++) acc += w[n] * s_nei[wv][n][d];
            wnei[(size_t)al*KC + d] = f2b(acc);
        }
    } else {
        for (int d=lane; d<D_; d+=64){
            float acc = 0.f;
            #pragma unroll
            for (int n=0;n<N_;n++) acc += w[n] * bu2f(cur16[((size_t)mol*L_ + idxn[n])*KC + d]);
            wnei[(size_t)al*KC + d] = f2b(acc);
        }
    }
    if (lane < 24) wnei[(size_t)al*KC + 200 + lane] = 0;
    if (lane==0) wsum[al] = wsv;
}

// MFMA ctx GEMM: elu(wnei[16384,KC] @ WatT[r]^T + wsum*bias) -> XH x-half. 128x64 tile.
__global__ void __launch_bounds__(256) k_ctxmfma(const unsigned short* __restrict__ Wn,
        const float* __restrict__ wsum, const unsigned short* __restrict__ WatT,
        const float* __restrict__ bias, int r, unsigned short* __restrict__ XH){
    __shared__ unsigned short As[128][40];
    __shared__ unsigned short Bs[64][40];
    int tid = threadIdx.x;
    int m0 = ((int)blockIdx.x & 127) * 128;
    int n0 = ((int)blockIdx.x >> 7) * 64;
    const unsigned short* Bt = WatT + (size_t)r*NC*KC;
    int lane = tid & 63, wv = tid >> 6;
    int quad = lane >> 4, lm = lane & 15;
    f32x4 acc[2][4];
    #pragma unroll
    for (int a=0;a<2;a++)
        #pragma unroll
        for (int b=0;b<4;b++) acc[a][b] = (f32x4){0.f,0.f,0.f,0.f};
    for (int ks = 0; ks < 7; ks++){
        int r0_ = tid >> 2, c0 = (tid & 3) * 8;
        int r1_ = (tid + 256) >> 2, c1 = ((tid + 256) & 3) * 8;
        uint4 a0 = *(const uint4*)&Wn[(size_t)(m0 + r0_)*KC + ks*32 + c0];
        uint4 a1 = *(const uint4*)&Wn[(size_t)(m0 + r1_)*KC + ks*32 + c1];
        uint4 b0 = *(const uint4*)&Bt[(size_t)(n0 + (tid >> 2))*KC + ks*32 + (tid & 3)*8];
        __syncthreads();
        *(uint4*)&As[r0_][c0] = a0;
        *(uint4*)&As[r1_][c1] = a1;
        *(uint4*)&Bs[tid >> 2][(tid & 3)*8] = b0;
        __syncthreads();
        short8 av0 = *(const short8*)&As[wv*32 + lm][quad*8];
        short8 av1 = *(const short8*)&As[wv*32 + 16 + lm][quad*8];
        #pragma unroll
        for (int ns=0; ns<4; ns++){
            short8 bv = *(const short8*)&Bs[ns*16 + lm][quad*8];
            acc[0][ns] = __builtin_amdgcn_mfma_f32_16x16x32_bf16(av0, bv, acc[0][ns], 0,0,0);
            acc[1][ns] = __builtin_amdgcn_mfma_f32_16x16x32_bf16(av1, bv, acc[1][ns], 0,0,0);
        }
    }
    #pragma unroll
    for (int ms=0; ms<2; ms++)
      #pragma unroll
      for (int ns=0; ns<4; ns++){
        int n = n0 + ns*16 + lm;
        if (n < 200){
            float bv = bias[r*D_ + n];
            #pragma unroll
            for (int i=0;i<4;i++){
                int row = m0 + wv*32 + ms*16 + quad*4 + i;
                float v = acc[ms][ns][i] + wsum[row]*bv;
                XH[(size_t)row*KP + n] = f2b(eluf(v));
            }
        }
      }
}

// MFMA gate GEMM: C[16384,NP] = XH @ B2t[r]^T. 128x128 tile.
__global__ void __launch_bounds__(256) k_gemm(const unsigned short* __restrict__ XH,
        const unsigned short* __restrict__ B2t, unsigned short* __restrict__ C, int r){
    __shared__ unsigned short As[128][40];
    __shared__ unsigned short Bs[128][40];
    int tid = threadIdx.x;
    int m0 = ((int)blockIdx.x & 127) * 128;
    int n0 = ((int)blockIdx.x >> 7) * 128;
    const unsigned short* Bt = B2t + (size_t)r*NP*KP;
    int lane = tid & 63, wv = tid >> 6;
    int quad = lane >> 4, lm = lane & 15;
    f32x4 acc[2][8];
    #pragma unroll
    for (int a=0;a<2;a++)
        #pragma unroll
        for (int b=0;b<8;b++) acc[a][b] = (f32x4){0.f,0.f,0.f,0.f};
    for (int ks = 0; ks < 13; ks++){
        int r0_ = tid >> 2, c0 = (tid & 3) * 8;
        int r1_ = (tid + 256) >> 2, c1 = ((tid + 256) & 3) * 8;
        uint4 a0 = *(const uint4*)&XH[(size_t)(m0 + r0_)*KP + ks*32 + c0];
        uint4 a1 = *(const uint4*)&XH[(size_t)(m0 + r1_)*KP + ks*32 + c1];
        uint4 b0 = *(const uint4*)&Bt[(size_t)(n0 + r0_)*KP + ks*32 + c0];
        uint4 b1 = *(const uint4*)&Bt[(size_t)(n0 + r1_)*KP + ks*32 + c1];
        __syncthreads();
        *(uint4*)&As[r0_][c0] = a0;
        *(uint4*)&As[r1_][c1] = a1;
        *(uint4*)&Bs[r0_][c0] = b0;
        *(uint4*)&Bs[r1_][c1] = b1;
        __syncthreads();
        short8 av0 = *(const short8*)&As[wv*32 + lm][quad*8];
        short8 av1 = *(const short8*)&As[wv*32 + 16 + lm][quad*8];
        #pragma unroll
        for (int ns=0; ns<8; ns++){
            short8 bv = *(const short8*)&Bs[ns*16 + lm][quad*8];
            acc[0][ns] = __builtin_amdgcn_mfma_f32_16x16x32_bf16(av0, bv, acc[0][ns], 0,0,0);
            acc[1][ns] = __builtin_amdgcn_mfma_f32_16x16x32_bf16(av1, bv, acc[1][ns], 0,0,0);
        }
    }
    #pragma unroll
    for (int ms=0; ms<2; ms++)
      #pragma unroll
      for (int ns=0; ns<8; ns++)
        #pragma unroll
        for (int i=0;i<4;i++){
            int row = m0 + wv*32 + ms*16 + quad*4 + i;
            C[(size_t)row*NP + n0 + ns*16 + lm] = f2b(acc[ms][ns][i]);
        }
}

// GRU combine, wave-per-atom; GRU state lives in XH h-half (bf16). Writes cur16;
// fuses next-round s1/tb dots (r<2) or curdot (r==2).
__global__ void __launch_bounds__(256) k_gru2(const unsigned short* __restrict__ C,
        unsigned short* __restrict__ XH, unsigned short* __restrict__ cur16,
        const float* __restrict__ bih, const float* __restrict__ bhh,
        const float* __restrict__ W_align, const float* __restrict__ Wma, int r,
        float* __restrict__ s1, float* __restrict__ tb, float* __restrict__ curdot){
    int wv = threadIdx.x >> 6, lane = threadIdx.x & 63;
    int al = blockIdx.x*4 + wv;
    size_t base = (size_t)al*NP;
    const float* bi = bih + r*G3D_;
    const float* bh = bhh + r*G3D_;
    const float* Wa = W_align + (r+1)*2*D_;   // dereferenced only when r<2
    bool last = (r == R_-1);
    float a1 = 0.f, a2 = 0.f;
    for (int j = lane; j < D_; j += 64){
        float rsum = bu2f(C[base + j]);
        float zsum = bu2f(C[base + 200 + j]);
        float gin  = bu2f(C[base + 400 + j]);
        float ghn  = bu2f(C[base + 600 + j]);
        float rr = sigmf(rsum + bi[j] + bh[j]);
        float zz = sigmf(zsum + bi[D_+j] + bh[D_+j]);
        float nn = tanhf(gin + bi[2*D_+j] + rr*(ghn + bh[2*D_+j]));
        size_t hx = (size_t)al*KP + 200 + j;
        float hv = bu2f(XH[hx]);
        float hn = (1.f-zz)*nn + zz*hv;
        XH[hx] = f2b(hn);
        float cv = fmaxf(hn, 0.f);
        cur16[(size_t)al*KC + j] = f2b(cv);
        if (last){
            a1 += cv * Wma[D_+j];
        } else {
            a1 += cv * Wa[j];
            a2 += cv * Wa[D_+j];
        }
    }
    if (lane < 24) cur16[(size_t)al*KC + 200 + lane] = 0;
    for (int o=32;o>0;o>>=1){ a1 += __shfl_xor(a1,o); a2 += __shfl_xor(a2,o); }
    if (lane==0){
        if (last) curdot[al] = a1;
        else { s1[al] = a1; tb[al] = a2; }
    }
}

__device__ __forceinline__ float brSum(float v, float* s_red){
    for (int o=32;o>0;o>>=1) v += __shfl_xor(v,o);
    int lane = threadIdx.x & 63, wid = threadIdx.x >> 6;
    __syncthreads();
    if (lane==0) s_red[wid] = v;
    __syncthreads();
    float r = 0.f;
    int nw = blockDim.x >> 6;
    for (int i=0;i<nw;i++) r += s_red[i];
    return r;
}

__device__ __forceinline__ float brMax(float v, float* s_red){
    for (int o=32;o>0;o>>=1) v = fmaxf(v, __shfl_xor(v,o));
    int lane = threadIdx.x & 63, wid = threadIdx.x >> 6;
    __syncthreads();
    if (lane==0) s_red[wid] = v;
    __syncthreads();
    float r = s_red[0];
    int nw = blockDim.x >> 6;
    for (int i=1;i<nw;i++) r = fmaxf(r, s_red[i]);
    return r;
}

// molecule phase, 512 threads (8 waves): cur16 tile in LDS; 2-way chunk splits; bf16 weights;
// gates GEMV unroll-4.
__global__ void __launch_bounds__(512) k_mol(const unsigned short* __restrict__ cur16,
    const float* __restrict__ curdot, const float* __restrict__ atom_mask,
    const float* __restrict__ Wma, const float* __restrict__ bma,
    const unsigned short* __restrict__ Wmt16, const float* __restrict__ bmt,
    const unsigned short* __restrict__ mTi, const unsigned short* __restrict__ mTh,
    const float* __restrict__ mbih, const float* __restrict__ mbhh,
    const unsigned short* __restrict__ Wme16, const float* __restrict__ bme,
    const float* __restrict__ Wout, const float* __restrict__ bout,
    void* __restrict__ out, const unsigned* __restrict__ amtag){
    int b = blockIdx.x, tid = threadIdx.x;
    int dq = tid & 255, cq = tid >> 8;
    __shared__ unsigned short s_cur[L_*KC];
    __shared__ float s_am[L_], s_neg[L_], s_cd[L_], s_w[L_];
    __shared__ float s_mf[D_], s_act[D_], s_wc[D_], s_ctx[D_];
    __shared__ float s_gi[G3D_], s_gh[G3D_];
    __shared__ float s_part[2][256];
    __shared__ float s_red[8];
    const uint4* src = (const uint4*)(cur16 + (size_t)b*L_*KC);
    for (int i = tid; i < L_*KC/8; i += 512) ((uint4*)s_cur)[i] = src[i];
    if (tid < L_){
        float am = atom_mask[b*L_ + tid];
        s_am[tid] = am;
        s_neg[tid] = (am == 0.f) ? NEGV : 0.f;
        s_cd[tid] = curdot[b*L_ + tid];
    }
    __syncthreads();
    {
        float a0 = 0.f, a1 = 0.f;
        if (dq < D_)
            for (int l=cq*64; l<cq*64+64; l+=2){
                a0 += bu2f(s_cur[l*KC + dq]) * s_am[l];
                a1 += bu2f(s_cur[(l+1)*KC + dq]) * s_am[l+1];
            }
        s_part[cq][dq] = a0 + a1;
        __syncthreads();
        if (tid < D_){
            float v = s_part[0][tid] + s_part[1][tid];
            s_mf[tid] = v; s_act[tid] = fmaxf(v, 0.f);
        }
        __syncthreads();
    }
    float bma0 = bma[0];
    for (int t=0;t<T_;t++){
        float p = (tid < D_) ? s_act[tid] * Wma[tid] : 0.f;
        float s1v = brSum(p, s_red);
        float sc = (tid < L_) ? (lreluf(s1v + s_cd[tid] + bma0) + s_neg[tid]) : -1e30f;
        float mx = brMax(sc, s_red);
        float e = (tid < L_) ? expf(sc - mx) : 0.f;
        float se = brSum(e, s_red);
        float wv_ = (tid < L_) ? e/se*s_am[tid] : 0.f;
        if (tid < L_) s_w[tid] = wv_;
        float wsm = brSum(wv_, s_red);
        __syncthreads();
        {
            float a0 = 0.f, a1 = 0.f;
            if (dq < D_)
                for (int l=cq*64; l<cq*64+64; l+=2){
                    a0 += s_w[l] * bu2f(s_cur[l*KC + dq]);
                    a1 += s_w[l+1] * bu2f(s_cur[(l+1)*KC + dq]);
                }
            s_part[cq][dq] = a0 + a1;
            __syncthreads();
            if (tid < D_) s_wc[tid] = s_part[0][tid] + s_part[1][tid];
            __syncthreads();
        }
        {
            float a0 = 0.f, a1 = 0.f;
            if (dq < D_)
                for (int k=cq*100; k<cq*100+100; k+=2){
                    a0 += s_wc[k] * bu2f(Wmt16[(size_t)k*D_ + dq]);
                    a1 += s_wc[k+1] * bu2f(Wmt16[(size_t)(k+1)*D_ + dq]);
                }
            s_part[cq][dq] = a0 + a1;
            __syncthreads();
            if (tid < D_)
                s_ctx[tid] = eluf(s_part[0][tid] + s_part[1][tid] + wsm * bmt[tid]);
            __syncthreads();
        }
        for (int j=tid; j<G3D_; j+=512){
            float ai0=0.f, ai1=0.f, ai2=0.f, ai3=0.f;
            float ah0=0.f, ah1=0.f, ah2=0.f, ah3=0.f;
            for (int k=0;k<D_;k+=4){
                ai0 += s_ctx[k]   * bu2f(mTi[(size_t)k*G3D_ + j]);
                ai1 += s_ctx[k+1] * bu2f(mTi[(size_t)(k+1)*G3D_ + j]);
                ai2 += s_ctx[k+2] * bu2f(mTi[(size_t)(k+2)*G3D_ + j]);
                ai3 += s_ctx[k+3] * bu2f(mTi[(size_t)(k+3)*G3D_ + j]);
                ah0 += s_mf[k]    * bu2f(mTh[(size_t)k*G3D_ + j]);
                ah1 += s_mf[k+1]  * bu2f(mTh[(size_t)(k+1)*G3D_ + j]);
                ah2 += s_mf[k+2]  * bu2f(mTh[(size_t)(k+2)*G3D_ + j]);
                ah3 += s_mf[k+3]  * bu2f(mTh[(size_t)(k+3)*G3D_ + j]);
            }
            s_gi[j] = (ai0+ai1)+(ai2+ai3); s_gh[j] = (ah0+ah1)+(ah2+ah3);
        }
        __syncthreads();
        if (tid < D_){
            int d = tid;
            float rr = sigmf(s_gi[d] + mbih[d] + s_gh[d] + mbhh[d]);
            float zz = sigmf(s_gi[D_+d] + mbih[D_+d] + s_gh[D_+d] + mbhh[D_+d]);
            float nn = tanhf(s_gi[2*D_+d] + mbih[2*D_+d] + rr*(s_gh[2*D_+d] + mbhh[2*D_+d]));
            float nm = (1.f-zz)*nn + zz*s_mf[d];
            s_mf[d] = nm; s_act[d] = fmaxf(nm, 0.f);
        }
        __syncthreads();
    }
    const float dd = (float)(R_ - 2);
    {
        float a0 = 0.f, a1 = 0.f;
        if (dq < D_)
            for (int k=cq*100; k<cq*100+100; k+=2){
                float mf0 = s_mf[k], mf1 = s_mf[k+1];
                a0 += mf0 * bu2f(Wme16[(size_t)k*D_ + dq])
                    + (mf0 + dd) * bu2f(Wme16[(size_t)(D_+k)*D_ + dq]);
                a1 += mf1 * bu2f(Wme16[(size_t)(k+1)*D_ + dq])
                    + (mf1 + dd) * bu2f(Wme16[(size_t)(D_+k+1)*D_ + dq]);
            }
        s_part[cq][dq] = a0 + a1;
        __syncthreads();
        float p = 0.f;
        if (tid < D_)
            p = (s_part[0][tid] + s_part[1][tid] + bme[tid]) * Wout[tid];
        float o = brSum(p, s_red);
        if (tid==0){
            o += bout[0];
            if (*amtag == FP32TAG) ((float*)out)[b] = o;
            else ((bf16*)out)[b] = __float2bfloat16(o);
        }
    }
}

extern "C" void kernel_launch(void* const* d_in, const int* in_sizes, int n_in,
                              void* d_out, int out_size, void* d_ws, size_t ws_size,
                              hipStream_t stream) {
    const int* adl = (const int*)d_in[2];
    const int* bdl = (const int*)d_in[3];
    const unsigned* amtag = (const unsigned*)d_in[4];

    static const int srcidx[NSEG] = {4,9,10,12,15,16,17,18,20,23,24,26,27,28};
    static const int segsz[NSEG]  = {16384,1200,3,600,1800,1800,400,1,200,600,600,200,200,1};
    CvtArgs ca;
    int ofs[NSEG+1]; ofs[0] = 0;
    for (int i=0;i<NSEG;i++){ ca.src[i] = d_in[srcidx[i]]; ca.ofs[i] = ofs[i]; ofs[i+1] = ofs[i] + segsz[i]; }
    ca.ofs[NSEG] = ofs[NSEG];   // 23989

    // ws layout. ~54 MB total.
    float* ws   = (float*)d_ws;
    float* conv = ws;                                            // 24000 fl
    unsigned short* XH    = (unsigned short*)(conv + 24000);     // BL_*KP sh
    unsigned short* B2t   = XH + (size_t)BL_*KP;                 // PREPB_N sh
    unsigned short* WatT  = B2t + PREPB_N;                       // PREPW_N sh
    unsigned short* mTi   = WatT + PREPW_N;                      // PREPM_N sh
    unsigned short* mTh   = mTi + PREPM_N;                       // PREPM_N sh
    unsigned short* Wmt16 = mTh + PREPM_N;                       // PREPT_N sh
    unsigned short* Wme16 = Wmt16 + PREPT_N;                     // PREPE_N sh
    unsigned short* Bi16  = Wme16 + PREPE_N;                     // BI_N sh
    unsigned short* cur16 = Bi16 + BI_N;                         // BL_*KC sh
    unsigned short* creg  = cur16 + (size_t)BL_*KC;              // C region: BL_*NP sh
    unsigned short* C = creg;
    unsigned short* A16  = creg;                                 // overlay (dead before wnei)
    unsigned short* wnei = creg;                                 // BL_*KC sh overlay
    unsigned short* Q16  = creg + (size_t)BL_*KC;                // B_*MB_*D_ sh overlay
    unsigned short* P16  = Q16 + (size_t)B_*MB_*D_;              // BL_*D_ sh overlay
    float* s1     = (float*)(creg + (size_t)BL_*NP);
    float* tb     = s1 + BL_;
    float* wsum   = tb + BL_;
    float* curdot = wsum + BL_;

    const float* c_amask = conv + ofs[0];
    const float* c_Walign= conv + ofs[1];
    const float* c_balign= conv + ofs[2];
    const float* c_batt  = conv + ofs[3];
    const float* c_bih   = conv + ofs[4];
    const float* c_bhh   = conv + ofs[5];
    const float* c_Wma   = conv + ofs[6];
    const float* c_bma   = conv + ofs[7];
    const float* c_bmt   = conv + ofs[8];
    const float* c_mbih  = conv + ofs[9];
    const float* c_mbhh  = conv + ofs[10];
    const float* c_bme   = conv + ofs[11];
    const float* c_Wout  = conv + ofs[12];
    const float* c_bout  = conv + ofs[13];

    PrepArgs A;
    A.cvt = ca;
    A.Wih = d_in[13]; A.Whh = d_in[14]; A.Watt = d_in[11];
    A.mWih = d_in[21]; A.mWhh = d_in[22]; A.Wmt = d_in[19]; A.Wme = d_in[25];
    A.bond = d_in[1]; A.Wnei = d_in[7]; A.atom = d_in[0]; A.Watom = d_in[5];
    A.conv = conv;
    A.B2t = B2t; A.WatT = WatT; A.mTi = mTi; A.mTh = mTh;
    A.Wmt16 = Wmt16; A.Wme16 = Wme16; A.XH = XH; A.A16 = A16; A.Bi16 = Bi16;
    A.amtag = amtag;
    A.ew_total = CONV_N + PREPB_N + PREPW_N + PREPM_N + PREPT_N + PREPE_N
               + XHPAD_N + A_N + BI_N;   // 4990773

    k_prep<<<(A.ew_total + 255)/256, 256, 0, stream>>>(A);
    k_initmm<<<(AROWS/128)*7, 256, 0, stream>>>(A16, Bi16, d_in[6], d_in[8],
                                                XH, P16, Q16, amtag);

    for (int r=0; r<R_; r++){
        k_attn<<<BL_/4, 256, 0, stream>>>(cur16, XH, s1, tb, adl, bdl, P16, Q16,
                                          c_Walign, c_balign, r, wnei, wsum);
        k_ctxmfma<<<(BL_/128)*(NC/64), 256, 0, stream>>>(wnei, wsum, WatT, c_batt, r, XH);
        k_gemm<<<(BL_/128)*(NP/128), 256, 0, stream>>>(XH, B2t, C, r);
        k_gru2<<<BL_/4, 256, 0, stream>>>(C, XH, cur16, c_bih, c_bhh,
                                          c_Walign, c_Wma, r, s1, tb, curdot);
    }

    k_mol<<<B_, 512, 0, stream>>>(cur16, curdot, c_amask, c_Wma, c_bma, Wmt16, c_bmt,
                                  mTi, mTh, c_mbih, c_mbhh, Wme16, c_bme, c_Wout, c_bout,
                                  d_out, amtag);
}